// Round 8
// baseline (266.786 us; speedup 1.0000x reference)
//
#include <hip/hip_runtime.h>

#define B_     64
#define DIM_   384
#define RES_   14
#define N_     196
#define HEADS_ 8
#define KD_    32
#define D_     128
#define DH_    1024
#define QK_    256
#define CH_    1536
#define EPS_   1e-5f
#define SCALE_ 0.17677669529663687f   // 32^-0.5

typedef unsigned short u16;
typedef unsigned int u32;
typedef short v8s __attribute__((ext_vector_type(8)));
typedef float v4f __attribute__((ext_vector_type(4)));
typedef u16  v4u __attribute__((ext_vector_type(4)));
typedef u32  v2u __attribute__((ext_vector_type(2)));
typedef _Float16 h2 __attribute__((ext_vector_type(2)));

static __device__ __forceinline__ u16 f2bf(float f) {
    unsigned int u = __builtin_bit_cast(unsigned int, f);
    u = (u + 0x7fffu + ((u >> 16) & 1u)) >> 16;
    return (u16)u;
}
static __device__ __forceinline__ float bf2f(u16 u) {
    unsigned int x = ((unsigned int)u) << 16;
    return __builtin_bit_cast(float, x);
}

// workspace layout (u16 element offsets)
// GEMM operand images: [kstep][kquad(4)][row(128)][8] = 4096 elems (8KB)/kstep
#define WBI_OFF  0u          // Wb  image: 12 mtiles x 12 ksteps      (589824)
#define WPI_OFF  589824u     // wp  image: 3 mtiles x 32 ksteps       (393216)
#define QI_OFF   983040u     // qT  [B][8][256][32]                   (4194304)
#define KI_OFF   5177344u    // kT  [B][8][256][32]                   (4194304)
#define VI_OFF   9371648u    // v   image: [B][8] x 7 ksteps          (14680064)
#define VLOC_U16 53411840u   // vlocI in ao image layout              (16777216)
#define TAIL_OFF 79101952u   // xI (6291456)
#define TB_OFF   98770944u   // BN tables fp32[5888]
#define BIASE_OFF 98785920u  // biasE [196][8][196] fp32 (614656 u16)

// ---------------------------------------------------------------------------
// barrier-free direct-from-global 128x128 MFMA core.
// ---------------------------------------------------------------------------
template<int KSTEPS>
static __device__ __forceinline__ void gemm_direct(
    const u16* __restrict__ Ag, const u16* __restrict__ Bg,
    v4f acc[4][4], int tid)
{
    const int lane = tid & 63, w = tid >> 6;
    const int wm = (w & 1) * 64, wn = (w >> 1) * 64;
    const int quad = lane >> 4, l16 = lane & 15;
    const u16* pa = Ag + quad * 1024 + (wm + l16) * 8;
    const u16* pb = Bg + quad * 1024 + (wn + l16) * 8;
    v8s a[2][4], b[2][4];
    #pragma unroll
    for (int i = 0; i < 4; i++) {
        a[0][i] = *(const v8s*)(pa + i * 128);
        b[0][i] = *(const v8s*)(pb + i * 128);
    }
    #pragma unroll
    for (int ks = 0; ks < KSTEPS; ks++) {
        const int cur = ks & 1, nxt = cur ^ 1;
        if (ks + 1 < KSTEPS) {
            const u16* qa = pa + (size_t)(ks + 1) * 4096;
            const u16* qb = pb + (size_t)(ks + 1) * 4096;
            #pragma unroll
            for (int i = 0; i < 4; i++) {
                a[nxt][i] = *(const v8s*)(qa + i * 128);
                b[nxt][i] = *(const v8s*)(qb + i * 128);
            }
        }
        #pragma unroll
        for (int i = 0; i < 4; i++)
            #pragma unroll
            for (int j = 0; j < 4; j++)
                acc[i][j] = __builtin_amdgcn_mfma_f32_16x16x32_bf16(a[cur][i], b[cur][j], acc[i][j], 0, 0, 0);
    }
}

// ---------------------------------------------------------------------------
// k_pre: ALL preprocessing in one launch.
// ---------------------------------------------------------------------------
__global__ __launch_bounds__(256) void k_pre(
    const float* __restrict__ x,
    const float* __restrict__ wq, const float* __restrict__ wk,
    const float* __restrict__ wv, const float* __restrict__ wp,
    const float* __restrict__ ab,
    const float* __restrict__ th1w, const float* __restrict__ th1b,
    const float* __restrict__ bq, const float* __restrict__ bnq,
    const float* __restrict__ bk, const float* __restrict__ bnk,
    const float* __restrict__ bv, const float* __restrict__ bnv,
    const float* __restrict__ bp, const float* __restrict__ bnp,
    const float* __restrict__ bvl, const float* __restrict__ bnvl,
    const int* __restrict__ bidx,
    u16* __restrict__ xI, u16* __restrict__ WbI, u16* __restrict__ WpI,
    float* __restrict__ TB, float* __restrict__ biasE)
{
    __shared__ float T[64][65];
    const int tid = threadIdx.x;
    if (blockIdx.x < 1536) {      // ---- castX ----
        const int t  = blockIdx.x;
        const int n0 = (t & 3) * 64;
        const int k0 = ((t >> 2) % 6) * 64;
        const int b  = t / 24;
        const int c = tid & 63, r4 = tid >> 6;
        #pragma unroll
        for (int i = 0; i < 16; i++) {
            int kr = i * 4 + r4;
            int gn = n0 + c;
            T[kr][c] = (gn < N_) ? x[((size_t)b * DIM_ + k0 + kr) * N_ + gn] : 0.f;
        }
        __syncthreads();
        #pragma unroll
        for (int it = 0; it < 16; it++) {
            int j = it * 256 + tid;
            int kk = j & 63, nn = j >> 6;
            int k = k0 + kk, n = n0 + nn;
            xI[(size_t)b * 98304 + (n >> 7) * 49152 + (k >> 5) * 4096
               + ((k >> 3) & 3) * 1024 + (n & 127) * 8 + (k & 7)] = f2bf(T[kk][nn]);
        }
        return;
    }
    int i = (blockIdx.x - 1536) * 256 + tid;
    if (i < 589824) {           // qkv weight image
        int mt = i / 49152, rem = i % 49152;
        int ks = rem >> 12, r2 = rem & 4095;
        int q = r2 >> 10, row = (r2 >> 3) & 127, e = r2 & 7;
        int c = mt * 128 + row, k = ks * 32 + q * 8 + e;
        float v = (c < 256) ? wq[c * 384 + k]
                : (c < 512) ? wk[(c - 256) * 384 + k]
                            : wv[(size_t)(c - 512) * 384 + k];
        WbI[i] = f2bf(v);
    } else if (i < 983040) {    // proj weight image
        int j = i - 589824;
        int mt = j >> 17, rem = j & 131071;
        int ks = rem >> 12, r2 = rem & 4095;
        int q = r2 >> 10, row = (r2 >> 3) & 127, e = r2 & 7;
        int p = mt * 128 + row, k = ks * 32 + q * 8 + e;
        WpI[j] = f2bf(wp[(size_t)p * 1024 + k]);
    } else if (i < 985984) {    // BN tables
        int j = i - 983040;
        if (j < 256) {
            int c = j;
            float s = bnq[c] * rsqrtf(bnq[768 + c] + EPS_);
            float t = (bq[c] - bnq[512 + c]) * s + bnq[256 + c];
            TB[c] = s * SCALE_; TB[256 + c] = t * SCALE_;
        } else if (j < 512) {
            int c = j - 256;
            float s = bnk[c] * rsqrtf(bnk[768 + c] + EPS_);
            float t = (bk[c] - bnk[512 + c]) * s + bnk[256 + c];
            TB[512 + c] = s; TB[768 + c] = t;
        } else if (j < 1536) {
            int c = j - 512;
            float s = bnv[c] * rsqrtf(bnv[3072 + c] + EPS_);
            float t = (bv[c] - bnv[2048 + c]) * s + bnv[1024 + c];
            TB[1024 + c] = s; TB[2048 + c] = t;
        } else if (j < 1920) {
            int c = j - 1536;
            float s = bnp[c] * rsqrtf(bnp[1152 + c] + EPS_);
            float t = (bp[c] - bnp[768 + c]) * s + bnp[384 + c];
            TB[3072 + c] = s; TB[3456 + c] = t;
        } else {
            int c = j - 1920;
            float s = bnvl[c] * rsqrtf(bnvl[3072 + c] + EPS_);
            float t = (bvl[c] - bnvl[2048 + c]) * s + bnvl[1024 + c];
            TB[3840 + c] = s; TB[4864 + c] = t;
        }
    } else if (i < 1293312) {   // biasE[n][o][m] = th1-folded bias - 5
        int j = i - 985984;
        int m = j % N_;
        int t = j / N_;
        int o = t & 7;
        int n = t >> 3;
        int idx = bidx[n * N_ + m];
        float a = th1b[o];
        #pragma unroll
        for (int h = 0; h < 8; h++) a += th1w[o * 8 + h] * ab[h * N_ + idx];
        biasE[j] = a - 5.f;
    }
}

// ---------------------------------------------------------------------------
// K1: QKV GEMM (direct core).
// XCD swizzle: 1536 blocks = 8 XCDs x (8 b x 24 tiles).
// ---------------------------------------------------------------------------
__global__ __launch_bounds__(256) void k_qkv(
    const u16* __restrict__ WbI, const u16* __restrict__ xI,
    const float* __restrict__ TB,
    u16* __restrict__ qI, u16* __restrict__ kI, u16* __restrict__ vI)
{
    const int tid = threadIdx.x;
    const int L = blockIdx.x + 2 * (blockIdx.y + 12 * blockIdx.z);
    const int idx = L >> 3;                 // 0..191
    const int b  = (L & 7) * 8 + idx / 24;  // contiguous b-chunk per XCD
    const int r  = idx % 24;
    const int mt = r >> 1, nt = r & 1;
    v4f acc[4][4] = {};
    gemm_direct<12>(WbI + (size_t)mt * 49152,
                    xI + ((size_t)b * 2 + nt) * 49152, acc, tid);

    const int lane = tid & 63, w = tid >> 6;
    const int wm = (w & 1) * 64, wn = (w >> 1) * 64;
    const int quad = lane >> 4, l16 = lane & 15;
    #pragma unroll
    for (int i = 0; i < 4; i++) {
        #pragma unroll
        for (int j = 0; j < 4; j++) {
            int gc = mt * 128 + wm + i * 16 + quad * 4;  // global channel base
            int n  = nt * 128 + wn + j * 16 + l16;       // token (0..255)
            v4f v = acc[i][j];
            if (gc < 256) {            // q
                v4f s = *(const v4f*)&TB[gc];
                v4f t = *(const v4f*)&TB[256 + gc];
                v4u u;
                #pragma unroll
                for (int r2 = 0; r2 < 4; r2++) u[r2] = f2bf(v[r2] * s[r2] + t[r2]);
                *(v4u*)&qI[((size_t)(b * 8 + (gc >> 5)) * 256 + n) * 32 + (gc & 31)] = u;
            } else if (gc < 512) {     // k
                int c = gc - 256;
                v4f s = *(const v4f*)&TB[512 + c];
                v4f t = *(const v4f*)&TB[768 + c];
                v4u u;
                #pragma unroll
                for (int r2 = 0; r2 < 4; r2++) u[r2] = f2bf(v[r2] * s[r2] + t[r2]);
                *(v4u*)&kI[((size_t)(b * 8 + (c >> 5)) * 256 + n) * 32 + (c & 31)] = u;
            } else {                   // v -> image (row = e, col = n as k-dim)
                int c = gc - 512;      // 0..1023
                if (n < 224) {
                    int o = c >> 7, e = c & 127;
                    u16* base = vI + ((size_t)(b * 8 + o) * 7 + (n >> 5)) * 4096
                                + ((n >> 3) & 3) * 1024 + (n & 7);
                    #pragma unroll
                    for (int r2 = 0; r2 < 4; r2++) {
                        u16 outv = 0;
                        if (n < N_) outv = f2bf(v[r2] * TB[1024 + c + r2] + TB[2048 + c + r2]);
                        base[(e + r2) * 8] = outv;
                    }
                }
            }
        }
    }
}

// ---------------------------------------------------------------------------
// K2: depthwise 3x3 conv. Block = 64 channels of one (b,o).
// ---------------------------------------------------------------------------
__global__ __launch_bounds__(256) void k_dwconv(
    const u16* __restrict__ vI, const float* __restrict__ wvl,
    const float* __restrict__ TB, u16* __restrict__ vlocI)
{
    __shared__ u16 V[64 * 230];             // 29440 B
    const int tid = threadIdx.x;
    const int sub = blockIdx.x;             // 0..15: o = sub>>1, half = sub&1
    const int b   = blockIdx.y;
    const int o   = sub >> 1;
    const int e0  = (sub & 1) * 64;
    const u16* img = vI + (size_t)(b * 8 + o) * 28672;

    {
        const int quad = tid >> 6, l = tid & 63;
        #pragma unroll
        for (int i = 0; i < 7; i++) {
            v8s u = *(const v8s*)&img[i * 4096 + quad * 1024 + (e0 + l) * 8];
            const u32* ui = (const u32*)&u;
            int m0 = i * 32 + quad * 8;
            u32* dst = (u32*)&V[l * 230 + m0];
            #pragma unroll
            for (int c = 0; c < 4; c++) dst[c] = ui[c];
        }
    }
    __syncthreads();

    const int e = tid & 63, j = tid >> 6;
    const int cg = sub * 64 + e;
    const int y0 = j * 4;
    const int ny = (j == 3) ? 2 : 4;
    float wgt[9];
    #pragma unroll
    for (int k = 0; k < 9; k++) wgt[k] = wvl[cg * 9 + k];
    const float sc = TB[3840 + cg], sh = TB[4864 + cg];
    u32 po[4][7];

    for (int yi = 0; yi < ny; yi++) {
        int y = y0 + yi;
        float a[3][16];
        #pragma unroll
        for (int dy = 0; dy < 3; dy++) {
            int yy = y + dy - 1;
            a[dy][0] = 0.f; a[dy][15] = 0.f;
            if (yy < 0 || yy > 13) {
                #pragma unroll
                for (int x = 1; x < 15; x++) a[dy][x] = 0.f;
            } else {
                const u16* rp = &V[e * 230 + yy * 14];
                #pragma unroll
                for (int c4 = 0; c4 < 7; c4++) {
                    u32 u = *(const u32*)&rp[c4 * 2];
                    a[dy][1 + 2 * c4] = bf2f((u16)(u & 0xffffu));
                    a[dy][2 + 2 * c4] = bf2f((u16)(u >> 16));
                }
            }
        }
        #pragma unroll
        for (int xp = 0; xp < 7; xp++) {
            u32 pk = 0;
            #pragma unroll
            for (int half = 0; half < 2; half++) {
                int x = 2 * xp + half;
                float s = 0.f;
                #pragma unroll
                for (int dy = 0; dy < 3; dy++)
                    #pragma unroll
                    for (int kx = 0; kx < 3; kx++)
                        s += wgt[dy * 3 + kx] * a[dy][x + kx];
                u16 bv = f2bf(s * sc + sh);
                pk |= ((u32)bv) << (16 * half);
            }
            po[yi][xp] = pk;
        }
    }
    __syncthreads();

    for (int yi = 0; yi < ny; yi++) {
        u32* dst = (u32*)&V[e * 196 + (y0 + yi) * 14];
        #pragma unroll
        for (int xp = 0; xp < 7; xp++) dst[xp] = po[yi][xp];
    }
    __syncthreads();

    for (int it = 0; it < 7; it++) {
        int idx = it * 256 + tid;
        if (idx < 1568) {
            int g = idx / 196, n = idx - g * 196;
            v4u lo, hi;
            #pragma unroll
            for (int r = 0; r < 4; r++) lo[r] = V[(g * 8 + r) * 196 + n];
            #pragma unroll
            for (int r = 0; r < 4; r++) hi[r] = V[(g * 8 + 4 + r) * 196 + n];
            u16* dst = vlocI + ((size_t)(b * 2 + (n >> 7)) * 32 + sub * 2 + (g >> 2)) * 4096
                     + (g & 3) * 1024 + (n & 127) * 8;
            *(v4u*)dst = lo;
            *(v4u*)(dst + 4) = hi;
        }
    }
}

// ---------------------------------------------------------------------------
// K3: FUSED attention + AV + vloc + relu + PROJECTION + BN -> out fp32.
// 512 threads / 8 waves, QBLK=16, register-resident softmax (round-7 core).
// NEW: block (b,qt) owns all 1024 ao-channels for its 16 tokens = one full
// K-column of the projection GEMM. Epilogue writes relu(av+vloc) to LDS
// Ao[16n][512c] (XOR bit4-6 swizzle, B-frag order); after o-heads 0-3 / 4-7
// the two K=512 halves of out = Wp . ao run in-block (wave w -> p-tiles
// {w, w+8, w+16}; A-frags streamed from the L2-resident WpI image),
// accumulating in 12 registers; BN + fp32 store. aoI HBM round-trip
// (25 MB write + 33 MB read) and the k_proj launch are eliminated.
// LDS: Ps 14848 + Ao 16384 + Zf = ~31.2 KB (red/invS alias inside Ao).
// XCD swizzle: 832 blocks = 8 XCDs x (8 b x 13 qt).
// ---------------------------------------------------------------------------
#define SLST 232   // P-slice m-stride in u16 (464 B row; %8==0 for 16B align)
__global__ __launch_bounds__(512, 4) void k_attn_av(
    const u16* __restrict__ qI, const u16* __restrict__ kI,
    const u16* __restrict__ vI,
    const float* __restrict__ th1w,
    const float* __restrict__ th2w, const float* __restrict__ th2b,
    const float* __restrict__ biasE,
    const u16* __restrict__ vlocI,
    const u16* __restrict__ WpI, const float* __restrict__ TB,
    float* __restrict__ out)
{
    __shared__ __attribute__((aligned(16))) u16 Ps[2][16 * SLST];  // 14848 B
    __shared__ __attribute__((aligned(16))) u16 Ao[16 * 512];      // 16384 B
    __shared__ __attribute__((aligned(16))) u16 Zf[8];             // zero frag
    float* red  = (float*)&Ao[0];      // [8 wave][8 o][16 q] = 4096 B (pre-o-loop)
    float* invS = (float*)&Ao[2048];   // [8 o][16 q] = 512 B     (pre-o-loop)
    const int tid = threadIdx.x;
    const int w = tid >> 6, lane = tid & 63;
    const int quad = lane >> 4, l16 = lane & 15;
    const int L = blockIdx.x + 13 * blockIdx.y;
    const int idx = L >> 3;                 // 0..103
    const int b  = (L & 7) * 8 + idx / 13;  // contiguous b-chunk per XCD
    const int qt = idx % 13;                // 0..12
    const int n0 = qt * 16;
    if (tid < 8) Zf[tid] = 0;

    const int nmt = (w < 5) ? 2 : 1;        // waves 0-4: mtiles {w, w+8}; 5-7: {w}
    const int nq  = n0 + l16;               // this lane's q token
    const int nb  = (nq < N_) ? nq : 0;     // clamped biasE row
    const float* bErow = biasE + (size_t)nb * 1568;

    // ---- phase A + B1: S via MFMA (all 8 h per mtile), th1-mix + exp in regs
    h2 E[2][8][2] = {};     // [mi][o][pair]; pair p covers m r={2p,2p+1}
    #pragma unroll
    for (int mi = 0; mi < 2; mi++) {
        if (mi >= nmt) break;
        const int mt = w + mi * 8;
        v4f S[8];
        const u16* qb0 = qI + (size_t)b * 8 * 8192;
        const u16* kb0 = kI + (size_t)b * 8 * 8192;
        #pragma unroll
        for (int h = 0; h < 8; h++) {
            v8s qf = *(const v8s*)&qb0[h * 8192 + (n0 + l16) * 32 + quad * 8];
            v8s kf = *(const v8s*)&kb0[h * 8192 + (mt * 16 + l16) * 32 + quad * 8];
            v4f z = {};
            S[h] = __builtin_amdgcn_mfma_f32_16x16x32_bf16(kf, qf, z, 0, 0, 0);
        }
        const bool mvalid = (mt < 12) || (quad == 0);   // all 4 m < 196 ?
        const int mb = mt * 16 + quad * 4;
        if (mvalid) {
            #pragma unroll
            for (int o = 0; o < 8; o++) {
                v4f a = *(const v4f*)&bErow[o * 196 + mb];
                #pragma unroll
                for (int h = 0; h < 8; h++) {
                    float t1 = th1w[o * 8 + h];
                    #pragma unroll
                    for (int r = 0; r < 4; r++) a[r] += t1 * S[h][r];
                }
                E[mi][o][0] = h2{(_Float16)__expf(a[0]), (_Float16)__expf(a[1])};
                E[mi][o][1] = h2{(_Float16)__expf(a[2]), (_Float16)__expf(a[3])};
            }
        }
    }

    // ---- B2: softmax denominators per (o, q) ----
    {
        float psum[8];
        #pragma unroll
        for (int o = 0; o < 8; o++) {
            float s = (float)E[0][o][0].x + (float)E[0][o][0].y
                    + (float)E[0][o][1].x + (float)E[0][o][1].y
                    + (float)E[1][o][0].x + (float)E[1][o][0].y
                    + (float)E[1][o][1].x + (float)E[1][o][1].y;
            s += __shfl_xor(s, 16, 64);
            s += __shfl_xor(s, 32, 64);
            psum[o] = s;
        }
        red[(w * 8 + quad * 2 + 0) * 16 + l16] = psum[quad * 2 + 0];
        red[(w * 8 + quad * 2 + 1) * 16 + l16] = psum[quad * 2 + 1];
    }
    __syncthreads();
    if (tid < 128) {
        int o = tid >> 4, q = tid & 15;
        float s = 0.f;
        #pragma unroll
        for (int wv = 0; wv < 8; wv++) s += red[(wv * 8 + o) * 16 + q];
        invS[o * 16 + q] = 1.f / s;
    }
    __syncthreads();

    // fold invS into E (packed f16 mul)
    #pragma unroll
    for (int o = 0; o < 8; o++) {
        float is = invS[o * 16 + l16];
        h2 is2 = h2{(_Float16)is, (_Float16)is};
        E[0][o][0] *= is2; E[0][o][1] *= is2;
        E[1][o][0] *= is2; E[1][o][1] *= is2;
    }

    // ---- C-loop over output heads: B3 slice write + AV MFMA + Ao epilogue,
    //      with the two projection K-halves after o2=3 and o2=7 ----
    const bool act = (nq < N_);
    char* psrow0 = (char*)&Ps[0][0] + l16 * (SLST * 2);
    char* psrow1 = (char*)&Ps[1][0] + l16 * (SLST * 2);
    char* aorow  = (char*)&Ao[0] + l16 * 1024;         // row n = l16, 1024 B
    const int aswz = (l16 & 7) << 4;                   // XOR bits 4-6
    const u16* wpb = WpI + quad * 1024 + (w * 16 + l16) * 8;
    v4f pacc[3] = {};                                  // proj accumulators

    #pragma unroll
    for (int o2 = 0; o2 < 8; o2++) {
        char* psb = (o2 & 1) ? psrow1 : psrow0;
        // B3: P[o2] for this lane's m-chunks; zeros for invalid m (196..208)
        #pragma unroll
        for (int mi = 0; mi < 2; mi++) {
            if (mi >= nmt) break;
            const int mt = w + mi * 8;
            const bool mvalid = (mt < 12) || (quad == 0);
            u32 pk0 = 0, pk1 = 0;
            if (mvalid) {
                float p0 = th2b[o2], p1 = th2b[o2], p2 = th2b[o2], p3 = th2b[o2];
                #pragma unroll
                for (int o = 0; o < 8; o++) {
                    float wgt = th2w[o2 * 8 + o];
                    p0 += wgt * (float)E[mi][o][0].x;
                    p1 += wgt * (float)E[mi][o][0].y;
                    p2 += wgt * (float)E[mi][o][1].x;
                    p3 += wgt * (float)E[mi][o][1].y;
                }
                pk0 = (u32)f2bf(p0) | ((u32)f2bf(p1) << 16);
                pk1 = (u32)f2bf(p2) | ((u32)f2bf(p3) << 16);
            }
            v2u pw; pw[0] = pk0; pw[1] = pk1;
            *(v2u*)(psb + mt * 32 + quad * 8) = pw;   // in-bounds: <= 416 < 464
        }
        // issue ALL 7 V fragments before the barrier (fly during the drain)
        const u16* vb = vI + (size_t)(b * 8 + o2) * 28672;
        const u16* af = vb + quad * 1024 + (w * 16 + l16) * 8;
        v8s va[7];
        #pragma unroll
        for (int ks = 0; ks < 7; ks++)
            va[ks] = *(const v8s*)(af + (size_t)ks * 4096);
        __syncthreads();

        // AV: wave w -> e-rows w*16..+15 of head o2
        v4f acc = {};
        __builtin_amdgcn_s_setprio(1);
        #pragma unroll
        for (int ks = 0; ks < 7; ks++) {
            v8s bfr = (ks == 6 && quad >= 2)
                    ? *(const v8s*)&Zf[0]                       // m >= 208
                    : *(const v8s*)(psb + ks * 64 + quad * 16); // <= 415 in-row
            acc = __builtin_amdgcn_mfma_f32_16x16x32_bf16(va[ks], bfr, acc, 0, 0, 0);
        }
        __builtin_amdgcn_s_setprio(0);

        // epilogue: relu(av + vloc) -> Ao (LDS, swizzled); zeros if !act
        {
            v4u u = {0, 0, 0, 0};
            if (act) {
                const int c0 = o2 * 128 + w * 16 + quad * 4;
                const size_t ioff = ((size_t)(b * 2 + (n0 >> 7)) * 32 + (c0 >> 5)) * 4096
                                  + ((c0 >> 3) & 3) * 1024 + (size_t)((n0 & 127) + l16) * 8 + (c0 & 7);
                v4u lv = *(const v4u*)&vlocI[ioff];
                #pragma unroll
                for (int r = 0; r < 4; r++)
                    u[r] = f2bf(fmaxf(acc[r] + bf2f(lv[r]), 0.f));
            }
            const int X = (o2 & 3) * 256 + w * 32 + quad * 8;   // byte in row
            *(v4u*)(aorow + (X ^ aswz)) = u;
        }

        // projection K-half after o2=3 (c 0..511) and o2=7 (c 512..1023)
        if (o2 == 3 || o2 == 7) {
            __syncthreads();                 // Ao half complete
            const int kh = o2 >> 2;          // 0 or 1
            __builtin_amdgcn_s_setprio(1);
            #pragma unroll
            for (int ks = 0; ks < 16; ks++) {
                v8s bf = *(const v8s*)(aorow + ((ks * 64 + quad * 16) ^ aswz));
                #pragma unroll
                for (int t = 0; t < 3; t++) {
                    v8s a = *(const v8s*)(wpb + (size_t)t * 131072
                                              + (size_t)(kh * 16 + ks) * 4096);
                    pacc[t] = __builtin_amdgcn_mfma_f32_16x16x32_bf16(a, bf, pacc[t], 0, 0, 0);
                }
            }
            __builtin_amdgcn_s_setprio(0);
            if (o2 == 3) __syncthreads();    // before o2=4 overwrites Ao
        }
    }

    // ---- BN + fp32 store: wave w -> p-tiles {w, w+8, w+16}, col n = nq ----
    if (act) {
        #pragma unroll
        for (int t = 0; t < 3; t++) {
            const int p0 = (w + t * 8) * 16 + quad * 4;
            v4f s = *(const v4f*)&TB[3072 + p0];
            v4f tt = *(const v4f*)&TB[3456 + p0];
            #pragma unroll
            for (int r = 0; r < 4; r++)
                out[((size_t)b * DIM_ + p0 + r) * N_ + nq] = pacc[t][r] * s[r] + tt[r];
        }
    }
}

// ---------------------------------------------------------------------------
extern "C" void kernel_launch(void* const* d_in, const int* in_sizes, int n_in,
                              void* d_out, int out_size, void* d_ws, size_t ws_size,
                              hipStream_t stream)
{
    const float* x    = (const float*)d_in[0];
    const float* wq   = (const float*)d_in[1];
    const float* bq   = (const float*)d_in[2];
    const float* bnq  = (const float*)d_in[3];
    const float* wk   = (const float*)d_in[4];
    const float* bk   = (const float*)d_in[5];
    const float* bnk  = (const float*)d_in[6];
    const float* wv   = (const float*)d_in[7];
    const float* bv   = (const float*)d_in[8];
    const float* bnv  = (const float*)d_in[9];
    const float* wvl  = (const float*)d_in[10];
    const float* bvl  = (const float*)d_in[11];
    const float* bnvl = (const float*)d_in[12];
    const float* th1w = (const float*)d_in[13];
    const float* th1b = (const float*)d_in[14];
    const float* th2w = (const float*)d_in[15];
    const float* th2b = (const float*)d_in[16];
    const float* wp   = (const float*)d_in[17];
    const float* bp   = (const float*)d_in[18];
    const float* bnp  = (const float*)d_in[19];
    const float* ab   = (const float*)d_in[20];
    const int*   bidx = (const int*)d_in[21];
    float* out = (float*)d_out;

    u16* wsb  = (u16*)d_ws;
    u16* WbI  = wsb + WBI_OFF;
    u16* WpI  = wsb + WPI_OFF;
    u16* qI   = wsb + QI_OFF;
    u16* kI   = wsb + KI_OFF;
    u16* vI   = wsb + VI_OFF;
    u16* vlocI = wsb + VLOC_U16;
    u16* xI   = wsb + TAIL_OFF;
    float* TB    = (float*)(wsb + TB_OFF);
    float* biasE = (float*)(wsb + BIASE_OFF);

    k_pre<<<dim3(6588), 256, 0, stream>>>(x, wq, wk, wv, wp, ab, th1w, th1b,
                                          bq, bnq, bk, bnk, bv, bnv, bp, bnp, bvl, bnvl,
                                          bidx, xI, WbI, WpI, TB, biasE);
    k_qkv<<<dim3(2, 12, B_), 256, 0, stream>>>(WbI, xI, TB, qI, kI, vI);
    k_dwconv<<<dim3(16, B_), 256, 0, stream>>>(vI, wvl, TB, vlocI);
    k_attn_av<<<dim3(13, B_), 512, 0, stream>>>(qI, kI, vI, th1w, th2w, th2b,
                                                biasE, vlocI, WpI, TB, out);
}

// Round 9
// 254.261 us; speedup vs baseline: 1.0493x; 1.0493x over previous
//
#include <hip/hip_runtime.h>

#define B_     64
#define DIM_   384
#define RES_   14
#define N_     196
#define HEADS_ 8
#define KD_    32
#define D_     128
#define DH_    1024
#define QK_    256
#define CH_    1536
#define EPS_   1e-5f
#define SCALE_ 0.17677669529663687f   // 32^-0.5

typedef unsigned short u16;
typedef unsigned int u32;
typedef short v8s __attribute__((ext_vector_type(8)));
typedef float v4f __attribute__((ext_vector_type(4)));
typedef u16  v4u __attribute__((ext_vector_type(4)));

static __device__ __forceinline__ u16 f2bf(float f) {
    unsigned int u = __builtin_bit_cast(unsigned int, f);
    u = (u + 0x7fffu + ((u >> 16) & 1u)) >> 16;
    return (u16)u;
}
static __device__ __forceinline__ float bf2f(u16 u) {
    unsigned int x = ((unsigned int)u) << 16;
    return __builtin_bit_cast(float, x);
}
static __device__ __forceinline__ u16 f2h(float f) {
    _Float16 h = (_Float16)f;
    return __builtin_bit_cast(u16, h);
}
static __device__ __forceinline__ float h2f(u16 u) {
    return (float)__builtin_bit_cast(_Float16, u);
}

// workspace layout (u16 element offsets)
// GEMM operand images: [kstep][kquad(4)][row(128)][8] = 4096 elems (8KB)/kstep
#define WBI_OFF  0u          // Wb  image: 12 mtiles x 12 ksteps      (589824)
#define WPI_OFF  589824u     // wp  image: 3 mtiles x 32 ksteps       (393216)
#define QI_OFF   983040u     // qT  [B][8][256][32]                   (4194304)
#define KI_OFF   5177344u    // kT  [B][8][256][32]                   (4194304)
#define VI_OFF   9371648u    // v   image: [B][8] x 7 ksteps          (14680064)
#define VLOC_U16 53411840u   // vlocI in aoI image layout             (16777216)
#define TAIL_OFF 79101952u   // union: xI (6291456) / aoI (16777216)
#define TB_OFF   98770944u   // BN tables fp32[5888]
#define BIASE_OFF 98785920u  // biasE [196][8][196] fp32 (614656 u16)

// ---------------------------------------------------------------------------
// barrier-free direct-from-global 128x128 MFMA core.
// ---------------------------------------------------------------------------
template<int KSTEPS>
static __device__ __forceinline__ void gemm_direct(
    const u16* __restrict__ Ag, const u16* __restrict__ Bg,
    v4f acc[4][4], int tid)
{
    const int lane = tid & 63, w = tid >> 6;
    const int wm = (w & 1) * 64, wn = (w >> 1) * 64;
    const int quad = lane >> 4, l16 = lane & 15;
    const u16* pa = Ag + quad * 1024 + (wm + l16) * 8;
    const u16* pb = Bg + quad * 1024 + (wn + l16) * 8;
    v8s a[2][4], b[2][4];
    #pragma unroll
    for (int i = 0; i < 4; i++) {
        a[0][i] = *(const v8s*)(pa + i * 128);
        b[0][i] = *(const v8s*)(pb + i * 128);
    }
    #pragma unroll
    for (int ks = 0; ks < KSTEPS; ks++) {
        const int cur = ks & 1, nxt = cur ^ 1;
        if (ks + 1 < KSTEPS) {
            const u16* qa = pa + (size_t)(ks + 1) * 4096;
            const u16* qb = pb + (size_t)(ks + 1) * 4096;
            #pragma unroll
            for (int i = 0; i < 4; i++) {
                a[nxt][i] = *(const v8s*)(qa + i * 128);
                b[nxt][i] = *(const v8s*)(qb + i * 128);
            }
        }
        #pragma unroll
        for (int i = 0; i < 4; i++)
            #pragma unroll
            for (int j = 0; j < 4; j++)
                acc[i][j] = __builtin_amdgcn_mfma_f32_16x16x32_bf16(a[cur][i], b[cur][j], acc[i][j], 0, 0, 0);
    }
}

// 3-deep 128x64 variant for k_proj (K=32 steps, 768 blocks = 3/CU).
template<int KSTEPS>
static __device__ __forceinline__ void gemm_direct3_n64(
    const u16* __restrict__ Ag, const u16* __restrict__ Bg,
    v4f acc[4][2], int tid)
{
    const int lane = tid & 63, w = tid >> 6;
    const int wm = (w & 1) * 64, wn = (w >> 1) * 32;
    const int quad = lane >> 4, l16 = lane & 15;
    const u16* pa = Ag + quad * 1024 + (wm + l16) * 8;
    const u16* pb = Bg + quad * 1024 + (wn + l16) * 8;
    v8s a[3][4], b[3][2];
    #pragma unroll
    for (int s = 0; s < 2; s++) {
        #pragma unroll
        for (int i = 0; i < 4; i++)
            a[s][i] = *(const v8s*)(pa + (size_t)s * 4096 + i * 128);
        #pragma unroll
        for (int j = 0; j < 2; j++)
            b[s][j] = *(const v8s*)(pb + (size_t)s * 4096 + j * 128);
    }
    #pragma unroll
    for (int ks = 0; ks < KSTEPS; ks++) {
        const int cur = ks % 3, nxt = (ks + 2) % 3;
        if (ks + 2 < KSTEPS) {
            const u16* qa = pa + (size_t)(ks + 2) * 4096;
            const u16* qb = pb + (size_t)(ks + 2) * 4096;
            #pragma unroll
            for (int i = 0; i < 4; i++)
                a[nxt][i] = *(const v8s*)(qa + i * 128);
            #pragma unroll
            for (int j = 0; j < 2; j++)
                b[nxt][j] = *(const v8s*)(qb + j * 128);
        }
        #pragma unroll
        for (int i = 0; i < 4; i++)
            #pragma unroll
            for (int j = 0; j < 2; j++)
                acc[i][j] = __builtin_amdgcn_mfma_f32_16x16x32_bf16(a[cur][i], b[cur][j], acc[i][j], 0, 0, 0);
    }
}

// ---------------------------------------------------------------------------
// k_pre: ALL preprocessing in one launch; DIVISION-FREE segmented grid.
//   [0,2048):    castX (b = t>>5, k0 = ((t>>2)&7)*64 skip>=6, n0 = (t&3)*64)
//   [2048,2240): WbI   (mt = t>>4, ks = t&15 skip>=12; in-block bit indexing)
//   [2240,2336): WpI   (mt = t>>5, ks = t&31)
//   [2336,2348): BN tables
//   [2348,3916): biasE (n = t>>3, o = t&7, m = tid)
// ---------------------------------------------------------------------------
__global__ __launch_bounds__(256) void k_pre(
    const float* __restrict__ x,
    const float* __restrict__ wq, const float* __restrict__ wk,
    const float* __restrict__ wv, const float* __restrict__ wp,
    const float* __restrict__ ab,
    const float* __restrict__ th1w, const float* __restrict__ th1b,
    const float* __restrict__ bq, const float* __restrict__ bnq,
    const float* __restrict__ bk, const float* __restrict__ bnk,
    const float* __restrict__ bv, const float* __restrict__ bnv,
    const float* __restrict__ bp, const float* __restrict__ bnp,
    const float* __restrict__ bvl, const float* __restrict__ bnvl,
    const int* __restrict__ bidx,
    u16* __restrict__ xI, u16* __restrict__ WbI, u16* __restrict__ WpI,
    float* __restrict__ TB, float* __restrict__ biasE)
{
    __shared__ float T[64][65];
    const int tid = threadIdx.x;
    const int t = blockIdx.x;
    if (t < 2048) {               // ---- castX ----
        const int k0i = (t >> 2) & 7;
        if (k0i >= 6) return;
        const int n0 = (t & 3) * 64;
        const int k0 = k0i * 64;
        const int b  = t >> 5;
        const int c = tid & 63, r4 = tid >> 6;
        #pragma unroll
        for (int i = 0; i < 16; i++) {
            int kr = i * 4 + r4;
            int gn = n0 + c;
            T[kr][c] = (gn < N_) ? x[((size_t)b * DIM_ + k0 + kr) * N_ + gn] : 0.f;
        }
        __syncthreads();
        #pragma unroll
        for (int it = 0; it < 16; it++) {
            int j = it * 256 + tid;
            int kk = j & 63, nn = j >> 6;
            int k = k0 + kk, n = n0 + nn;
            xI[(size_t)b * 98304 + (n >> 7) * 49152 + (k >> 5) * 4096
               + ((k >> 3) & 3) * 1024 + (n & 127) * 8 + (k & 7)] = f2bf(T[kk][nn]);
        }
        return;
    }
    if (t < 2240) {               // ---- WbI ----
        const int t2 = t - 2048;
        const int ks = t2 & 15;
        if (ks >= 12) return;
        const int mt = t2 >> 4;
        #pragma unroll
        for (int it = 0; it < 16; it++) {
            int r2 = it * 256 + tid;
            int q = r2 >> 10, row = (r2 >> 3) & 127, e = r2 & 7;
            int c = mt * 128 + row, k = ks * 32 + q * 8 + e;
            float v = (c < 256) ? wq[c * 384 + k]
                    : (c < 512) ? wk[(c - 256) * 384 + k]
                                : wv[(size_t)(c - 512) * 384 + k];
            WbI[(size_t)mt * 49152 + (size_t)ks * 4096 + r2] = f2bf(v);
        }
        return;
    }
    if (t < 2336) {               // ---- WpI ----
        const int t3 = t - 2240;
        const int mt = t3 >> 5, ks = t3 & 31;
        #pragma unroll
        for (int it = 0; it < 16; it++) {
            int r2 = it * 256 + tid;
            int q = r2 >> 10, row = (r2 >> 3) & 127, e = r2 & 7;
            int p = mt * 128 + row, k = ks * 32 + q * 8 + e;
            WpI[(size_t)mt * 131072 + (size_t)ks * 4096 + r2] = f2bf(wp[(size_t)p * 1024 + k]);
        }
        return;
    }
    if (t < 2348) {               // ---- BN tables ----
        int j = (t - 2336) * 256 + tid;
        if (j >= 2944) return;
        if (j < 256) {
            int c = j;
            float s = bnq[c] * rsqrtf(bnq[768 + c] + EPS_);
            float tt = (bq[c] - bnq[512 + c]) * s + bnq[256 + c];
            TB[c] = s * SCALE_; TB[256 + c] = tt * SCALE_;
        } else if (j < 512) {
            int c = j - 256;
            float s = bnk[c] * rsqrtf(bnk[768 + c] + EPS_);
            float tt = (bk[c] - bnk[512 + c]) * s + bnk[256 + c];
            TB[512 + c] = s; TB[768 + c] = tt;
        } else if (j < 1536) {
            int c = j - 512;
            float s = bnv[c] * rsqrtf(bnv[3072 + c] + EPS_);
            float tt = (bv[c] - bnv[2048 + c]) * s + bnv[1024 + c];
            TB[1024 + c] = s; TB[2048 + c] = tt;
        } else if (j < 1920) {
            int c = j - 1536;
            float s = bnp[c] * rsqrtf(bnp[1152 + c] + EPS_);
            float tt = (bp[c] - bnp[768 + c]) * s + bnp[384 + c];
            TB[3072 + c] = s; TB[3456 + c] = tt;
        } else {
            int c = j - 1920;
            float s = bnvl[c] * rsqrtf(bnvl[3072 + c] + EPS_);
            float tt = (bvl[c] - bnvl[2048 + c]) * s + bnvl[1024 + c];
            TB[3840 + c] = s; TB[4864 + c] = tt;
        }
        return;
    }
    {                             // ---- biasE ----
        const int t5 = t - 2348;          // 0..1567
        if (tid < N_) {
            const int n = t5 >> 3, o = t5 & 7;
            int idx = bidx[n * N_ + tid];
            float a = th1b[o];
            #pragma unroll
            for (int h = 0; h < 8; h++) a += th1w[o * 8 + h] * ab[h * N_ + idx];
            biasE[(size_t)(n * 8 + o) * N_ + tid] = a - 5.f;
        }
    }
}

// ---------------------------------------------------------------------------
// K1: QKV GEMM (direct core). qI/kI [b][h][256][32] bf16 (q pre-scaled),
// vI image per (b,o), 7 ksteps (n>=196 zero).
// XCD swizzle: 1536 blocks = 8 XCDs x (8 b x 24 tiles).
// ---------------------------------------------------------------------------
__global__ __launch_bounds__(256) void k_qkv(
    const u16* __restrict__ WbI, const u16* __restrict__ xI,
    const float* __restrict__ TB,
    u16* __restrict__ qI, u16* __restrict__ kI, u16* __restrict__ vI)
{
    const int tid = threadIdx.x;
    const int L = blockIdx.x + 2 * (blockIdx.y + 12 * blockIdx.z);
    const int idx = L >> 3;                 // 0..191
    const int b  = (L & 7) * 8 + idx / 24;  // contiguous b-chunk per XCD
    const int r  = idx % 24;
    const int mt = r >> 1, nt = r & 1;
    v4f acc[4][4] = {};
    gemm_direct<12>(WbI + (size_t)mt * 49152,
                    xI + ((size_t)b * 2 + nt) * 49152, acc, tid);

    const int lane = tid & 63, w = tid >> 6;
    const int wm = (w & 1) * 64, wn = (w >> 1) * 64;
    const int quad = lane >> 4, l16 = lane & 15;
    #pragma unroll
    for (int i = 0; i < 4; i++) {
        #pragma unroll
        for (int j = 0; j < 4; j++) {
            int gc = mt * 128 + wm + i * 16 + quad * 4;  // global channel base
            int n  = nt * 128 + wn + j * 16 + l16;       // token (0..255)
            v4f v = acc[i][j];
            if (gc < 256) {            // q
                v4f s = *(const v4f*)&TB[gc];
                v4f t = *(const v4f*)&TB[256 + gc];
                v4u u;
                #pragma unroll
                for (int r2 = 0; r2 < 4; r2++) u[r2] = f2bf(v[r2] * s[r2] + t[r2]);
                *(v4u*)&qI[((size_t)(b * 8 + (gc >> 5)) * 256 + n) * 32 + (gc & 31)] = u;
            } else if (gc < 512) {     // k
                int c = gc - 256;
                v4f s = *(const v4f*)&TB[512 + c];
                v4f t = *(const v4f*)&TB[768 + c];
                v4u u;
                #pragma unroll
                for (int r2 = 0; r2 < 4; r2++) u[r2] = f2bf(v[r2] * s[r2] + t[r2]);
                *(v4u*)&kI[((size_t)(b * 8 + (c >> 5)) * 256 + n) * 32 + (c & 31)] = u;
            } else {                   // v -> image (row = e, col = n as k-dim)
                int c = gc - 512;      // 0..1023
                if (n < 224) {
                    int o = c >> 7, e = c & 127;
                    u16* base = vI + ((size_t)(b * 8 + o) * 7 + (n >> 5)) * 4096
                                + ((n >> 3) & 3) * 1024 + (n & 7);
                    #pragma unroll
                    for (int r2 = 0; r2 < 4; r2++) {
                        u16 outv = 0;
                        if (n < N_) outv = f2bf(v[r2] * TB[1024 + c + r2] + TB[2048 + c + r2]);
                        base[(e + r2) * 8] = outv;
                    }
                }
            }
        }
    }
}

// ---------------------------------------------------------------------------
// K2: depthwise 3x3 conv. Block = 64 channels of one (b,o).
// ---------------------------------------------------------------------------
__global__ __launch_bounds__(256) void k_dwconv(
    const u16* __restrict__ vI, const float* __restrict__ wvl,
    const float* __restrict__ TB, u16* __restrict__ vlocI)
{
    __shared__ u16 V[64 * 230];             // 29440 B
    const int tid = threadIdx.x;
    const int sub = blockIdx.x;             // 0..15: o = sub>>1, half = sub&1
    const int b   = blockIdx.y;
    const int o   = sub >> 1;
    const int e0  = (sub & 1) * 64;
    const u16* img = vI + (size_t)(b * 8 + o) * 28672;

    {
        const int quad = tid >> 6, l = tid & 63;
        #pragma unroll
        for (int i = 0; i < 7; i++) {
            v8s u = *(const v8s*)&img[i * 4096 + quad * 1024 + (e0 + l) * 8];
            const u32* ui = (const u32*)&u;
            int m0 = i * 32 + quad * 8;
            u32* dst = (u32*)&V[l * 230 + m0];
            #pragma unroll
            for (int c = 0; c < 4; c++) dst[c] = ui[c];
        }
    }
    __syncthreads();

    const int e = tid & 63, j = tid >> 6;
    const int cg = sub * 64 + e;
    const int y0 = j * 4;
    const int ny = (j == 3) ? 2 : 4;
    float wgt[9];
    #pragma unroll
    for (int k = 0; k < 9; k++) wgt[k] = wvl[cg * 9 + k];
    const float sc = TB[3840 + cg], sh = TB[4864 + cg];
    u32 po[4][7];

    for (int yi = 0; yi < ny; yi++) {
        int y = y0 + yi;
        float a[3][16];
        #pragma unroll
        for (int dy = 0; dy < 3; dy++) {
            int yy = y + dy - 1;
            a[dy][0] = 0.f; a[dy][15] = 0.f;
            if (yy < 0 || yy > 13) {
                #pragma unroll
                for (int x = 1; x < 15; x++) a[dy][x] = 0.f;
            } else {
                const u16* rp = &V[e * 230 + yy * 14];
                #pragma unroll
                for (int c4 = 0; c4 < 7; c4++) {
                    u32 u = *(const u32*)&rp[c4 * 2];
                    a[dy][1 + 2 * c4] = bf2f((u16)(u & 0xffffu));
                    a[dy][2 + 2 * c4] = bf2f((u16)(u >> 16));
                }
            }
        }
        #pragma unroll
        for (int xp = 0; xp < 7; xp++) {
            u32 pk = 0;
            #pragma unroll
            for (int half = 0; half < 2; half++) {
                int x = 2 * xp + half;
                float s = 0.f;
                #pragma unroll
                for (int dy = 0; dy < 3; dy++)
                    #pragma unroll
                    for (int kx = 0; kx < 3; kx++)
                        s += wgt[dy * 3 + kx] * a[dy][x + kx];
                u16 bv = f2bf(s * sc + sh);
                pk |= ((u32)bv) << (16 * half);
            }
            po[yi][xp] = pk;
        }
    }
    __syncthreads();

    for (int yi = 0; yi < ny; yi++) {
        u32* dst = (u32*)&V[e * 196 + (y0 + yi) * 14];
        #pragma unroll
        for (int xp = 0; xp < 7; xp++) dst[xp] = po[yi][xp];
    }
    __syncthreads();

    for (int it = 0; it < 7; it++) {
        int idx = it * 256 + tid;
        if (idx < 1568) {
            int g = idx / 196, n = idx - g * 196;
            v4u lo, hi;
            #pragma unroll
            for (int r = 0; r < 4; r++) lo[r] = V[(g * 8 + r) * 196 + n];
            #pragma unroll
            for (int r = 0; r < 4; r++) hi[r] = V[(g * 8 + 4 + r) * 196 + n];
            u16* dst = vlocI + ((size_t)(b * 2 + (n >> 7)) * 32 + sub * 2 + (g >> 2)) * 4096
                     + (g & 3) * 1024 + (n & 127) * 8;
            *(v4u*)dst = lo;
            *(v4u*)(dst + 4) = hi;
        }
    }
}

// ---------------------------------------------------------------------------
// K3: FUSED attention + AV + vloc + relu -> aoI (round-5 config: QBLK=16,
// Sl stride 200, Zf zero-fragment, V prefetch, setprio).
// XCD swizzle: 832 blocks = 8 XCDs x (8 b x 13 qt).
// ---------------------------------------------------------------------------
#define SLS 200   // Sl stride (u16 elems); %4==0 for b64/b128 alignment
__global__ __launch_bounds__(512, 6) void k_attn_av(
    const u16* __restrict__ qI, const u16* __restrict__ kI,
    const u16* __restrict__ vI,
    const float* __restrict__ th1w,
    const float* __restrict__ th2w, const float* __restrict__ th2b,
    const float* __restrict__ biasE,
    const u16* __restrict__ vlocI, u16* __restrict__ aoI)
{
    __shared__ u16 Sl[8 * 16 * SLS];   // [h][q16][m<200] = 51200 B
    __shared__ float red[128][4];
    __shared__ float invS[128];        // [h*16+q]
    __shared__ __attribute__((aligned(16))) u16 Zf[8];   // zero fragment
    const int tid = threadIdx.x;
    const int w = tid >> 6, lane = tid & 63;
    const int quad = lane >> 4, l16 = lane & 15;
    const int L = blockIdx.x + 13 * blockIdx.y;
    const int idx = L >> 3;                 // 0..103
    const int b  = (L & 7) * 8 + idx / 13;  // contiguous b-chunk per XCD
    const int qt = idx % 13;                // 0..12
    const int n0 = qt * 16;
    if (tid < 8) Zf[tid] = 0;

    // phase A: wave w -> head w. Operand-swapped MFMA: D[m_local][q16].
    {
        const int h = w;
        const u16* qb = qI + (size_t)(b * 8 + h) * 8192;
        const u16* kb = kI + (size_t)(b * 8 + h) * 8192;
        v8s qf = *(const v8s*)&qb[(n0 + l16) * 32 + quad * 8];   // B operand (cols)
        #pragma unroll
        for (int mt = 0; mt < 13; mt++) {
            v8s kf = *(const v8s*)&kb[(mt * 16 + l16) * 32 + quad * 8]; // A operand (rows)
            v4f acc = {};
            acc = __builtin_amdgcn_mfma_f32_16x16x32_bf16(kf, qf, acc, 0, 0, 0);
            if (mt < 12 || quad < 2) {
                v4u pk;
                #pragma unroll
                for (int r = 0; r < 4; r++) pk[r] = f2h(acc[r]);
                *(v4u*)&Sl[(h * 16 + l16) * SLS + mt * 16 + quad * 4] = pk;
            }
        }
    }
    __syncthreads();

    // phase B1: thread owns (m-pair, q-quad); all LDS traffic u32, biasE float2
    const int mp  = (tid & 127) * 2;   // 0,2,...,254
    const int qh  = tid >> 7;          // 0..3 -> q = qh*4 + qq
    const bool pvalid = (mp < N_);
    for (int qq = 0; qq < 4; qq++) {
        int q = qh * 4 + qq;
        int n = n0 + q;
        if (pvalid && n < N_) {
            const float* bE = biasE + (size_t)n * 1568 + mp;
            float S0[8], S1[8];
            #pragma unroll
            for (int h = 0; h < 8; h++) {
                u32 u = *(const u32*)&Sl[(h * 16 + q) * SLS + mp];
                S0[h] = h2f((u16)(u & 0xffffu));
                S1[h] = h2f((u16)(u >> 16));
            }
            u32 ew[8];
            #pragma unroll
            for (int o = 0; o < 8; o++) {
                float2 bb = *(const float2*)&bE[o * 196];
                float a0 = bb.x, a1 = bb.y;
                #pragma unroll
                for (int h = 0; h < 8; h++) {
                    a0 += th1w[o * 8 + h] * S0[h];
                    a1 += th1w[o * 8 + h] * S1[h];
                }
                ew[o] = (u32)f2h(__expf(a0)) | ((u32)f2h(__expf(a1)) << 16);
            }
            #pragma unroll
            for (int o = 0; o < 8; o++)
                *(u32*)&Sl[(o * 16 + q) * SLS + mp] = ew[o];
        }
    }
    __syncthreads();

    // phase B2: 128 rows x 4 quarters; vectorized u32 LDS reads (m < 196)
    {
        int r = tid >> 2, quarter = tid & 3;
        int mstart = quarter * 48;
        int cnt = (quarter == 3) ? 26 : 24;
        const u16* rowp = &Sl[r * SLS + mstart];
        float s = 0.f;
        for (int i = 0; i < cnt; i++) {
            u32 u = *(const u32*)&rowp[i * 2];
            s += h2f((u16)(u & 0xffffu)) + h2f((u16)(u >> 16));
        }
        red[r][quarter] = s;
    }
    __syncthreads();
    if (tid < 128)
        invS[tid] = 1.f / (red[tid][0] + red[tid][1] + red[tid][2] + red[tid][3]);
    __syncthreads();

    // phase B3: scale + TH2 in place (bf16); m-pair u32 traffic; zero m<200
    for (int qq = 0; qq < 4; qq++) {
        int q = qh * 4 + qq;
        bool valid = pvalid && (n0 + q < N_);
        u32 pw[8];
        if (valid) {
            float s0[8], s1[8];
            #pragma unroll
            for (int h = 0; h < 8; h++) {
                u32 u = *(const u32*)&Sl[(h * 16 + q) * SLS + mp];
                float is = invS[h * 16 + q];
                s0[h] = h2f((u16)(u & 0xffffu)) * is;
                s1[h] = h2f((u16)(u >> 16)) * is;
            }
            #pragma unroll
            for (int o = 0; o < 8; o++) {
                float v0 = th2b[o], v1 = th2b[o];
                #pragma unroll
                for (int h = 0; h < 8; h++) {
                    v0 += th2w[o * 8 + h] * s0[h];
                    v1 += th2w[o * 8 + h] * s1[h];
                }
                pw[o] = (u32)f2bf(v0) | ((u32)f2bf(v1) << 16);
            }
        } else {
            #pragma unroll
            for (int o = 0; o < 8; o++) pw[o] = 0;
        }
        if (mp < SLS) {
            #pragma unroll
            for (int o = 0; o < 8; o++)
                *(u32*)&Sl[(o * 16 + q) * SLS + mp] = pw[o];
        }
    }

    // pre-issue phase C's first V fragments (pure global, no LDS dependency)
    const int o = w;
    const u16* vb = vI + (size_t)(b * 8 + o) * 28672;
    v8s a0pre[4];
    {
        const u16* ab00 = vb + quad * 1024 + l16 * 8;   // eh=0 base
        #pragma unroll
        for (int e = 0; e < 4; e++) a0pre[e] = *(const v8s*)(ab00 + e * 128);
    }
    __syncthreads();

    // phase C: AV. Wave w handles o = w; all 16 output columns live.
    {
        const int half_ = n0 >> 7;
        const int row0 = n0 & 127;
        const int n = n0 + l16;
        const bool act = (n < N_);
        const u16* prow = &Sl[(o * 16 + l16) * SLS];
        __builtin_amdgcn_s_setprio(1);
        #pragma unroll
        for (int eh = 0; eh < 2; eh++) {       // 2 e-halves of 64
            v4f acc[4] = {};
            v8s a[2][4];
            const u16* ab0 = vb + quad * 1024 + (eh * 64 + l16) * 8;
            if (eh == 0) {
                #pragma unroll
                for (int e = 0; e < 4; e++) a[0][e] = a0pre[e];
            } else {
                #pragma unroll
                for (int e = 0; e < 4; e++) a[0][e] = *(const v8s*)(ab0 + e * 128);
            }
            #pragma unroll
            for (int ks = 0; ks < 7; ks++) {
                const int cur = ks & 1, nxt = cur ^ 1;
                if (ks < 6) {
                    const u16* an = ab0 + (size_t)(ks + 1) * 4096;
                    #pragma unroll
                    for (int e = 0; e < 4; e++) a[nxt][e] = *(const v8s*)(an + e * 128);
                }
                const u16* psrc = (ks == 6 && quad != 0) ? &Zf[0]
                                                         : &prow[ks * 32 + quad * 8];
                v8s bfr = *(const v8s*)psrc;
                #pragma unroll
                for (int e = 0; e < 4; e++)
                    acc[e] = __builtin_amdgcn_mfma_f32_16x16x32_bf16(a[cur][e], bfr, acc[e], 0, 0, 0);
            }
            if (act) {
                #pragma unroll
                for (int e = 0; e < 4; e++) {
                    const int c0 = o * 128 + (eh * 4 + e) * 16 + quad * 4;
                    const size_t ioff = ((size_t)(b * 2 + half_) * 32 + (c0 >> 5)) * 4096
                                      + ((c0 >> 3) & 3) * 1024 + (size_t)(row0 + l16) * 8 + (c0 & 7);
                    v4u lv = *(const v4u*)&vlocI[ioff];
                    v4u u;
                    #pragma unroll
                    for (int r = 0; r < 4; r++)
                        u[r] = f2bf(fmaxf(acc[e][r] + bf2f(lv[r]), 0.f));
                    *(v4u*)&aoI[ioff] = u;
                }
            }
        }
        __builtin_amdgcn_s_setprio(0);
    }
}

// ---------------------------------------------------------------------------
// K6: projection GEMM (3-deep, 128x64 tile, K=1024) + BN -> out fp32.
// 768 blocks = 3/CU (was 384 = 1.5/CU, half the machine idle in round 2).
// XCD swizzle: 768 blocks = 8 XCDs x (8 b x 12 tiles).
// ---------------------------------------------------------------------------
__global__ __launch_bounds__(256) void k_proj(
    const u16* __restrict__ WpI, const u16* __restrict__ aoI,
    const float* __restrict__ TB, float* __restrict__ out)
{
    const int tid = threadIdx.x;
    const int L = blockIdx.x + 4 * (blockIdx.y + 3 * blockIdx.z);
    const int idx = L >> 3;                 // 0..95
    const int b  = (L & 7) * 8 + idx / 12;  // contiguous b-chunk per XCD
    const int r  = idx % 12;
    const int mt = r >> 2, ntq = r & 3;     // mt 0..2, ntq 0..3 (64-col tiles)
    v4f acc[4][2] = {};
    gemm_direct3_n64<32>(WpI + (size_t)mt * 131072,
                         aoI + ((size_t)b * 2 + (ntq >> 1)) * 131072 + (ntq & 1) * 512,
                         acc, tid);

    const int lane = tid & 63, w = tid >> 6;
    const int wm = (w & 1) * 64, wn = (w >> 1) * 32;
    const int quad = lane >> 4, l16 = lane & 15;
    #pragma unroll
    for (int i = 0; i < 4; i++) {
        #pragma unroll
        for (int j = 0; j < 2; j++) {
            int p0 = mt * 128 + wm + i * 16 + quad * 4;
            int n  = ntq * 64 + wn + j * 16 + l16;
            if (n < N_) {
                v4f s = *(const v4f*)&TB[3072 + p0];
                v4f t = *(const v4f*)&TB[3456 + p0];
                #pragma unroll
                for (int r2 = 0; r2 < 4; r2++)
                    out[((size_t)b * DIM_ + p0 + r2) * N_ + n] = acc[i][j][r2] * s[r2] + t[r2];
            }
        }
    }
}

// ---------------------------------------------------------------------------
extern "C" void kernel_launch(void* const* d_in, const int* in_sizes, int n_in,
                              void* d_out, int out_size, void* d_ws, size_t ws_size,
                              hipStream_t stream)
{
    const float* x    = (const float*)d_in[0];
    const float* wq   = (const float*)d_in[1];
    const float* bq   = (const float*)d_in[2];
    const float* bnq  = (const float*)d_in[3];
    const float* wk   = (const float*)d_in[4];
    const float* bk   = (const float*)d_in[5];
    const float* bnk  = (const float*)d_in[6];
    const float* wv   = (const float*)d_in[7];
    const float* bv   = (const float*)d_in[8];
    const float* bnv  = (const float*)d_in[9];
    const float* wvl  = (const float*)d_in[10];
    const float* bvl  = (const float*)d_in[11];
    const float* bnvl = (const float*)d_in[12];
    const float* th1w = (const float*)d_in[13];
    const float* th1b = (const float*)d_in[14];
    const float* th2w = (const float*)d_in[15];
    const float* th2b = (const float*)d_in[16];
    const float* wp   = (const float*)d_in[17];
    const float* bp   = (const float*)d_in[18];
    const float* bnp  = (const float*)d_in[19];
    const float* ab   = (const float*)d_in[20];
    const int*   bidx = (const int*)d_in[21];
    float* out = (float*)d_out;

    u16* wsb  = (u16*)d_ws;
    u16* WbI  = wsb + WBI_OFF;
    u16* WpI  = wsb + WPI_OFF;
    u16* qI   = wsb + QI_OFF;
    u16* kI   = wsb + KI_OFF;
    u16* vI   = wsb + VI_OFF;
    u16* vlocI = wsb + VLOC_U16;
    u16* xI   = wsb + TAIL_OFF;   // aliased: xI -> aoI (disjoint lifetimes)
    u16* aoI  = wsb + TAIL_OFF;
    float* TB    = (float*)(wsb + TB_OFF);
    float* biasE = (float*)(wsb + BIASE_OFF);

    k_pre<<<dim3(3916), 256, 0, stream>>>(x, wq, wk, wv, wp, ab, th1w, th1b,
                                          bq, bnq, bk, bnk, bv, bnv, bp, bnp, bvl, bnvl,
                                          bidx, xI, WbI, WpI, TB, biasE);
    k_qkv<<<dim3(2, 12, B_), 256, 0, stream>>>(WbI, xI, TB, qI, kI, vI);
    k_dwconv<<<dim3(16, B_), 256, 0, stream>>>(vI, wvl, TB, vlocI);
    k_attn_av<<<dim3(13, B_), 512, 0, stream>>>(qI, kI, vI, th1w, th2w, th2b,
                                                biasE, vlocI, aoI);
    k_proj<<<dim3(4, 3, B_), 256, 0, stream>>>(WpI, aoI, TB, out);
}

// Round 10
// 242.590 us; speedup vs baseline: 1.0997x; 1.0481x over previous
//
#include <hip/hip_runtime.h>

#define B_     64
#define DIM_   384
#define RES_   14
#define N_     196
#define HEADS_ 8
#define KD_    32
#define D_     128
#define DH_    1024
#define QK_    256
#define CH_    1536
#define EPS_   1e-5f
#define SCALE_ 0.17677669529663687f   // 32^-0.5

typedef unsigned short u16;
typedef unsigned int u32;
typedef short v8s __attribute__((ext_vector_type(8)));
typedef float v4f __attribute__((ext_vector_type(4)));
typedef u16  v4u __attribute__((ext_vector_type(4)));
typedef u16  v8u __attribute__((ext_vector_type(8)));

static __device__ __forceinline__ u16 f2bf(float f) {
    unsigned int u = __builtin_bit_cast(unsigned int, f);
    u = (u + 0x7fffu + ((u >> 16) & 1u)) >> 16;
    return (u16)u;
}
static __device__ __forceinline__ float bf2f(u16 u) {
    unsigned int x = ((unsigned int)u) << 16;
    return __builtin_bit_cast(float, x);
}
static __device__ __forceinline__ u16 f2h(float f) {
    _Float16 h = (_Float16)f;
    return __builtin_bit_cast(u16, h);
}
static __device__ __forceinline__ float h2f(u16 u) {
    return (float)__builtin_bit_cast(_Float16, u);
}

// workspace layout (u16 element offsets)
// GEMM operand images: [kstep][kquad(4)][row(128)][8] = 4096 elems (8KB)/kstep
#define WBI_OFF  0u          // Wb  image: 12 mtiles x 12 ksteps      (589824)
#define WPI_OFF  589824u     // wp  image: 3 mtiles x 32 ksteps       (393216)
#define QI_OFF   983040u     // qT  [B][8][256][32]                   (4194304)
#define KI_OFF   5177344u    // kT  [B][8][256][32]                   (4194304)
#define VI_OFF   9371648u    // v   image: [B][8] x 7 ksteps          (14680064)
#define VLOC_U16 53411840u   // vlocI in aoI image layout             (16777216)
#define TAIL_OFF 79101952u   // union: xI (6291456) / aoI (16777216)
#define TB_OFF   98770944u   // BN tables fp32[5888]
#define BIASE_OFF 98785920u  // biasE [196][8][196] fp32 (614656 u16)

// ---------------------------------------------------------------------------
// barrier-free direct-from-global 128x128 MFMA core.
// ---------------------------------------------------------------------------
template<int KSTEPS>
static __device__ __forceinline__ void gemm_direct(
    const u16* __restrict__ Ag, const u16* __restrict__ Bg,
    v4f acc[4][4], int tid)
{
    const int lane = tid & 63, w = tid >> 6;
    const int wm = (w & 1) * 64, wn = (w >> 1) * 64;
    const int quad = lane >> 4, l16 = lane & 15;
    const u16* pa = Ag + quad * 1024 + (wm + l16) * 8;
    const u16* pb = Bg + quad * 1024 + (wn + l16) * 8;
    v8s a[2][4], b[2][4];
    #pragma unroll
    for (int i = 0; i < 4; i++) {
        a[0][i] = *(const v8s*)(pa + i * 128);
        b[0][i] = *(const v8s*)(pb + i * 128);
    }
    #pragma unroll
    for (int ks = 0; ks < KSTEPS; ks++) {
        const int cur = ks & 1, nxt = cur ^ 1;
        if (ks + 1 < KSTEPS) {
            const u16* qa = pa + (size_t)(ks + 1) * 4096;
            const u16* qb = pb + (size_t)(ks + 1) * 4096;
            #pragma unroll
            for (int i = 0; i < 4; i++) {
                a[nxt][i] = *(const v8s*)(qa + i * 128);
                b[nxt][i] = *(const v8s*)(qb + i * 128);
            }
        }
        #pragma unroll
        for (int i = 0; i < 4; i++)
            #pragma unroll
            for (int j = 0; j < 4; j++)
                acc[i][j] = __builtin_amdgcn_mfma_f32_16x16x32_bf16(a[cur][i], b[cur][j], acc[i][j], 0, 0, 0);
    }
}

// 3-deep variant for long-K latency-exposed GEMMs (k_proj: K=32 steps).
template<int KSTEPS>
static __device__ __forceinline__ void gemm_direct3(
    const u16* __restrict__ Ag, const u16* __restrict__ Bg,
    v4f acc[4][4], int tid)
{
    const int lane = tid & 63, w = tid >> 6;
    const int wm = (w & 1) * 64, wn = (w >> 1) * 64;
    const int quad = lane >> 4, l16 = lane & 15;
    const u16* pa = Ag + quad * 1024 + (wm + l16) * 8;
    const u16* pb = Bg + quad * 1024 + (wn + l16) * 8;
    v8s a[3][4], b[3][4];
    #pragma unroll
    for (int s = 0; s < 2; s++) {
        #pragma unroll
        for (int i = 0; i < 4; i++) {
            a[s][i] = *(const v8s*)(pa + (size_t)s * 4096 + i * 128);
            b[s][i] = *(const v8s*)(pb + (size_t)s * 4096 + i * 128);
        }
    }
    #pragma unroll
    for (int ks = 0; ks < KSTEPS; ks++) {
        const int cur = ks % 3, nxt = (ks + 2) % 3;
        if (ks + 2 < KSTEPS) {
            const u16* qa = pa + (size_t)(ks + 2) * 4096;
            const u16* qb = pb + (size_t)(ks + 2) * 4096;
            #pragma unroll
            for (int i = 0; i < 4; i++) {
                a[nxt][i] = *(const v8s*)(qa + i * 128);
                b[nxt][i] = *(const v8s*)(qb + i * 128);
            }
        }
        #pragma unroll
        for (int i = 0; i < 4; i++)
            #pragma unroll
            for (int j = 0; j < 4; j++)
                acc[i][j] = __builtin_amdgcn_mfma_f32_16x16x32_bf16(a[cur][i], b[cur][j], acc[i][j], 0, 0, 0);
    }
}

// ---------------------------------------------------------------------------
// k_pre: ALL preprocessing in one launch (round-5 version).
// ---------------------------------------------------------------------------
__global__ __launch_bounds__(256) void k_pre(
    const float* __restrict__ x,
    const float* __restrict__ wq, const float* __restrict__ wk,
    const float* __restrict__ wv, const float* __restrict__ wp,
    const float* __restrict__ ab,
    const float* __restrict__ th1w, const float* __restrict__ th1b,
    const float* __restrict__ bq, const float* __restrict__ bnq,
    const float* __restrict__ bk, const float* __restrict__ bnk,
    const float* __restrict__ bv, const float* __restrict__ bnv,
    const float* __restrict__ bp, const float* __restrict__ bnp,
    const float* __restrict__ bvl, const float* __restrict__ bnvl,
    const int* __restrict__ bidx,
    u16* __restrict__ xI, u16* __restrict__ WbI, u16* __restrict__ WpI,
    float* __restrict__ TB, float* __restrict__ biasE)
{
    __shared__ float T[64][65];
    const int tid = threadIdx.x;
    if (blockIdx.x < 1536) {      // ---- castX ----
        const int t  = blockIdx.x;
        const int n0 = (t & 3) * 64;
        const int k0 = ((t >> 2) % 6) * 64;
        const int b  = t / 24;
        const int c = tid & 63, r4 = tid >> 6;
        #pragma unroll
        for (int i = 0; i < 16; i++) {
            int kr = i * 4 + r4;
            int gn = n0 + c;
            T[kr][c] = (gn < N_) ? x[((size_t)b * DIM_ + k0 + kr) * N_ + gn] : 0.f;
        }
        __syncthreads();
        #pragma unroll
        for (int it = 0; it < 16; it++) {
            int j = it * 256 + tid;
            int kk = j & 63, nn = j >> 6;
            int k = k0 + kk, n = n0 + nn;
            xI[(size_t)b * 98304 + (n >> 7) * 49152 + (k >> 5) * 4096
               + ((k >> 3) & 3) * 1024 + (n & 127) * 8 + (k & 7)] = f2bf(T[kk][nn]);
        }
        return;
    }
    int i = (blockIdx.x - 1536) * 256 + tid;
    if (i < 589824) {           // qkv weight image
        int mt = i / 49152, rem = i % 49152;
        int ks = rem >> 12, r2 = rem & 4095;
        int q = r2 >> 10, row = (r2 >> 3) & 127, e = r2 & 7;
        int c = mt * 128 + row, k = ks * 32 + q * 8 + e;
        float v = (c < 256) ? wq[c * 384 + k]
                : (c < 512) ? wk[(c - 256) * 384 + k]
                            : wv[(size_t)(c - 512) * 384 + k];
        WbI[i] = f2bf(v);
    } else if (i < 983040) {    // proj weight image
        int j = i - 589824;
        int mt = j >> 17, rem = j & 131071;
        int ks = rem >> 12, r2 = rem & 4095;
        int q = r2 >> 10, row = (r2 >> 3) & 127, e = r2 & 7;
        int p = mt * 128 + row, k = ks * 32 + q * 8 + e;
        WpI[j] = f2bf(wp[(size_t)p * 1024 + k]);
    } else if (i < 985984) {    // BN tables
        int j = i - 983040;
        if (j < 256) {
            int c = j;
            float s = bnq[c] * rsqrtf(bnq[768 + c] + EPS_);
            float t = (bq[c] - bnq[512 + c]) * s + bnq[256 + c];
            TB[c] = s * SCALE_; TB[256 + c] = t * SCALE_;
        } else if (j < 512) {
            int c = j - 256;
            float s = bnk[c] * rsqrtf(bnk[768 + c] + EPS_);
            float t = (bk[c] - bnk[512 + c]) * s + bnk[256 + c];
            TB[512 + c] = s; TB[768 + c] = t;
        } else if (j < 1536) {
            int c = j - 512;
            float s = bnv[c] * rsqrtf(bnv[3072 + c] + EPS_);
            float t = (bv[c] - bnv[2048 + c]) * s + bnv[1024 + c];
            TB[1024 + c] = s; TB[2048 + c] = t;
        } else if (j < 1920) {
            int c = j - 1536;
            float s = bnp[c] * rsqrtf(bnp[1152 + c] + EPS_);
            float t = (bp[c] - bnp[768 + c]) * s + bnp[384 + c];
            TB[3072 + c] = s; TB[3456 + c] = t;
        } else {
            int c = j - 1920;
            float s = bnvl[c] * rsqrtf(bnvl[3072 + c] + EPS_);
            float t = (bvl[c] - bnvl[2048 + c]) * s + bnvl[1024 + c];
            TB[3840 + c] = s; TB[4864 + c] = t;
        }
    } else if (i < 1293312) {   // biasE[n][o][m] = th1-folded bias - 5
        int j = i - 985984;
        int m = j % N_;
        int t = j / N_;
        int o = t & 7;
        int n = t >> 3;
        int idx = bidx[n * N_ + m];
        float a = th1b[o];
        #pragma unroll
        for (int h = 0; h < 8; h++) a += th1w[o * 8 + h] * ab[h * N_ + idx];
        biasE[j] = a - 5.f;
    }
}

// ---------------------------------------------------------------------------
// K1: QKV GEMM (direct core). NEW v-epilogue: per-wave LDS transpose so the
// vI image is written as 16B coalesced chunks (was: 64 scalar 2B scattered
// stores per thread on the largest intermediate tensor, 29.4 MB).
// XCD swizzle: 1536 blocks = 8 XCDs x (8 b x 24 tiles).
// ---------------------------------------------------------------------------
__global__ __launch_bounds__(256) void k_qkv(
    const u16* __restrict__ WbI, const u16* __restrict__ xI,
    const float* __restrict__ TB,
    u16* __restrict__ qI, u16* __restrict__ kI, u16* __restrict__ vI)
{
    __shared__ u16 S[4][64][20];   // per-wave [tok64][ch16 pad20] = 10240 B
    const int tid = threadIdx.x;
    const int L = blockIdx.x + 2 * (blockIdx.y + 12 * blockIdx.z);
    const int idx = L >> 3;                 // 0..191
    const int b  = (L & 7) * 8 + idx / 24;  // contiguous b-chunk per XCD
    const int r  = idx % 24;
    const int mt = r >> 1, nt = r & 1;
    v4f acc[4][4] = {};
    gemm_direct<12>(WbI + (size_t)mt * 49152,
                    xI + ((size_t)b * 2 + nt) * 49152, acc, tid);

    const int lane = tid & 63, w = tid >> 6;
    const int wm = (w & 1) * 64, wn = (w >> 1) * 64;
    const int quad = lane >> 4, l16 = lane & 15;

    if (mt < 4) {                 // ---- q / k epilogue (unchanged) ----
        #pragma unroll
        for (int i = 0; i < 4; i++) {
            #pragma unroll
            for (int j = 0; j < 4; j++) {
                int gc = mt * 128 + wm + i * 16 + quad * 4;
                int n  = nt * 128 + wn + j * 16 + l16;
                v4f v = acc[i][j];
                if (gc < 256) {            // q
                    v4f s = *(const v4f*)&TB[gc];
                    v4f t = *(const v4f*)&TB[256 + gc];
                    v4u u;
                    #pragma unroll
                    for (int r2 = 0; r2 < 4; r2++) u[r2] = f2bf(v[r2] * s[r2] + t[r2]);
                    *(v4u*)&qI[((size_t)(b * 8 + (gc >> 5)) * 256 + n) * 32 + (gc & 31)] = u;
                } else {                   // k
                    int c = gc - 256;
                    v4f s = *(const v4f*)&TB[512 + c];
                    v4f t = *(const v4f*)&TB[768 + c];
                    v4u u;
                    #pragma unroll
                    for (int r2 = 0; r2 < 4; r2++) u[r2] = f2bf(v[r2] * s[r2] + t[r2]);
                    *(v4u*)&kI[((size_t)(b * 8 + (c >> 5)) * 256 + n) * 32 + (c & 31)] = u;
                }
            }
        }
    } else {                      // ---- v epilogue: LDS transpose ----
        const int o = mt - 4;
        u16* vbase = vI + (size_t)(b * 8 + o) * 28672;
        const int ntBase = nt * 128;
        #pragma unroll
        for (int i = 0; i < 4; i++) {
            const int e0 = wm + i * 16;                  // 16-channel group base
            const int cg = o * 128 + e0 + quad * 4;      // global v channel
            v4f s = *(const v4f*)&TB[1024 + cg];
            v4f t = *(const v4f*)&TB[2048 + cg];
            // stage: lane (quad,l16) -> S[w][tok][quad*4..+3], zeros for n>=196
            #pragma unroll
            for (int j = 0; j < 4; j++) {
                int n = ntBase + wn + j * 16 + l16;
                v4u u = {0, 0, 0, 0};
                if (n < N_) {
                    v4f v = acc[i][j];
                    #pragma unroll
                    for (int r2 = 0; r2 < 4; r2++) u[r2] = f2bf(v[r2] * s[r2] + t[r2]);
                }
                *(v4u*)&S[w][j * 16 + l16][quad * 4] = u;
            }
            asm volatile("s_waitcnt lgkmcnt(0)" ::: "memory");
            // read out (ch, 8-tok) chunks -> 16B coalesced image stores
            #pragma unroll
            for (int half = 0; half < 2; half++) {
                int c = half * 64 + lane;        // chunk 0..127
                int ch = c >> 3, t0 = (c & 7) * 8;
                int n0 = ntBase + wn + t0;
                if (n0 < 224) {
                    v8u val;
                    #pragma unroll
                    for (int k = 0; k < 8; k++) val[k] = S[w][t0 + k][ch];
                    *(v8u*)&vbase[(size_t)(n0 >> 5) * 4096 + ((n0 >> 3) & 3) * 1024
                                  + (size_t)(e0 + ch) * 8] = val;
                }
            }
            asm volatile("s_waitcnt lgkmcnt(0)" ::: "memory");   // WAR vs next i
        }
    }
}

// ---------------------------------------------------------------------------
// K2: depthwise 3x3 conv. Block = 64 channels of one (b,o).
// ---------------------------------------------------------------------------
__global__ __launch_bounds__(256) void k_dwconv(
    const u16* __restrict__ vI, const float* __restrict__ wvl,
    const float* __restrict__ TB, u16* __restrict__ vlocI)
{
    __shared__ u16 V[64 * 230];             // 29440 B
    const int tid = threadIdx.x;
    const int sub = blockIdx.x;             // 0..15: o = sub>>1, half = sub&1
    const int b   = blockIdx.y;
    const int o   = sub >> 1;
    const int e0  = (sub & 1) * 64;
    const u16* img = vI + (size_t)(b * 8 + o) * 28672;

    {
        const int quad = tid >> 6, l = tid & 63;
        #pragma unroll
        for (int i = 0; i < 7; i++) {
            v8s u = *(const v8s*)&img[i * 4096 + quad * 1024 + (e0 + l) * 8];
            const u32* ui = (const u32*)&u;
            int m0 = i * 32 + quad * 8;
            u32* dst = (u32*)&V[l * 230 + m0];
            #pragma unroll
            for (int c = 0; c < 4; c++) dst[c] = ui[c];
        }
    }
    __syncthreads();

    const int e = tid & 63, j = tid >> 6;
    const int cg = sub * 64 + e;
    const int y0 = j * 4;
    const int ny = (j == 3) ? 2 : 4;
    float wgt[9];
    #pragma unroll
    for (int k = 0; k < 9; k++) wgt[k] = wvl[cg * 9 + k];
    const float sc = TB[3840 + cg], sh = TB[4864 + cg];
    u32 po[4][7];

    for (int yi = 0; yi < ny; yi++) {
        int y = y0 + yi;
        float a[3][16];
        #pragma unroll
        for (int dy = 0; dy < 3; dy++) {
            int yy = y + dy - 1;
            a[dy][0] = 0.f; a[dy][15] = 0.f;
            if (yy < 0 || yy > 13) {
                #pragma unroll
                for (int x = 1; x < 15; x++) a[dy][x] = 0.f;
            } else {
                const u16* rp = &V[e * 230 + yy * 14];
                #pragma unroll
                for (int c4 = 0; c4 < 7; c4++) {
                    u32 u = *(const u32*)&rp[c4 * 2];
                    a[dy][1 + 2 * c4] = bf2f((u16)(u & 0xffffu));
                    a[dy][2 + 2 * c4] = bf2f((u16)(u >> 16));
                }
            }
        }
        #pragma unroll
        for (int xp = 0; xp < 7; xp++) {
            u32 pk = 0;
            #pragma unroll
            for (int half = 0; half < 2; half++) {
                int x = 2 * xp + half;
                float s = 0.f;
                #pragma unroll
                for (int dy = 0; dy < 3; dy++)
                    #pragma unroll
                    for (int kx = 0; kx < 3; kx++)
                        s += wgt[dy * 3 + kx] * a[dy][x + kx];
                u16 bv = f2bf(s * sc + sh);
                pk |= ((u32)bv) << (16 * half);
            }
            po[yi][xp] = pk;
        }
    }
    __syncthreads();

    for (int yi = 0; yi < ny; yi++) {
        u32* dst = (u32*)&V[e * 196 + (y0 + yi) * 14];
        #pragma unroll
        for (int xp = 0; xp < 7; xp++) dst[xp] = po[yi][xp];
    }
    __syncthreads();

    for (int it = 0; it < 7; it++) {
        int idx = it * 256 + tid;
        if (idx < 1568) {
            int g = idx / 196, n = idx - g * 196;
            v4u lo, hi;
            #pragma unroll
            for (int r = 0; r < 4; r++) lo[r] = V[(g * 8 + r) * 196 + n];
            #pragma unroll
            for (int r = 0; r < 4; r++) hi[r] = V[(g * 8 + 4 + r) * 196 + n];
            u16* dst = vlocI + ((size_t)(b * 2 + (n >> 7)) * 32 + sub * 2 + (g >> 2)) * 4096
                     + (g & 3) * 1024 + (n & 127) * 8;
            *(v4u*)dst = lo;
            *(v4u*)(dst + 4) = hi;
        }
    }
}

// ---------------------------------------------------------------------------
// K3: FUSED attention + AV + vloc + relu -> aoI (round-5 config: QBLK=16,
// Sl stride 200, Zf zero-fragment, V prefetch, setprio).
// XCD swizzle: 832 blocks = 8 XCDs x (8 b x 13 qt).
// ---------------------------------------------------------------------------
#define SLS 200   // Sl stride (u16 elems); %4==0 for b64/b128 alignment
__global__ __launch_bounds__(512, 6) void k_attn_av(
    const u16* __restrict__ qI, const u16* __restrict__ kI,
    const u16* __restrict__ vI,
    const float* __restrict__ th1w,
    const float* __restrict__ th2w, const float* __restrict__ th2b,
    const float* __restrict__ biasE,
    const u16* __restrict__ vlocI, u16* __restrict__ aoI)
{
    __shared__ u16 Sl[8 * 16 * SLS];   // [h][q16][m<200] = 51200 B
    __shared__ float red[128][4];
    __shared__ float invS[128];        // [h*16+q]
    __shared__ __attribute__((aligned(16))) u16 Zf[8];   // zero fragment
    const int tid = threadIdx.x;
    const int w = tid >> 6, lane = tid & 63;
    const int quad = lane >> 4, l16 = lane & 15;
    const int L = blockIdx.x + 13 * blockIdx.y;
    const int idx = L >> 3;                 // 0..103
    const int b  = (L & 7) * 8 + idx / 13;  // contiguous b-chunk per XCD
    const int qt = idx % 13;                // 0..12
    const int n0 = qt * 16;
    if (tid < 8) Zf[tid] = 0;

    // phase A: wave w -> head w. Operand-swapped MFMA: D[m_local][q16].
    {
        const int h = w;
        const u16* qb = qI + (size_t)(b * 8 + h) * 8192;
        const u16* kb = kI + (size_t)(b * 8 + h) * 8192;
        v8s qf = *(const v8s*)&qb[(n0 + l16) * 32 + quad * 8];   // B operand (cols)
        #pragma unroll
        for (int mt = 0; mt < 13; mt++) {
            v8s kf = *(const v8s*)&kb[(mt * 16 + l16) * 32 + quad * 8]; // A operand (rows)
            v4f acc = {};
            acc = __builtin_amdgcn_mfma_f32_16x16x32_bf16(kf, qf, acc, 0, 0, 0);
            if (mt < 12 || quad < 2) {
                v4u pk;
                #pragma unroll
                for (int r = 0; r < 4; r++) pk[r] = f2h(acc[r]);
                *(v4u*)&Sl[(h * 16 + l16) * SLS + mt * 16 + quad * 4] = pk;
            }
        }
    }
    __syncthreads();

    // phase B1: thread owns (m-pair, q-quad); all LDS traffic u32, biasE float2
    const int mp  = (tid & 127) * 2;   // 0,2,...,254
    const int qh  = tid >> 7;          // 0..3 -> q = qh*4 + qq
    const bool pvalid = (mp < N_);
    for (int qq = 0; qq < 4; qq++) {
        int q = qh * 4 + qq;
        int n = n0 + q;
        if (pvalid && n < N_) {
            const float* bE = biasE + (size_t)n * 1568 + mp;
            float S0[8], S1[8];
            #pragma unroll
            for (int h = 0; h < 8; h++) {
                u32 u = *(const u32*)&Sl[(h * 16 + q) * SLS + mp];
                S0[h] = h2f((u16)(u & 0xffffu));
                S1[h] = h2f((u16)(u >> 16));
            }
            u32 ew[8];
            #pragma unroll
            for (int o = 0; o < 8; o++) {
                float2 bb = *(const float2*)&bE[o * 196];
                float a0 = bb.x, a1 = bb.y;
                #pragma unroll
                for (int h = 0; h < 8; h++) {
                    a0 += th1w[o * 8 + h] * S0[h];
                    a1 += th1w[o * 8 + h] * S1[h];
                }
                ew[o] = (u32)f2h(__expf(a0)) | ((u32)f2h(__expf(a1)) << 16);
            }
            #pragma unroll
            for (int o = 0; o < 8; o++)
                *(u32*)&Sl[(o * 16 + q) * SLS + mp] = ew[o];
        }
    }
    __syncthreads();

    // phase B2: 128 rows x 4 quarters; vectorized u32 LDS reads (m < 196)
    {
        int r = tid >> 2, quarter = tid & 3;
        int mstart = quarter * 48;
        int cnt = (quarter == 3) ? 26 : 24;
        const u16* rowp = &Sl[r * SLS + mstart];
        float s = 0.f;
        for (int i = 0; i < cnt; i++) {
            u32 u = *(const u32*)&rowp[i * 2];
            s += h2f((u16)(u & 0xffffu)) + h2f((u16)(u >> 16));
        }
        red[r][quarter] = s;
    }
    __syncthreads();
    if (tid < 128)
        invS[tid] = 1.f / (red[tid][0] + red[tid][1] + red[tid][2] + red[tid][3]);
    __syncthreads();

    // phase B3: scale + TH2 in place (bf16); m-pair u32 traffic; zero m<200
    for (int qq = 0; qq < 4; qq++) {
        int q = qh * 4 + qq;
        bool valid = pvalid && (n0 + q < N_);
        u32 pw[8];
        if (valid) {
            float s0[8], s1[8];
            #pragma unroll
            for (int h = 0; h < 8; h++) {
                u32 u = *(const u32*)&Sl[(h * 16 + q) * SLS + mp];
                float is = invS[h * 16 + q];
                s0[h] = h2f((u16)(u & 0xffffu)) * is;
                s1[h] = h2f((u16)(u >> 16)) * is;
            }
            #pragma unroll
            for (int o = 0; o < 8; o++) {
                float v0 = th2b[o], v1 = th2b[o];
                #pragma unroll
                for (int h = 0; h < 8; h++) {
                    v0 += th2w[o * 8 + h] * s0[h];
                    v1 += th2w[o * 8 + h] * s1[h];
                }
                pw[o] = (u32)f2bf(v0) | ((u32)f2bf(v1) << 16);
            }
        } else {
            #pragma unroll
            for (int o = 0; o < 8; o++) pw[o] = 0;
        }
        if (mp < SLS) {
            #pragma unroll
            for (int o = 0; o < 8; o++)
                *(u32*)&Sl[(o * 16 + q) * SLS + mp] = pw[o];
        }
    }

    // pre-issue phase C's first V fragments (pure global, no LDS dependency)
    const int o = w;
    const u16* vb = vI + (size_t)(b * 8 + o) * 28672;
    v8s a0pre[4];
    {
        const u16* ab00 = vb + quad * 1024 + l16 * 8;   // eh=0 base
        #pragma unroll
        for (int e = 0; e < 4; e++) a0pre[e] = *(const v8s*)(ab00 + e * 128);
    }
    __syncthreads();

    // phase C: AV. Wave w handles o = w; all 16 output columns live.
    {
        const int half_ = n0 >> 7;
        const int row0 = n0 & 127;
        const int n = n0 + l16;
        const bool act = (n < N_);
        const u16* prow = &Sl[(o * 16 + l16) * SLS];
        __builtin_amdgcn_s_setprio(1);
        #pragma unroll
        for (int eh = 0; eh < 2; eh++) {       // 2 e-halves of 64
            v4f acc[4] = {};
            v8s a[2][4];
            const u16* ab0 = vb + quad * 1024 + (eh * 64 + l16) * 8;
            if (eh == 0) {
                #pragma unroll
                for (int e = 0; e < 4; e++) a[0][e] = a0pre[e];
            } else {
                #pragma unroll
                for (int e = 0; e < 4; e++) a[0][e] = *(const v8s*)(ab0 + e * 128);
            }
            #pragma unroll
            for (int ks = 0; ks < 7; ks++) {
                const int cur = ks & 1, nxt = cur ^ 1;
                if (ks < 6) {
                    const u16* an = ab0 + (size_t)(ks + 1) * 4096;
                    #pragma unroll
                    for (int e = 0; e < 4; e++) a[nxt][e] = *(const v8s*)(an + e * 128);
                }
                const u16* psrc = (ks == 6 && quad != 0) ? &Zf[0]
                                                         : &prow[ks * 32 + quad * 8];
                v8s bfr = *(const v8s*)psrc;
                #pragma unroll
                for (int e = 0; e < 4; e++)
                    acc[e] = __builtin_amdgcn_mfma_f32_16x16x32_bf16(a[cur][e], bfr, acc[e], 0, 0, 0);
            }
            if (act) {
                #pragma unroll
                for (int e = 0; e < 4; e++) {
                    const int c0 = o * 128 + (eh * 4 + e) * 16 + quad * 4;
                    const size_t ioff = ((size_t)(b * 2 + half_) * 32 + (c0 >> 5)) * 4096
                                      + ((c0 >> 3) & 3) * 1024 + (size_t)(row0 + l16) * 8 + (c0 & 7);
                    v4u lv = *(const v4u*)&vlocI[ioff];
                    v4u u;
                    #pragma unroll
                    for (int r = 0; r < 4; r++)
                        u[r] = f2bf(fmaxf(acc[e][r] + bf2f(lv[r]), 0.f));
                    *(v4u*)&aoI[ioff] = u;
                }
            }
        }
        __builtin_amdgcn_s_setprio(0);
    }
}

// ---------------------------------------------------------------------------
// K6: projection GEMM (3-deep direct core, K=1024) + BN -> out fp32
// XCD swizzle: 384 blocks = 8 XCDs x (8 b x 6 tiles).
// ---------------------------------------------------------------------------
__global__ __launch_bounds__(256) void k_proj(
    const u16* __restrict__ WpI, const u16* __restrict__ aoI,
    const float* __restrict__ TB, float* __restrict__ out)
{
    const int tid = threadIdx.x;
    const int L = blockIdx.x + 2 * (blockIdx.y + 3 * blockIdx.z);
    const int idx = L >> 3;                 // 0..47
    const int b  = (L & 7) * 8 + idx / 6;   // contiguous b-chunk per XCD
    const int r  = idx % 6;
    const int mt = r >> 1, nt = r & 1;
    v4f acc[4][4] = {};
    gemm_direct3<32>(WpI + (size_t)mt * 131072,
                     aoI + ((size_t)b * 2 + nt) * 131072, acc, tid);

    const int lane = tid & 63, w = tid >> 6;
    const int wm = (w & 1) * 64, wn = (w >> 1) * 64;
    const int quad = lane >> 4, l16 = lane & 15;
    #pragma unroll
    for (int i = 0; i < 4; i++) {
        #pragma unroll
        for (int j = 0; j < 4; j++) {
            int p0 = mt * 128 + wm + i * 16 + quad * 4;
            int n  = nt * 128 + wn + j * 16 + l16;
            if (n < N_) {
                v4f s = *(const v4f*)&TB[3072 + p0];
                v4f t = *(const v4f*)&TB[3456 + p0];
                #pragma unroll
                for (int r2 = 0; r2 < 4; r2++)
                    out[((size_t)b * DIM_ + p0 + r2) * N_ + n] = acc[i][j][r2] * s[r2] + t[r2];
            }
        }
    }
}

// ---------------------------------------------------------------------------
extern "C" void kernel_launch(void* const* d_in, const int* in_sizes, int n_in,
                              void* d_out, int out_size, void* d_ws, size_t ws_size,
                              hipStream_t stream)
{
    const float* x    = (const float*)d_in[0];
    const float* wq   = (const float*)d_in[1];
    const float* bq   = (const float*)d_in[2];
    const float* bnq  = (const float*)d_in[3];
    const float* wk   = (const float*)d_in[4];
    const float* bk   = (const float*)d_in[5];
    const float* bnk  = (const float*)d_in[6];
    const float* wv   = (const float*)d_in[7];
    const float* bv   = (const float*)d_in[8];
    const float* bnv  = (const float*)d_in[9];
    const float* wvl  = (const float*)d_in[10];
    const float* bvl  = (const float*)d_in[11];
    const float* bnvl = (const float*)d_in[12];
    const float* th1w = (const float*)d_in[13];
    const float* th1b = (const float*)d_in[14];
    const float* th2w = (const float*)d_in[15];
    const float* th2b = (const float*)d_in[16];
    const float* wp   = (const float*)d_in[17];
    const float* bp   = (const float*)d_in[18];
    const float* bnp  = (const float*)d_in[19];
    const float* ab   = (const float*)d_in[20];
    const int*   bidx = (const int*)d_in[21];
    float* out = (float*)d_out;

    u16* wsb  = (u16*)d_ws;
    u16* WbI  = wsb + WBI_OFF;
    u16* WpI  = wsb + WPI_OFF;
    u16* qI   = wsb + QI_OFF;
    u16* kI   = wsb + KI_OFF;
    u16* vI   = wsb + VI_OFF;
    u16* vlocI = wsb + VLOC_U16;
    u16* xI   = wsb + TAIL_OFF;   // aliased: xI -> aoI (disjoint lifetimes)
    u16* aoI  = wsb + TAIL_OFF;
    float* TB    = (float*)(wsb + TB_OFF);
    float* biasE = (float*)(wsb + BIASE_OFF);

    k_pre<<<dim3(6588), 256, 0, stream>>>(x, wq, wk, wv, wp, ab, th1w, th1b,
                                          bq, bnq, bk, bnk, bv, bnv, bp, bnp, bvl, bnvl,
                                          bidx, xI, WbI, WpI, TB, biasE);
    k_qkv<<<dim3(2, 12, B_), 256, 0, stream>>>(WbI, xI, TB, qI, kI, vI);
    k_dwconv<<<dim3(16, B_), 256, 0, stream>>>(vI, wvl, TB, vlocI);
    k_attn_av<<<dim3(13, B_), 512, 0, stream>>>(qI, kI, vI, th1w, th2w, th2b,
                                                biasE, vlocI, aoI);
    k_proj<<<dim3(2, 3, B_), 256, 0, stream>>>(WpI, aoI, TB, out);
}

// Round 11
// 241.955 us; speedup vs baseline: 1.1026x; 1.0026x over previous
//
#include <hip/hip_runtime.h>

#define B_     64
#define DIM_   384
#define RES_   14
#define N_     196
#define HEADS_ 8
#define KD_    32
#define D_     128
#define DH_    1024
#define QK_    256
#define CH_    1536
#define EPS_   1e-5f
#define SCALE_ 0.17677669529663687f   // 32^-0.5

typedef unsigned short u16;
typedef unsigned int u32;
typedef short v8s __attribute__((ext_vector_type(8)));
typedef float v4f __attribute__((ext_vector_type(4)));
typedef u16  v4u __attribute__((ext_vector_type(4)));
typedef u16  v8u __attribute__((ext_vector_type(8)));

static __device__ __forceinline__ u16 f2bf(float f) {
    unsigned int u = __builtin_bit_cast(unsigned int, f);
    u = (u + 0x7fffu + ((u >> 16) & 1u)) >> 16;
    return (u16)u;
}
static __device__ __forceinline__ float bf2f(u16 u) {
    unsigned int x = ((unsigned int)u) << 16;
    return __builtin_bit_cast(float, x);
}
static __device__ __forceinline__ u16 f2h(float f) {
    _Float16 h = (_Float16)f;
    return __builtin_bit_cast(u16, h);
}
static __device__ __forceinline__ float h2f(u16 u) {
    return (float)__builtin_bit_cast(_Float16, u);
}

// workspace layout (u16 element offsets)
// GEMM operand images: [kstep][kquad(4)][row(128)][8] = 4096 elems (8KB)/kstep
#define WBI_OFF  0u          // Wb  image: 12 mtiles x 12 ksteps      (589824)
#define WPI_OFF  589824u     // wp  image: 3 mtiles x 32 ksteps       (393216)
#define QI_OFF   983040u     // qT  [B][8][256][32]                   (4194304)
#define KI_OFF   5177344u    // kT  [B][8][256][32]                   (4194304)
#define VI_OFF   9371648u    // v   image: [B][8] x 7 ksteps          (14680064)
#define VLOC_U16 53411840u   // vlocI in aoI image layout             (16777216)
#define TAIL_OFF 79101952u   // union: xI (6291456) / aoI (16777216)
#define TB_OFF   98770944u   // BN tables fp32[5888]
#define BIASE_OFF 98785920u  // biasE [196][8][196] fp32 (614656 u16)

// ---------------------------------------------------------------------------
// barrier-free direct-from-global 128x128 MFMA core.
// ---------------------------------------------------------------------------
template<int KSTEPS>
static __device__ __forceinline__ void gemm_direct(
    const u16* __restrict__ Ag, const u16* __restrict__ Bg,
    v4f acc[4][4], int tid)
{
    const int lane = tid & 63, w = tid >> 6;
    const int wm = (w & 1) * 64, wn = (w >> 1) * 64;
    const int quad = lane >> 4, l16 = lane & 15;
    const u16* pa = Ag + quad * 1024 + (wm + l16) * 8;
    const u16* pb = Bg + quad * 1024 + (wn + l16) * 8;
    v8s a[2][4], b[2][4];
    #pragma unroll
    for (int i = 0; i < 4; i++) {
        a[0][i] = *(const v8s*)(pa + i * 128);
        b[0][i] = *(const v8s*)(pb + i * 128);
    }
    #pragma unroll
    for (int ks = 0; ks < KSTEPS; ks++) {
        const int cur = ks & 1, nxt = cur ^ 1;
        if (ks + 1 < KSTEPS) {
            const u16* qa = pa + (size_t)(ks + 1) * 4096;
            const u16* qb = pb + (size_t)(ks + 1) * 4096;
            #pragma unroll
            for (int i = 0; i < 4; i++) {
                a[nxt][i] = *(const v8s*)(qa + i * 128);
                b[nxt][i] = *(const v8s*)(qb + i * 128);
            }
        }
        #pragma unroll
        for (int i = 0; i < 4; i++)
            #pragma unroll
            for (int j = 0; j < 4; j++)
                acc[i][j] = __builtin_amdgcn_mfma_f32_16x16x32_bf16(a[cur][i], b[cur][j], acc[i][j], 0, 0, 0);
    }
}

// 3-deep variant for long-K latency-exposed GEMMs (k_proj: K=32 steps).
template<int KSTEPS>
static __device__ __forceinline__ void gemm_direct3(
    const u16* __restrict__ Ag, const u16* __restrict__ Bg,
    v4f acc[4][4], int tid)
{
    const int lane = tid & 63, w = tid >> 6;
    const int wm = (w & 1) * 64, wn = (w >> 1) * 64;
    const int quad = lane >> 4, l16 = lane & 15;
    const u16* pa = Ag + quad * 1024 + (wm + l16) * 8;
    const u16* pb = Bg + quad * 1024 + (wn + l16) * 8;
    v8s a[3][4], b[3][4];
    #pragma unroll
    for (int s = 0; s < 2; s++) {
        #pragma unroll
        for (int i = 0; i < 4; i++) {
            a[s][i] = *(const v8s*)(pa + (size_t)s * 4096 + i * 128);
            b[s][i] = *(const v8s*)(pb + (size_t)s * 4096 + i * 128);
        }
    }
    #pragma unroll
    for (int ks = 0; ks < KSTEPS; ks++) {
        const int cur = ks % 3, nxt = (ks + 2) % 3;
        if (ks + 2 < KSTEPS) {
            const u16* qa = pa + (size_t)(ks + 2) * 4096;
            const u16* qb = pb + (size_t)(ks + 2) * 4096;
            #pragma unroll
            for (int i = 0; i < 4; i++) {
                a[nxt][i] = *(const v8s*)(qa + i * 128);
                b[nxt][i] = *(const v8s*)(qb + i * 128);
            }
        }
        #pragma unroll
        for (int i = 0; i < 4; i++)
            #pragma unroll
            for (int j = 0; j < 4; j++)
                acc[i][j] = __builtin_amdgcn_mfma_f32_16x16x32_bf16(a[cur][i], b[cur][j], acc[i][j], 0, 0, 0);
    }
}

// ---------------------------------------------------------------------------
// k_pre: ALL preprocessing in one launch. VECTORIZED STORES (the k_qkv-v
// lesson applied): castX packs 8 k-values per 16B store (was 16 scalar 2B
// stores/thread); WbI/WpI pack 8 elems with float4 source reads (was 2B/lane).
// Grid: [0,1536) castX | [1536,1824) WbI | [1824,2016) WpI
//       [2016,2028) BN | [2028,3229) biasE
// ---------------------------------------------------------------------------
__global__ __launch_bounds__(256) void k_pre(
    const float* __restrict__ x,
    const float* __restrict__ wq, const float* __restrict__ wk,
    const float* __restrict__ wv, const float* __restrict__ wp,
    const float* __restrict__ ab,
    const float* __restrict__ th1w, const float* __restrict__ th1b,
    const float* __restrict__ bq, const float* __restrict__ bnq,
    const float* __restrict__ bk, const float* __restrict__ bnk,
    const float* __restrict__ bv, const float* __restrict__ bnv,
    const float* __restrict__ bp, const float* __restrict__ bnp,
    const float* __restrict__ bvl, const float* __restrict__ bnvl,
    const int* __restrict__ bidx,
    u16* __restrict__ xI, u16* __restrict__ WbI, u16* __restrict__ WpI,
    float* __restrict__ TB, float* __restrict__ biasE)
{
    __shared__ float T[64][65];
    const int tid = threadIdx.x;
    const int t = blockIdx.x;
    if (t < 1536) {               // ---- castX (vectorized 16B image stores) ----
        const int n0 = (t & 3) * 64;
        const int k0 = ((t >> 2) % 6) * 64;
        const int b  = t / 24;
        const int c = tid & 63, r4 = tid >> 6;
        #pragma unroll
        for (int i = 0; i < 16; i++) {
            int kr = i * 4 + r4;
            int gn = n0 + c;
            T[kr][c] = (gn < N_) ? x[((size_t)b * DIM_ + k0 + kr) * N_ + gn] : 0.f;
        }
        __syncthreads();
        #pragma unroll
        for (int it = 0; it < 2; it++) {
            int m2 = it * 256 + tid;          // (token, k-octet) item
            int oct = m2 & 7, nn = m2 >> 3;
            int k = k0 + oct * 8, n = n0 + nn;
            v8u u;
            #pragma unroll
            for (int e = 0; e < 8; e++) u[e] = f2bf(T[oct * 8 + e][nn]);
            *(v8u*)&xI[(size_t)b * 98304 + (n >> 7) * 49152 + (k >> 5) * 4096
                       + ((k >> 3) & 3) * 1024 + (n & 127) * 8] = u;
        }
        return;
    }
    if (t < 1824) {               // ---- WbI: 8 elems/thread, float4 reads ----
        int base = ((t - 1536) * 256 + tid) * 8;       // < 589824
        int mt = base / 49152, rem = base % 49152;
        int ks = rem >> 12, r2 = rem & 4095;
        int q = r2 >> 10, row = (r2 >> 3) & 127;
        int c = mt * 128 + row, k = ks * 32 + q * 8;
        const float* src = (c < 256) ? &wq[c * 384 + k]
                         : (c < 512) ? &wk[(c - 256) * 384 + k]
                                     : &wv[(size_t)(c - 512) * 384 + k];
        float4 v0 = *(const float4*)src;
        float4 v1 = *(const float4*)(src + 4);
        v8u u;
        u[0] = f2bf(v0.x); u[1] = f2bf(v0.y); u[2] = f2bf(v0.z); u[3] = f2bf(v0.w);
        u[4] = f2bf(v1.x); u[5] = f2bf(v1.y); u[6] = f2bf(v1.z); u[7] = f2bf(v1.w);
        *(v8u*)&WbI[base] = u;
        return;
    }
    if (t < 2016) {               // ---- WpI: 8 elems/thread ----
        int base = ((t - 1824) * 256 + tid) * 8;       // < 393216
        int mt = base >> 17, rem = base & 131071;
        int ks = rem >> 12, r2 = rem & 4095;
        int q = r2 >> 10, row = (r2 >> 3) & 127;
        int p = mt * 128 + row, k = ks * 32 + q * 8;
        const float* src = &wp[(size_t)p * 1024 + k];
        float4 v0 = *(const float4*)src;
        float4 v1 = *(const float4*)(src + 4);
        v8u u;
        u[0] = f2bf(v0.x); u[1] = f2bf(v0.y); u[2] = f2bf(v0.z); u[3] = f2bf(v0.w);
        u[4] = f2bf(v1.x); u[5] = f2bf(v1.y); u[6] = f2bf(v1.z); u[7] = f2bf(v1.w);
        *(v8u*)&WpI[base] = u;
        return;
    }
    if (t < 2028) {               // ---- BN tables ----
        int j = (t - 2016) * 256 + tid;
        if (j >= 2944) return;
        if (j < 256) {
            int c = j;
            float s = bnq[c] * rsqrtf(bnq[768 + c] + EPS_);
            float tt = (bq[c] - bnq[512 + c]) * s + bnq[256 + c];
            TB[c] = s * SCALE_; TB[256 + c] = tt * SCALE_;
        } else if (j < 512) {
            int c = j - 256;
            float s = bnk[c] * rsqrtf(bnk[768 + c] + EPS_);
            float tt = (bk[c] - bnk[512 + c]) * s + bnk[256 + c];
            TB[512 + c] = s; TB[768 + c] = tt;
        } else if (j < 1536) {
            int c = j - 512;
            float s = bnv[c] * rsqrtf(bnv[3072 + c] + EPS_);
            float tt = (bv[c] - bnv[2048 + c]) * s + bnv[1024 + c];
            TB[1024 + c] = s; TB[2048 + c] = tt;
        } else if (j < 1920) {
            int c = j - 1536;
            float s = bnp[c] * rsqrtf(bnp[1152 + c] + EPS_);
            float tt = (bp[c] - bnp[768 + c]) * s + bnp[384 + c];
            TB[3072 + c] = s; TB[3456 + c] = tt;
        } else {
            int c = j - 1920;
            float s = bnvl[c] * rsqrtf(bnvl[3072 + c] + EPS_);
            float tt = (bvl[c] - bnvl[2048 + c]) * s + bnvl[1024 + c];
            TB[3840 + c] = s; TB[4864 + c] = tt;
        }
        return;
    }
    {                             // ---- biasE ----
        int j = (t - 2028) * 256 + tid;
        if (j >= 307328) return;
        int m = j % N_;
        int t2 = j / N_;
        int o = t2 & 7;
        int n = t2 >> 3;
        int idx = bidx[n * N_ + m];
        float a = th1b[o];
        #pragma unroll
        for (int h = 0; h < 8; h++) a += th1w[o * 8 + h] * ab[h * N_ + idx];
        biasE[j] = a - 5.f;
    }
}

// ---------------------------------------------------------------------------
// K1: QKV GEMM (direct core). v-epilogue: per-wave LDS transpose so the
// vI image is written as 16B coalesced chunks.
// XCD swizzle: 1536 blocks = 8 XCDs x (8 b x 24 tiles).
// ---------------------------------------------------------------------------
__global__ __launch_bounds__(256) void k_qkv(
    const u16* __restrict__ WbI, const u16* __restrict__ xI,
    const float* __restrict__ TB,
    u16* __restrict__ qI, u16* __restrict__ kI, u16* __restrict__ vI)
{
    __shared__ u16 S[4][64][20];   // per-wave [tok64][ch16 pad20] = 10240 B
    const int tid = threadIdx.x;
    const int L = blockIdx.x + 2 * (blockIdx.y + 12 * blockIdx.z);
    const int idx = L >> 3;                 // 0..191
    const int b  = (L & 7) * 8 + idx / 24;  // contiguous b-chunk per XCD
    const int r  = idx % 24;
    const int mt = r >> 1, nt = r & 1;
    v4f acc[4][4] = {};
    gemm_direct<12>(WbI + (size_t)mt * 49152,
                    xI + ((size_t)b * 2 + nt) * 49152, acc, tid);

    const int lane = tid & 63, w = tid >> 6;
    const int wm = (w & 1) * 64, wn = (w >> 1) * 64;
    const int quad = lane >> 4, l16 = lane & 15;

    if (mt < 4) {                 // ---- q / k epilogue (unchanged) ----
        #pragma unroll
        for (int i = 0; i < 4; i++) {
            #pragma unroll
            for (int j = 0; j < 4; j++) {
                int gc = mt * 128 + wm + i * 16 + quad * 4;
                int n  = nt * 128 + wn + j * 16 + l16;
                v4f v = acc[i][j];
                if (gc < 256) {            // q
                    v4f s = *(const v4f*)&TB[gc];
                    v4f t = *(const v4f*)&TB[256 + gc];
                    v4u u;
                    #pragma unroll
                    for (int r2 = 0; r2 < 4; r2++) u[r2] = f2bf(v[r2] * s[r2] + t[r2]);
                    *(v4u*)&qI[((size_t)(b * 8 + (gc >> 5)) * 256 + n) * 32 + (gc & 31)] = u;
                } else {                   // k
                    int c = gc - 256;
                    v4f s = *(const v4f*)&TB[512 + c];
                    v4f t = *(const v4f*)&TB[768 + c];
                    v4u u;
                    #pragma unroll
                    for (int r2 = 0; r2 < 4; r2++) u[r2] = f2bf(v[r2] * s[r2] + t[r2]);
                    *(v4u*)&kI[((size_t)(b * 8 + (c >> 5)) * 256 + n) * 32 + (c & 31)] = u;
                }
            }
        }
    } else {                      // ---- v epilogue: LDS transpose ----
        const int o = mt - 4;
        u16* vbase = vI + (size_t)(b * 8 + o) * 28672;
        const int ntBase = nt * 128;
        #pragma unroll
        for (int i = 0; i < 4; i++) {
            const int e0 = wm + i * 16;                  // 16-channel group base
            const int cg = o * 128 + e0 + quad * 4;      // global v channel
            v4f s = *(const v4f*)&TB[1024 + cg];
            v4f t = *(const v4f*)&TB[2048 + cg];
            // stage: lane (quad,l16) -> S[w][tok][quad*4..+3], zeros for n>=196
            #pragma unroll
            for (int j = 0; j < 4; j++) {
                int n = ntBase + wn + j * 16 + l16;
                v4u u = {0, 0, 0, 0};
                if (n < N_) {
                    v4f v = acc[i][j];
                    #pragma unroll
                    for (int r2 = 0; r2 < 4; r2++) u[r2] = f2bf(v[r2] * s[r2] + t[r2]);
                }
                *(v4u*)&S[w][j * 16 + l16][quad * 4] = u;
            }
            asm volatile("s_waitcnt lgkmcnt(0)" ::: "memory");
            // read out (ch, 8-tok) chunks -> 16B coalesced image stores
            #pragma unroll
            for (int half = 0; half < 2; half++) {
                int c = half * 64 + lane;        // chunk 0..127
                int ch = c >> 3, t0 = (c & 7) * 8;
                int n0 = ntBase + wn + t0;
                if (n0 < 224) {
                    v8u val;
                    #pragma unroll
                    for (int k = 0; k < 8; k++) val[k] = S[w][t0 + k][ch];
                    *(v8u*)&vbase[(size_t)(n0 >> 5) * 4096 + ((n0 >> 3) & 3) * 1024
                                  + (size_t)(e0 + ch) * 8] = val;
                }
            }
            asm volatile("s_waitcnt lgkmcnt(0)" ::: "memory");   // WAR vs next i
        }
    }
}

// ---------------------------------------------------------------------------
// K2: depthwise 3x3 conv. Block = 64 channels of one (b,o).
// ---------------------------------------------------------------------------
__global__ __launch_bounds__(256) void k_dwconv(
    const u16* __restrict__ vI, const float* __restrict__ wvl,
    const float* __restrict__ TB, u16* __restrict__ vlocI)
{
    __shared__ u16 V[64 * 230];             // 29440 B
    const int tid = threadIdx.x;
    const int sub = blockIdx.x;             // 0..15: o = sub>>1, half = sub&1
    const int b   = blockIdx.y;
    const int o   = sub >> 1;
    const int e0  = (sub & 1) * 64;
    const u16* img = vI + (size_t)(b * 8 + o) * 28672;

    {
        const int quad = tid >> 6, l = tid & 63;
        #pragma unroll
        for (int i = 0; i < 7; i++) {
            v8s u = *(const v8s*)&img[i * 4096 + quad * 1024 + (e0 + l) * 8];
            const u32* ui = (const u32*)&u;
            int m0 = i * 32 + quad * 8;
            u32* dst = (u32*)&V[l * 230 + m0];
            #pragma unroll
            for (int c = 0; c < 4; c++) dst[c] = ui[c];
        }
    }
    __syncthreads();

    const int e = tid & 63, j = tid >> 6;
    const int cg = sub * 64 + e;
    const int y0 = j * 4;
    const int ny = (j == 3) ? 2 : 4;
    float wgt[9];
    #pragma unroll
    for (int k = 0; k < 9; k++) wgt[k] = wvl[cg * 9 + k];
    const float sc = TB[3840 + cg], sh = TB[4864 + cg];
    u32 po[4][7];

    for (int yi = 0; yi < ny; yi++) {
        int y = y0 + yi;
        float a[3][16];
        #pragma unroll
        for (int dy = 0; dy < 3; dy++) {
            int yy = y + dy - 1;
            a[dy][0] = 0.f; a[dy][15] = 0.f;
            if (yy < 0 || yy > 13) {
                #pragma unroll
                for (int x = 1; x < 15; x++) a[dy][x] = 0.f;
            } else {
                const u16* rp = &V[e * 230 + yy * 14];
                #pragma unroll
                for (int c4 = 0; c4 < 7; c4++) {
                    u32 u = *(const u32*)&rp[c4 * 2];
                    a[dy][1 + 2 * c4] = bf2f((u16)(u & 0xffffu));
                    a[dy][2 + 2 * c4] = bf2f((u16)(u >> 16));
                }
            }
        }
        #pragma unroll
        for (int xp = 0; xp < 7; xp++) {
            u32 pk = 0;
            #pragma unroll
            for (int half = 0; half < 2; half++) {
                int x = 2 * xp + half;
                float s = 0.f;
                #pragma unroll
                for (int dy = 0; dy < 3; dy++)
                    #pragma unroll
                    for (int kx = 0; kx < 3; kx++)
                        s += wgt[dy * 3 + kx] * a[dy][x + kx];
                u16 bv = f2bf(s * sc + sh);
                pk |= ((u32)bv) << (16 * half);
            }
            po[yi][xp] = pk;
        }
    }
    __syncthreads();

    for (int yi = 0; yi < ny; yi++) {
        u32* dst = (u32*)&V[e * 196 + (y0 + yi) * 14];
        #pragma unroll
        for (int xp = 0; xp < 7; xp++) dst[xp] = po[yi][xp];
    }
    __syncthreads();

    for (int it = 0; it < 7; it++) {
        int idx = it * 256 + tid;
        if (idx < 1568) {
            int g = idx / 196, n = idx - g * 196;
            v4u lo, hi;
            #pragma unroll
            for (int r = 0; r < 4; r++) lo[r] = V[(g * 8 + r) * 196 + n];
            #pragma unroll
            for (int r = 0; r < 4; r++) hi[r] = V[(g * 8 + 4 + r) * 196 + n];
            u16* dst = vlocI + ((size_t)(b * 2 + (n >> 7)) * 32 + sub * 2 + (g >> 2)) * 4096
                     + (g & 3) * 1024 + (n & 127) * 8;
            *(v4u*)dst = lo;
            *(v4u*)(dst + 4) = hi;
        }
    }
}

// ---------------------------------------------------------------------------
// K3: FUSED attention + AV + vloc + relu -> aoI (round-5 config: QBLK=16,
// Sl stride 200, Zf zero-fragment, V prefetch, setprio).
// XCD swizzle: 832 blocks = 8 XCDs x (8 b x 13 qt).
// ---------------------------------------------------------------------------
#define SLS 200   // Sl stride (u16 elems); %4==0 for b64/b128 alignment
__global__ __launch_bounds__(512, 6) void k_attn_av(
    const u16* __restrict__ qI, const u16* __restrict__ kI,
    const u16* __restrict__ vI,
    const float* __restrict__ th1w,
    const float* __restrict__ th2w, const float* __restrict__ th2b,
    const float* __restrict__ biasE,
    const u16* __restrict__ vlocI, u16* __restrict__ aoI)
{
    __shared__ u16 Sl[8 * 16 * SLS];   // [h][q16][m<200] = 51200 B
    __shared__ float red[128][4];
    __shared__ float invS[128];        // [h*16+q]
    __shared__ __attribute__((aligned(16))) u16 Zf[8];   // zero fragment
    const int tid = threadIdx.x;
    const int w = tid >> 6, lane = tid & 63;
    const int quad = lane >> 4, l16 = lane & 15;
    const int L = blockIdx.x + 13 * blockIdx.y;
    const int idx = L >> 3;                 // 0..103
    const int b  = (L & 7) * 8 + idx / 13;  // contiguous b-chunk per XCD
    const int qt = idx % 13;                // 0..12
    const int n0 = qt * 16;
    if (tid < 8) Zf[tid] = 0;

    // phase A: wave w -> head w. Operand-swapped MFMA: D[m_local][q16].
    {
        const int h = w;
        const u16* qb = qI + (size_t)(b * 8 + h) * 8192;
        const u16* kb = kI + (size_t)(b * 8 + h) * 8192;
        v8s qf = *(const v8s*)&qb[(n0 + l16) * 32 + quad * 8];   // B operand (cols)
        #pragma unroll
        for (int mt = 0; mt < 13; mt++) {
            v8s kf = *(const v8s*)&kb[(mt * 16 + l16) * 32 + quad * 8]; // A operand (rows)
            v4f acc = {};
            acc = __builtin_amdgcn_mfma_f32_16x16x32_bf16(kf, qf, acc, 0, 0, 0);
            if (mt < 12 || quad < 2) {
                v4u pk;
                #pragma unroll
                for (int r = 0; r < 4; r++) pk[r] = f2h(acc[r]);
                *(v4u*)&Sl[(h * 16 + l16) * SLS + mt * 16 + quad * 4] = pk;
            }
        }
    }
    __syncthreads();

    // phase B1: thread owns (m-pair, q-quad); all LDS traffic u32, biasE float2
    const int mp  = (tid & 127) * 2;   // 0,2,...,254
    const int qh  = tid >> 7;          // 0..3 -> q = qh*4 + qq
    const bool pvalid = (mp < N_);
    for (int qq = 0; qq < 4; qq++) {
        int q = qh * 4 + qq;
        int n = n0 + q;
        if (pvalid && n < N_) {
            const float* bE = biasE + (size_t)n * 1568 + mp;
            float S0[8], S1[8];
            #pragma unroll
            for (int h = 0; h < 8; h++) {
                u32 u = *(const u32*)&Sl[(h * 16 + q) * SLS + mp];
                S0[h] = h2f((u16)(u & 0xffffu));
                S1[h] = h2f((u16)(u >> 16));
            }
            u32 ew[8];
            #pragma unroll
            for (int o = 0; o < 8; o++) {
                float2 bb = *(const float2*)&bE[o * 196];
                float a0 = bb.x, a1 = bb.y;
                #pragma unroll
                for (int h = 0; h < 8; h++) {
                    a0 += th1w[o * 8 + h] * S0[h];
                    a1 += th1w[o * 8 + h] * S1[h];
                }
                ew[o] = (u32)f2h(__expf(a0)) | ((u32)f2h(__expf(a1)) << 16);
            }
            #pragma unroll
            for (int o = 0; o < 8; o++)
                *(u32*)&Sl[(o * 16 + q) * SLS + mp] = ew[o];
        }
    }
    __syncthreads();

    // phase B2: 128 rows x 4 quarters; vectorized u32 LDS reads (m < 196)
    {
        int r = tid >> 2, quarter = tid & 3;
        int mstart = quarter * 48;
        int cnt = (quarter == 3) ? 26 : 24;
        const u16* rowp = &Sl[r * SLS + mstart];
        float s = 0.f;
        for (int i = 0; i < cnt; i++) {
            u32 u = *(const u32*)&rowp[i * 2];
            s += h2f((u16)(u & 0xffffu)) + h2f((u16)(u >> 16));
        }
        red[r][quarter] = s;
    }
    __syncthreads();
    if (tid < 128)
        invS[tid] = 1.f / (red[tid][0] + red[tid][1] + red[tid][2] + red[tid][3]);
    __syncthreads();

    // phase B3: scale + TH2 in place (bf16); m-pair u32 traffic; zero m<200
    for (int qq = 0; qq < 4; qq++) {
        int q = qh * 4 + qq;
        bool valid = pvalid && (n0 + q < N_);
        u32 pw[8];
        if (valid) {
            float s0[8], s1[8];
            #pragma unroll
            for (int h = 0; h < 8; h++) {
                u32 u = *(const u32*)&Sl[(h * 16 + q) * SLS + mp];
                float is = invS[h * 16 + q];
                s0[h] = h2f((u16)(u & 0xffffu)) * is;
                s1[h] = h2f((u16)(u >> 16)) * is;
            }
            #pragma unroll
            for (int o = 0; o < 8; o++) {
                float v0 = th2b[o], v1 = th2b[o];
                #pragma unroll
                for (int h = 0; h < 8; h++) {
                    v0 += th2w[o * 8 + h] * s0[h];
                    v1 += th2w[o * 8 + h] * s1[h];
                }
                pw[o] = (u32)f2bf(v0) | ((u32)f2bf(v1) << 16);
            }
        } else {
            #pragma unroll
            for (int o = 0; o < 8; o++) pw[o] = 0;
        }
        if (mp < SLS) {
            #pragma unroll
            for (int o = 0; o < 8; o++)
                *(u32*)&Sl[(o * 16 + q) * SLS + mp] = pw[o];
        }
    }

    // pre-issue phase C's first V fragments (pure global, no LDS dependency)
    const int o = w;
    const u16* vb = vI + (size_t)(b * 8 + o) * 28672;
    v8s a0pre[4];
    {
        const u16* ab00 = vb + quad * 1024 + l16 * 8;   // eh=0 base
        #pragma unroll
        for (int e = 0; e < 4; e++) a0pre[e] = *(const v8s*)(ab00 + e * 128);
    }
    __syncthreads();

    // phase C: AV. Wave w handles o = w; all 16 output columns live.
    {
        const int half_ = n0 >> 7;
        const int row0 = n0 & 127;
        const int n = n0 + l16;
        const bool act = (n < N_);
        const u16* prow = &Sl[(o * 16 + l16) * SLS];
        __builtin_amdgcn_s_setprio(1);
        #pragma unroll
        for (int eh = 0; eh < 2; eh++) {       // 2 e-halves of 64
            v4f acc[4] = {};
            v8s a[2][4];
            const u16* ab0 = vb + quad * 1024 + (eh * 64 + l16) * 8;
            if (eh == 0) {
                #pragma unroll
                for (int e = 0; e < 4; e++) a[0][e] = a0pre[e];
            } else {
                #pragma unroll
                for (int e = 0; e < 4; e++) a[0][e] = *(const v8s*)(ab0 + e * 128);
            }
            #pragma unroll
            for (int ks = 0; ks < 7; ks++) {
                const int cur = ks & 1, nxt = cur ^ 1;
                if (ks < 6) {
                    const u16* an = ab0 + (size_t)(ks + 1) * 4096;
                    #pragma unroll
                    for (int e = 0; e < 4; e++) a[nxt][e] = *(const v8s*)(an + e * 128);
                }
                const u16* psrc = (ks == 6 && quad != 0) ? &Zf[0]
                                                         : &prow[ks * 32 + quad * 8];
                v8s bfr = *(const v8s*)psrc;
                #pragma unroll
                for (int e = 0; e < 4; e++)
                    acc[e] = __builtin_amdgcn_mfma_f32_16x16x32_bf16(a[cur][e], bfr, acc[e], 0, 0, 0);
            }
            if (act) {
                #pragma unroll
                for (int e = 0; e < 4; e++) {
                    const int c0 = o * 128 + (eh * 4 + e) * 16 + quad * 4;
                    const size_t ioff = ((size_t)(b * 2 + half_) * 32 + (c0 >> 5)) * 4096
                                      + ((c0 >> 3) & 3) * 1024 + (size_t)(row0 + l16) * 8 + (c0 & 7);
                    v4u lv = *(const v4u*)&vlocI[ioff];
                    v4u u;
                    #pragma unroll
                    for (int r = 0; r < 4; r++)
                        u[r] = f2bf(fmaxf(acc[e][r] + bf2f(lv[r]), 0.f));
                    *(v4u*)&aoI[ioff] = u;
                }
            }
        }
        __builtin_amdgcn_s_setprio(0);
    }
}

// ---------------------------------------------------------------------------
// K6: projection GEMM (3-deep direct core, K=1024) + BN -> out fp32
// XCD swizzle: 384 blocks = 8 XCDs x (8 b x 6 tiles).
// ---------------------------------------------------------------------------
__global__ __launch_bounds__(256) void k_proj(
    const u16* __restrict__ WpI, const u16* __restrict__ aoI,
    const float* __restrict__ TB, float* __restrict__ out)
{
    const int tid = threadIdx.x;
    const int L = blockIdx.x + 2 * (blockIdx.y + 3 * blockIdx.z);
    const int idx = L >> 3;                 // 0..47
    const int b  = (L & 7) * 8 + idx / 6;   // contiguous b-chunk per XCD
    const int r  = idx % 6;
    const int mt = r >> 1, nt = r & 1;
    v4f acc[4][4] = {};
    gemm_direct3<32>(WpI + (size_t)mt * 131072,
                     aoI + ((size_t)b * 2 + nt) * 131072, acc, tid);

    const int lane = tid & 63, w = tid >> 6;
    const int wm = (w & 1) * 64, wn = (w >> 1) * 64;
    const int quad = lane >> 4, l16 = lane & 15;
    #pragma unroll
    for (int i = 0; i < 4; i++) {
        #pragma unroll
        for (int j = 0; j < 4; j++) {
            int p0 = mt * 128 + wm + i * 16 + quad * 4;
            int n  = nt * 128 + wn + j * 16 + l16;
            if (n < N_) {
                v4f s = *(const v4f*)&TB[3072 + p0];
                v4f t = *(const v4f*)&TB[3456 + p0];
                #pragma unroll
                for (int r2 = 0; r2 < 4; r2++)
                    out[((size_t)b * DIM_ + p0 + r2) * N_ + n] = acc[i][j][r2] * s[r2] + t[r2];
            }
        }
    }
}

// ---------------------------------------------------------------------------
extern "C" void kernel_launch(void* const* d_in, const int* in_sizes, int n_in,
                              void* d_out, int out_size, void* d_ws, size_t ws_size,
                              hipStream_t stream)
{
    const float* x    = (const float*)d_in[0];
    const float* wq   = (const float*)d_in[1];
    const float* bq   = (const float*)d_in[2];
    const float* bnq  = (const float*)d_in[3];
    const float* wk   = (const float*)d_in[4];
    const float* bk   = (const float*)d_in[5];
    const float* bnk  = (const float*)d_in[6];
    const float* wv   = (const float*)d_in[7];
    const float* bv   = (const float*)d_in[8];
    const float* bnv  = (const float*)d_in[9];
    const float* wvl  = (const float*)d_in[10];
    const float* bvl  = (const float*)d_in[11];
    const float* bnvl = (const float*)d_in[12];
    const float* th1w = (const float*)d_in[13];
    const float* th1b = (const float*)d_in[14];
    const float* th2w = (const float*)d_in[15];
    const float* th2b = (const float*)d_in[16];
    const float* wp   = (const float*)d_in[17];
    const float* bp   = (const float*)d_in[18];
    const float* bnp  = (const float*)d_in[19];
    const float* ab   = (const float*)d_in[20];
    const int*   bidx = (const int*)d_in[21];
    float* out = (float*)d_out;

    u16* wsb  = (u16*)d_ws;
    u16* WbI  = wsb + WBI_OFF;
    u16* WpI  = wsb + WPI_OFF;
    u16* qI   = wsb + QI_OFF;
    u16* kI   = wsb + KI_OFF;
    u16* vI   = wsb + VI_OFF;
    u16* vlocI = wsb + VLOC_U16;
    u16* xI   = wsb + TAIL_OFF;   // aliased: xI -> aoI (disjoint lifetimes)
    u16* aoI  = wsb + TAIL_OFF;
    float* TB    = (float*)(wsb + TB_OFF);
    float* biasE = (float*)(wsb + BIASE_OFF);

    k_pre<<<dim3(3229), 256, 0, stream>>>(x, wq, wk, wv, wp, ab, th1w, th1b,
                                          bq, bnq, bk, bnk, bv, bnv, bp, bnp, bvl, bnvl,
                                          bidx, xI, WbI, WpI, TB, biasE);
    k_qkv<<<dim3(2, 12, B_), 256, 0, stream>>>(WbI, xI, TB, qI, kI, vI);
    k_dwconv<<<dim3(16, B_), 256, 0, stream>>>(vI, wvl, TB, vlocI);
    k_attn_av<<<dim3(13, B_), 512, 0, stream>>>(qI, kI, vI, th1w, th2w, th2b,
                                                biasE, vlocI, aoI);
    k_proj<<<dim3(2, 3, B_), 256, 0, stream>>>(WpI, aoI, TB, out);
}

// Round 12
// 239.947 us; speedup vs baseline: 1.1119x; 1.0084x over previous
//
#include <hip/hip_runtime.h>

#define B_     64
#define DIM_   384
#define RES_   14
#define N_     196
#define HEADS_ 8
#define KD_    32
#define D_     128
#define DH_    1024
#define QK_    256
#define CH_    1536
#define EPS_   1e-5f
#define SCALE_ 0.17677669529663687f   // 32^-0.5

typedef unsigned short u16;
typedef unsigned int u32;
typedef short v8s __attribute__((ext_vector_type(8)));
typedef float v4f __attribute__((ext_vector_type(4)));
typedef u16  v4u __attribute__((ext_vector_type(4)));
typedef u16  v8u __attribute__((ext_vector_type(8)));

static __device__ __forceinline__ u16 f2bf(float f) {
    unsigned int u = __builtin_bit_cast(unsigned int, f);
    u = (u + 0x7fffu + ((u >> 16) & 1u)) >> 16;
    return (u16)u;
}
static __device__ __forceinline__ float bf2f(u16 u) {
    unsigned int x = ((unsigned int)u) << 16;
    return __builtin_bit_cast(float, x);
}
static __device__ __forceinline__ u16 f2h(float f) {
    _Float16 h = (_Float16)f;
    return __builtin_bit_cast(u16, h);
}
static __device__ __forceinline__ float h2f(u16 u) {
    return (float)__builtin_bit_cast(_Float16, u);
}

// workspace layout (u16 element offsets)
// GEMM operand images: [kstep][kquad(4)][row(128)][8] = 4096 elems (8KB)/kstep
#define WBI_OFF  0u          // Wb  image: 12 mtiles x 12 ksteps      (589824)
#define WPI_OFF  589824u     // wp  image: 3 mtiles x 32 ksteps       (393216)
#define QI_OFF   983040u     // qT  [B][8][256][32]                   (4194304)
#define KI_OFF   5177344u    // kT  [B][8][256][32]                   (4194304)
#define VI_OFF   9371648u    // v   image: [B][8] x 7 ksteps          (14680064)
#define VLOC_U16 53411840u   // vlocI in aoI image layout             (16777216)
#define TAIL_OFF 79101952u   // union: xI (6291456) / aoI (16777216)
#define TB_OFF   98770944u   // BN tables fp32[5888]
#define BIASE_OFF 98785920u  // biasE [196][8][196] fp32 (614656 u16)

// ---------------------------------------------------------------------------
// barrier-free direct-from-global 128x128 MFMA core.
// ---------------------------------------------------------------------------
template<int KSTEPS>
static __device__ __forceinline__ void gemm_direct(
    const u16* __restrict__ Ag, const u16* __restrict__ Bg,
    v4f acc[4][4], int tid)
{
    const int lane = tid & 63, w = tid >> 6;
    const int wm = (w & 1) * 64, wn = (w >> 1) * 64;
    const int quad = lane >> 4, l16 = lane & 15;
    const u16* pa = Ag + quad * 1024 + (wm + l16) * 8;
    const u16* pb = Bg + quad * 1024 + (wn + l16) * 8;
    v8s a[2][4], b[2][4];
    #pragma unroll
    for (int i = 0; i < 4; i++) {
        a[0][i] = *(const v8s*)(pa + i * 128);
        b[0][i] = *(const v8s*)(pb + i * 128);
    }
    #pragma unroll
    for (int ks = 0; ks < KSTEPS; ks++) {
        const int cur = ks & 1, nxt = cur ^ 1;
        if (ks + 1 < KSTEPS) {
            const u16* qa = pa + (size_t)(ks + 1) * 4096;
            const u16* qb = pb + (size_t)(ks + 1) * 4096;
            #pragma unroll
            for (int i = 0; i < 4; i++) {
                a[nxt][i] = *(const v8s*)(qa + i * 128);
                b[nxt][i] = *(const v8s*)(qb + i * 128);
            }
        }
        #pragma unroll
        for (int i = 0; i < 4; i++)
            #pragma unroll
            for (int j = 0; j < 4; j++)
                acc[i][j] = __builtin_amdgcn_mfma_f32_16x16x32_bf16(a[cur][i], b[cur][j], acc[i][j], 0, 0, 0);
    }
}

// 3-deep variant for long-K latency-exposed GEMMs (k_proj: K=32 steps).
template<int KSTEPS>
static __device__ __forceinline__ void gemm_direct3(
    const u16* __restrict__ Ag, const u16* __restrict__ Bg,
    v4f acc[4][4], int tid)
{
    const int lane = tid & 63, w = tid >> 6;
    const int wm = (w & 1) * 64, wn = (w >> 1) * 64;
    const int quad = lane >> 4, l16 = lane & 15;
    const u16* pa = Ag + quad * 1024 + (wm + l16) * 8;
    const u16* pb = Bg + quad * 1024 + (wn + l16) * 8;
    v8s a[3][4], b[3][4];
    #pragma unroll
    for (int s = 0; s < 2; s++) {
        #pragma unroll
        for (int i = 0; i < 4; i++) {
            a[s][i] = *(const v8s*)(pa + (size_t)s * 4096 + i * 128);
            b[s][i] = *(const v8s*)(pb + (size_t)s * 4096 + i * 128);
        }
    }
    #pragma unroll
    for (int ks = 0; ks < KSTEPS; ks++) {
        const int cur = ks % 3, nxt = (ks + 2) % 3;
        if (ks + 2 < KSTEPS) {
            const u16* qa = pa + (size_t)(ks + 2) * 4096;
            const u16* qb = pb + (size_t)(ks + 2) * 4096;
            #pragma unroll
            for (int i = 0; i < 4; i++) {
                a[nxt][i] = *(const v8s*)(qa + i * 128);
                b[nxt][i] = *(const v8s*)(qb + i * 128);
            }
        }
        #pragma unroll
        for (int i = 0; i < 4; i++)
            #pragma unroll
            for (int j = 0; j < 4; j++)
                acc[i][j] = __builtin_amdgcn_mfma_f32_16x16x32_bf16(a[cur][i], b[cur][j], acc[i][j], 0, 0, 0);
    }
}

// ---------------------------------------------------------------------------
// k_pre: ALL preprocessing in one launch (round-11 vectorized version).
// Grid: [0,1536) castX | [1536,1824) WbI | [1824,2016) WpI
//       [2016,2028) BN | [2028,3229) biasE
// ---------------------------------------------------------------------------
__global__ __launch_bounds__(256) void k_pre(
    const float* __restrict__ x,
    const float* __restrict__ wq, const float* __restrict__ wk,
    const float* __restrict__ wv, const float* __restrict__ wp,
    const float* __restrict__ ab,
    const float* __restrict__ th1w, const float* __restrict__ th1b,
    const float* __restrict__ bq, const float* __restrict__ bnq,
    const float* __restrict__ bk, const float* __restrict__ bnk,
    const float* __restrict__ bv, const float* __restrict__ bnv,
    const float* __restrict__ bp, const float* __restrict__ bnp,
    const float* __restrict__ bvl, const float* __restrict__ bnvl,
    const int* __restrict__ bidx,
    u16* __restrict__ xI, u16* __restrict__ WbI, u16* __restrict__ WpI,
    float* __restrict__ TB, float* __restrict__ biasE)
{
    __shared__ float T[64][65];
    const int tid = threadIdx.x;
    const int t = blockIdx.x;
    if (t < 1536) {               // ---- castX (vectorized 16B image stores) ----
        const int n0 = (t & 3) * 64;
        const int k0 = ((t >> 2) % 6) * 64;
        const int b  = t / 24;
        const int c = tid & 63, r4 = tid >> 6;
        #pragma unroll
        for (int i = 0; i < 16; i++) {
            int kr = i * 4 + r4;
            int gn = n0 + c;
            T[kr][c] = (gn < N_) ? x[((size_t)b * DIM_ + k0 + kr) * N_ + gn] : 0.f;
        }
        __syncthreads();
        #pragma unroll
        for (int it = 0; it < 2; it++) {
            int m2 = it * 256 + tid;          // (token, k-octet) item
            int oct = m2 & 7, nn = m2 >> 3;
            int k = k0 + oct * 8, n = n0 + nn;
            v8u u;
            #pragma unroll
            for (int e = 0; e < 8; e++) u[e] = f2bf(T[oct * 8 + e][nn]);
            *(v8u*)&xI[(size_t)b * 98304 + (n >> 7) * 49152 + (k >> 5) * 4096
                       + ((k >> 3) & 3) * 1024 + (n & 127) * 8] = u;
        }
        return;
    }
    if (t < 1824) {               // ---- WbI: 8 elems/thread, float4 reads ----
        int base = ((t - 1536) * 256 + tid) * 8;       // < 589824
        int mt = base / 49152, rem = base % 49152;
        int ks = rem >> 12, r2 = rem & 4095;
        int q = r2 >> 10, row = (r2 >> 3) & 127;
        int c = mt * 128 + row, k = ks * 32 + q * 8;
        const float* src = (c < 256) ? &wq[c * 384 + k]
                         : (c < 512) ? &wk[(c - 256) * 384 + k]
                                     : &wv[(size_t)(c - 512) * 384 + k];
        float4 v0 = *(const float4*)src;
        float4 v1 = *(const float4*)(src + 4);
        v8u u;
        u[0] = f2bf(v0.x); u[1] = f2bf(v0.y); u[2] = f2bf(v0.z); u[3] = f2bf(v0.w);
        u[4] = f2bf(v1.x); u[5] = f2bf(v1.y); u[6] = f2bf(v1.z); u[7] = f2bf(v1.w);
        *(v8u*)&WbI[base] = u;
        return;
    }
    if (t < 2016) {               // ---- WpI: 8 elems/thread ----
        int base = ((t - 1824) * 256 + tid) * 8;       // < 393216
        int mt = base >> 17, rem = base & 131071;
        int ks = rem >> 12, r2 = rem & 4095;
        int q = r2 >> 10, row = (r2 >> 3) & 127;
        int p = mt * 128 + row, k = ks * 32 + q * 8;
        const float* src = &wp[(size_t)p * 1024 + k];
        float4 v0 = *(const float4*)src;
        float4 v1 = *(const float4*)(src + 4);
        v8u u;
        u[0] = f2bf(v0.x); u[1] = f2bf(v0.y); u[2] = f2bf(v0.z); u[3] = f2bf(v0.w);
        u[4] = f2bf(v1.x); u[5] = f2bf(v1.y); u[6] = f2bf(v1.z); u[7] = f2bf(v1.w);
        *(v8u*)&WpI[base] = u;
        return;
    }
    if (t < 2028) {               // ---- BN tables ----
        int j = (t - 2016) * 256 + tid;
        if (j >= 2944) return;
        if (j < 256) {
            int c = j;
            float s = bnq[c] * rsqrtf(bnq[768 + c] + EPS_);
            float tt = (bq[c] - bnq[512 + c]) * s + bnq[256 + c];
            TB[c] = s * SCALE_; TB[256 + c] = tt * SCALE_;
        } else if (j < 512) {
            int c = j - 256;
            float s = bnk[c] * rsqrtf(bnk[768 + c] + EPS_);
            float tt = (bk[c] - bnk[512 + c]) * s + bnk[256 + c];
            TB[512 + c] = s; TB[768 + c] = tt;
        } else if (j < 1536) {
            int c = j - 512;
            float s = bnv[c] * rsqrtf(bnv[3072 + c] + EPS_);
            float tt = (bv[c] - bnv[2048 + c]) * s + bnv[1024 + c];
            TB[1024 + c] = s; TB[2048 + c] = tt;
        } else if (j < 1920) {
            int c = j - 1536;
            float s = bnp[c] * rsqrtf(bnp[1152 + c] + EPS_);
            float tt = (bp[c] - bnp[768 + c]) * s + bnp[384 + c];
            TB[3072 + c] = s; TB[3456 + c] = tt;
        } else {
            int c = j - 1920;
            float s = bnvl[c] * rsqrtf(bnvl[3072 + c] + EPS_);
            float tt = (bvl[c] - bnvl[2048 + c]) * s + bnvl[1024 + c];
            TB[3840 + c] = s; TB[4864 + c] = tt;
        }
        return;
    }
    {                             // ---- biasE ----
        int j = (t - 2028) * 256 + tid;
        if (j >= 307328) return;
        int m = j % N_;
        int t2 = j / N_;
        int o = t2 & 7;
        int n = t2 >> 3;
        int idx = bidx[n * N_ + m];
        float a = th1b[o];
        #pragma unroll
        for (int h = 0; h < 8; h++) a += th1w[o * 8 + h] * ab[h * N_ + idx];
        biasE[j] = a - 5.f;
    }
}

// ---------------------------------------------------------------------------
// K1: QKV GEMM (direct core). v-epilogue: per-wave LDS transpose so the
// vI image is written as 16B coalesced chunks.
// XCD swizzle: 1536 blocks = 8 XCDs x (8 b x 24 tiles).
// ---------------------------------------------------------------------------
__global__ __launch_bounds__(256) void k_qkv(
    const u16* __restrict__ WbI, const u16* __restrict__ xI,
    const float* __restrict__ TB,
    u16* __restrict__ qI, u16* __restrict__ kI, u16* __restrict__ vI)
{
    __shared__ u16 S[4][64][20];   // per-wave [tok64][ch16 pad20] = 10240 B
    const int tid = threadIdx.x;
    const int L = blockIdx.x + 2 * (blockIdx.y + 12 * blockIdx.z);
    const int idx = L >> 3;                 // 0..191
    const int b  = (L & 7) * 8 + idx / 24;  // contiguous b-chunk per XCD
    const int r  = idx % 24;
    const int mt = r >> 1, nt = r & 1;
    v4f acc[4][4] = {};
    gemm_direct<12>(WbI + (size_t)mt * 49152,
                    xI + ((size_t)b * 2 + nt) * 49152, acc, tid);

    const int lane = tid & 63, w = tid >> 6;
    const int wm = (w & 1) * 64, wn = (w >> 1) * 64;
    const int quad = lane >> 4, l16 = lane & 15;

    if (mt < 4) {                 // ---- q / k epilogue (unchanged) ----
        #pragma unroll
        for (int i = 0; i < 4; i++) {
            #pragma unroll
            for (int j = 0; j < 4; j++) {
                int gc = mt * 128 + wm + i * 16 + quad * 4;
                int n  = nt * 128 + wn + j * 16 + l16;
                v4f v = acc[i][j];
                if (gc < 256) {            // q
                    v4f s = *(const v4f*)&TB[gc];
                    v4f t = *(const v4f*)&TB[256 + gc];
                    v4u u;
                    #pragma unroll
                    for (int r2 = 0; r2 < 4; r2++) u[r2] = f2bf(v[r2] * s[r2] + t[r2]);
                    *(v4u*)&qI[((size_t)(b * 8 + (gc >> 5)) * 256 + n) * 32 + (gc & 31)] = u;
                } else {                   // k
                    int c = gc - 256;
                    v4f s = *(const v4f*)&TB[512 + c];
                    v4f t = *(const v4f*)&TB[768 + c];
                    v4u u;
                    #pragma unroll
                    for (int r2 = 0; r2 < 4; r2++) u[r2] = f2bf(v[r2] * s[r2] + t[r2]);
                    *(v4u*)&kI[((size_t)(b * 8 + (c >> 5)) * 256 + n) * 32 + (c & 31)] = u;
                }
            }
        }
    } else {                      // ---- v epilogue: LDS transpose ----
        const int o = mt - 4;
        u16* vbase = vI + (size_t)(b * 8 + o) * 28672;
        const int ntBase = nt * 128;
        #pragma unroll
        for (int i = 0; i < 4; i++) {
            const int e0 = wm + i * 16;                  // 16-channel group base
            const int cg = o * 128 + e0 + quad * 4;      // global v channel
            v4f s = *(const v4f*)&TB[1024 + cg];
            v4f t = *(const v4f*)&TB[2048 + cg];
            // stage: lane (quad,l16) -> S[w][tok][quad*4..+3], zeros for n>=196
            #pragma unroll
            for (int j = 0; j < 4; j++) {
                int n = ntBase + wn + j * 16 + l16;
                v4u u = {0, 0, 0, 0};
                if (n < N_) {
                    v4f v = acc[i][j];
                    #pragma unroll
                    for (int r2 = 0; r2 < 4; r2++) u[r2] = f2bf(v[r2] * s[r2] + t[r2]);
                }
                *(v4u*)&S[w][j * 16 + l16][quad * 4] = u;
            }
            asm volatile("s_waitcnt lgkmcnt(0)" ::: "memory");
            // read out (ch, 8-tok) chunks -> 16B coalesced image stores
            #pragma unroll
            for (int half = 0; half < 2; half++) {
                int c = half * 64 + lane;        // chunk 0..127
                int ch = c >> 3, t0 = (c & 7) * 8;
                int n0 = ntBase + wn + t0;
                if (n0 < 224) {
                    v8u val;
                    #pragma unroll
                    for (int k = 0; k < 8; k++) val[k] = S[w][t0 + k][ch];
                    *(v8u*)&vbase[(size_t)(n0 >> 5) * 4096 + ((n0 >> 3) & 3) * 1024
                                  + (size_t)(e0 + ch) * 8] = val;
                }
            }
            asm volatile("s_waitcnt lgkmcnt(0)" ::: "memory");   // WAR vs next i
        }
    }
}

// ---------------------------------------------------------------------------
// K2: depthwise 3x3 conv. Block = 64 channels of one (b,o).
// NEW output path: phase 2 rewrites the (dead) LDS buffer in [token][ch+pad]
// layout (scalar writes, consecutive-lane -> consecutive-address, free);
// phase 3 is then ONE ds_read_b128 + ONE 16B global store per item
// (was: 8 scalar ds_read_u16 + 2 stores).
// ---------------------------------------------------------------------------
__global__ __launch_bounds__(256) void k_dwconv(
    const u16* __restrict__ vI, const float* __restrict__ wvl,
    const float* __restrict__ TB, u16* __restrict__ vlocI)
{
    __shared__ __attribute__((aligned(16))) u16 V[64 * 230];   // 29440 B
    const int tid = threadIdx.x;
    const int sub = blockIdx.x;             // 0..15: o = sub>>1, half = sub&1
    const int b   = blockIdx.y;
    const int o   = sub >> 1;
    const int e0  = (sub & 1) * 64;
    const u16* img = vI + (size_t)(b * 8 + o) * 28672;

    {
        const int quad = tid >> 6, l = tid & 63;
        #pragma unroll
        for (int i = 0; i < 7; i++) {
            v8s u = *(const v8s*)&img[i * 4096 + quad * 1024 + (e0 + l) * 8];
            const u32* ui = (const u32*)&u;
            int m0 = i * 32 + quad * 8;
            u32* dst = (u32*)&V[l * 230 + m0];
            #pragma unroll
            for (int c = 0; c < 4; c++) dst[c] = ui[c];
        }
    }
    __syncthreads();

    const int e = tid & 63, j = tid >> 6;
    const int cg = sub * 64 + e;
    const int y0 = j * 4;
    const int ny = (j == 3) ? 2 : 4;
    float wgt[9];
    #pragma unroll
    for (int k = 0; k < 9; k++) wgt[k] = wvl[cg * 9 + k];
    const float sc = TB[3840 + cg], sh = TB[4864 + cg];
    u32 po[4][7];

    for (int yi = 0; yi < ny; yi++) {
        int y = y0 + yi;
        float a[3][16];
        #pragma unroll
        for (int dy = 0; dy < 3; dy++) {
            int yy = y + dy - 1;
            a[dy][0] = 0.f; a[dy][15] = 0.f;
            if (yy < 0 || yy > 13) {
                #pragma unroll
                for (int x = 1; x < 15; x++) a[dy][x] = 0.f;
            } else {
                const u16* rp = &V[e * 230 + yy * 14];
                #pragma unroll
                for (int c4 = 0; c4 < 7; c4++) {
                    u32 u = *(const u32*)&rp[c4 * 2];
                    a[dy][1 + 2 * c4] = bf2f((u16)(u & 0xffffu));
                    a[dy][2 + 2 * c4] = bf2f((u16)(u >> 16));
                }
            }
        }
        #pragma unroll
        for (int xp = 0; xp < 7; xp++) {
            u32 pk = 0;
            #pragma unroll
            for (int half = 0; half < 2; half++) {
                int x = 2 * xp + half;
                float s = 0.f;
                #pragma unroll
                for (int dy = 0; dy < 3; dy++)
                    #pragma unroll
                    for (int kx = 0; kx < 3; kx++)
                        s += wgt[dy * 3 + kx] * a[dy][x + kx];
                u16 bv = f2bf(s * sc + sh);
                pk |= ((u32)bv) << (16 * half);
            }
            po[yi][xp] = pk;
        }
    }
    __syncthreads();

    // phase 2: write results to V2[n][72-pad][ch] (transposed for vector gather)
    for (int yi = 0; yi < ny; yi++) {
        int y = y0 + yi;
        #pragma unroll
        for (int xp = 0; xp < 7; xp++) {
            u32 pk = po[yi][xp];
            int n = y * 14 + 2 * xp;
            V[n * 72 + e]       = (u16)(pk & 0xffffu);
            V[(n + 1) * 72 + e] = (u16)(pk >> 16);
        }
    }
    __syncthreads();

    // phase 3: one b128 gather + one 16B store per (g, n) item
    for (int it = 0; it < 7; it++) {
        int idx = it * 256 + tid;
        if (idx < 1568) {
            int g = idx / 196, n = idx - g * 196;
            v8u val = *(const v8u*)&V[n * 72 + g * 8];
            u16* dst = vlocI + ((size_t)(b * 2 + (n >> 7)) * 32 + sub * 2 + (g >> 2)) * 4096
                     + (g & 3) * 1024 + (n & 127) * 8;
            *(v8u*)dst = val;
        }
    }
}

// ---------------------------------------------------------------------------
// K3: FUSED attention + AV + vloc + relu -> aoI (round-5 config: QBLK=16,
// Sl stride 200, Zf zero-fragment, V prefetch, setprio).
// XCD swizzle: 832 blocks = 8 XCDs x (8 b x 13 qt).
// ---------------------------------------------------------------------------
#define SLS 200   // Sl stride (u16 elems); %4==0 for b64/b128 alignment
__global__ __launch_bounds__(512, 6) void k_attn_av(
    const u16* __restrict__ qI, const u16* __restrict__ kI,
    const u16* __restrict__ vI,
    const float* __restrict__ th1w,
    const float* __restrict__ th2w, const float* __restrict__ th2b,
    const float* __restrict__ biasE,
    const u16* __restrict__ vlocI, u16* __restrict__ aoI)
{
    __shared__ u16 Sl[8 * 16 * SLS];   // [h][q16][m<200] = 51200 B
    __shared__ float red[128][4];
    __shared__ float invS[128];        // [h*16+q]
    __shared__ __attribute__((aligned(16))) u16 Zf[8];   // zero fragment
    const int tid = threadIdx.x;
    const int w = tid >> 6, lane = tid & 63;
    const int quad = lane >> 4, l16 = lane & 15;
    const int L = blockIdx.x + 13 * blockIdx.y;
    const int idx = L >> 3;                 // 0..103
    const int b  = (L & 7) * 8 + idx / 13;  // contiguous b-chunk per XCD
    const int qt = idx % 13;                // 0..12
    const int n0 = qt * 16;
    if (tid < 8) Zf[tid] = 0;

    // phase A: wave w -> head w. Operand-swapped MFMA: D[m_local][q16].
    {
        const int h = w;
        const u16* qb = qI + (size_t)(b * 8 + h) * 8192;
        const u16* kb = kI + (size_t)(b * 8 + h) * 8192;
        v8s qf = *(const v8s*)&qb[(n0 + l16) * 32 + quad * 8];   // B operand (cols)
        #pragma unroll
        for (int mt = 0; mt < 13; mt++) {
            v8s kf = *(const v8s*)&kb[(mt * 16 + l16) * 32 + quad * 8]; // A operand (rows)
            v4f acc = {};
            acc = __builtin_amdgcn_mfma_f32_16x16x32_bf16(kf, qf, acc, 0, 0, 0);
            if (mt < 12 || quad < 2) {
                v4u pk;
                #pragma unroll
                for (int r = 0; r < 4; r++) pk[r] = f2h(acc[r]);
                *(v4u*)&Sl[(h * 16 + l16) * SLS + mt * 16 + quad * 4] = pk;
            }
        }
    }
    __syncthreads();

    // phase B1: thread owns (m-pair, q-quad); all LDS traffic u32, biasE float2
    const int mp  = (tid & 127) * 2;   // 0,2,...,254
    const int qh  = tid >> 7;          // 0..3 -> q = qh*4 + qq
    const bool pvalid = (mp < N_);
    for (int qq = 0; qq < 4; qq++) {
        int q = qh * 4 + qq;
        int n = n0 + q;
        if (pvalid && n < N_) {
            const float* bE = biasE + (size_t)n * 1568 + mp;
            float S0[8], S1[8];
            #pragma unroll
            for (int h = 0; h < 8; h++) {
                u32 u = *(const u32*)&Sl[(h * 16 + q) * SLS + mp];
                S0[h] = h2f((u16)(u & 0xffffu));
                S1[h] = h2f((u16)(u >> 16));
            }
            u32 ew[8];
            #pragma unroll
            for (int o = 0; o < 8; o++) {
                float2 bb = *(const float2*)&bE[o * 196];
                float a0 = bb.x, a1 = bb.y;
                #pragma unroll
                for (int h = 0; h < 8; h++) {
                    a0 += th1w[o * 8 + h] * S0[h];
                    a1 += th1w[o * 8 + h] * S1[h];
                }
                ew[o] = (u32)f2h(__expf(a0)) | ((u32)f2h(__expf(a1)) << 16);
            }
            #pragma unroll
            for (int o = 0; o < 8; o++)
                *(u32*)&Sl[(o * 16 + q) * SLS + mp] = ew[o];
        }
    }
    __syncthreads();

    // phase B2: 128 rows x 4 quarters; vectorized u32 LDS reads (m < 196)
    {
        int r = tid >> 2, quarter = tid & 3;
        int mstart = quarter * 48;
        int cnt = (quarter == 3) ? 26 : 24;
        const u16* rowp = &Sl[r * SLS + mstart];
        float s = 0.f;
        for (int i = 0; i < cnt; i++) {
            u32 u = *(const u32*)&rowp[i * 2];
            s += h2f((u16)(u & 0xffffu)) + h2f((u16)(u >> 16));
        }
        red[r][quarter] = s;
    }
    __syncthreads();
    if (tid < 128)
        invS[tid] = 1.f / (red[tid][0] + red[tid][1] + red[tid][2] + red[tid][3]);
    __syncthreads();

    // phase B3: scale + TH2 in place (bf16); m-pair u32 traffic; zero m<200
    for (int qq = 0; qq < 4; qq++) {
        int q = qh * 4 + qq;
        bool valid = pvalid && (n0 + q < N_);
        u32 pw[8];
        if (valid) {
            float s0[8], s1[8];
            #pragma unroll
            for (int h = 0; h < 8; h++) {
                u32 u = *(const u32*)&Sl[(h * 16 + q) * SLS + mp];
                float is = invS[h * 16 + q];
                s0[h] = h2f((u16)(u & 0xffffu)) * is;
                s1[h] = h2f((u16)(u >> 16)) * is;
            }
            #pragma unroll
            for (int o = 0; o < 8; o++) {
                float v0 = th2b[o], v1 = th2b[o];
                #pragma unroll
                for (int h = 0; h < 8; h++) {
                    v0 += th2w[o * 8 + h] * s0[h];
                    v1 += th2w[o * 8 + h] * s1[h];
                }
                pw[o] = (u32)f2bf(v0) | ((u32)f2bf(v1) << 16);
            }
        } else {
            #pragma unroll
            for (int o = 0; o < 8; o++) pw[o] = 0;
        }
        if (mp < SLS) {
            #pragma unroll
            for (int o = 0; o < 8; o++)
                *(u32*)&Sl[(o * 16 + q) * SLS + mp] = pw[o];
        }
    }

    // pre-issue phase C's first V fragments (pure global, no LDS dependency)
    const int o = w;
    const u16* vb = vI + (size_t)(b * 8 + o) * 28672;
    v8s a0pre[4];
    {
        const u16* ab00 = vb + quad * 1024 + l16 * 8;   // eh=0 base
        #pragma unroll
        for (int e = 0; e < 4; e++) a0pre[e] = *(const v8s*)(ab00 + e * 128);
    }
    __syncthreads();

    // phase C: AV. Wave w handles o = w; all 16 output columns live.
    {
        const int half_ = n0 >> 7;
        const int row0 = n0 & 127;
        const int n = n0 + l16;
        const bool act = (n < N_);
        const u16* prow = &Sl[(o * 16 + l16) * SLS];
        __builtin_amdgcn_s_setprio(1);
        #pragma unroll
        for (int eh = 0; eh < 2; eh++) {       // 2 e-halves of 64
            v4f acc[4] = {};
            v8s a[2][4];
            const u16* ab0 = vb + quad * 1024 + (eh * 64 + l16) * 8;
            if (eh == 0) {
                #pragma unroll
                for (int e = 0; e < 4; e++) a[0][e] = a0pre[e];
            } else {
                #pragma unroll
                for (int e = 0; e < 4; e++) a[0][e] = *(const v8s*)(ab0 + e * 128);
            }
            #pragma unroll
            for (int ks = 0; ks < 7; ks++) {
                const int cur = ks & 1, nxt = cur ^ 1;
                if (ks < 6) {
                    const u16* an = ab0 + (size_t)(ks + 1) * 4096;
                    #pragma unroll
                    for (int e = 0; e < 4; e++) a[nxt][e] = *(const v8s*)(an + e * 128);
                }
                const u16* psrc = (ks == 6 && quad != 0) ? &Zf[0]
                                                         : &prow[ks * 32 + quad * 8];
                v8s bfr = *(const v8s*)psrc;
                #pragma unroll
                for (int e = 0; e < 4; e++)
                    acc[e] = __builtin_amdgcn_mfma_f32_16x16x32_bf16(a[cur][e], bfr, acc[e], 0, 0, 0);
            }
            if (act) {
                #pragma unroll
                for (int e = 0; e < 4; e++) {
                    const int c0 = o * 128 + (eh * 4 + e) * 16 + quad * 4;
                    const size_t ioff = ((size_t)(b * 2 + half_) * 32 + (c0 >> 5)) * 4096
                                      + ((c0 >> 3) & 3) * 1024 + (size_t)(row0 + l16) * 8 + (c0 & 7);
                    v4u lv = *(const v4u*)&vlocI[ioff];
                    v4u u;
                    #pragma unroll
                    for (int r = 0; r < 4; r++)
                        u[r] = f2bf(fmaxf(acc[e][r] + bf2f(lv[r]), 0.f));
                    *(v4u*)&aoI[ioff] = u;
                }
            }
        }
        __builtin_amdgcn_s_setprio(0);
    }
}

// ---------------------------------------------------------------------------
// K6: projection GEMM (3-deep direct core, K=1024) + BN -> out fp32
// XCD swizzle: 384 blocks = 8 XCDs x (8 b x 6 tiles).
// ---------------------------------------------------------------------------
__global__ __launch_bounds__(256) void k_proj(
    const u16* __restrict__ WpI, const u16* __restrict__ aoI,
    const float* __restrict__ TB, float* __restrict__ out)
{
    const int tid = threadIdx.x;
    const int L = blockIdx.x + 2 * (blockIdx.y + 3 * blockIdx.z);
    const int idx = L >> 3;                 // 0..47
    const int b  = (L & 7) * 8 + idx / 6;   // contiguous b-chunk per XCD
    const int r  = idx % 6;
    const int mt = r >> 1, nt = r & 1;
    v4f acc[4][4] = {};
    gemm_direct3<32>(WpI + (size_t)mt * 131072,
                     aoI + ((size_t)b * 2 + nt) * 131072, acc, tid);

    const int lane = tid & 63, w = tid >> 6;
    const int wm = (w & 1) * 64, wn = (w >> 1) * 64;
    const int quad = lane >> 4, l16 = lane & 15;
    #pragma unroll
    for (int i = 0; i < 4; i++) {
        #pragma unroll
        for (int j = 0; j < 4; j++) {
            int p0 = mt * 128 + wm + i * 16 + quad * 4;
            int n  = nt * 128 + wn + j * 16 + l16;
            if (n < N_) {
                v4f s = *(const v4f*)&TB[3072 + p0];
                v4f t = *(const v4f*)&TB[3456 + p0];
                #pragma unroll
                for (int r2 = 0; r2 < 4; r2++)
                    out[((size_t)b * DIM_ + p0 + r2) * N_ + n] = acc[i][j][r2] * s[r2] + t[r2];
            }
        }
    }
}

// ---------------------------------------------------------------------------
extern "C" void kernel_launch(void* const* d_in, const int* in_sizes, int n_in,
                              void* d_out, int out_size, void* d_ws, size_t ws_size,
                              hipStream_t stream)
{
    const float* x    = (const float*)d_in[0];
    const float* wq   = (const float*)d_in[1];
    const float* bq   = (const float*)d_in[2];
    const float* bnq  = (const float*)d_in[3];
    const float* wk   = (const float*)d_in[4];
    const float* bk   = (const float*)d_in[5];
    const float* bnk  = (const float*)d_in[6];
    const float* wv   = (const float*)d_in[7];
    const float* bv   = (const float*)d_in[8];
    const float* bnv  = (const float*)d_in[9];
    const float* wvl  = (const float*)d_in[10];
    const float* bvl  = (const float*)d_in[11];
    const float* bnvl = (const float*)d_in[12];
    const float* th1w = (const float*)d_in[13];
    const float* th1b = (const float*)d_in[14];
    const float* th2w = (const float*)d_in[15];
    const float* th2b = (const float*)d_in[16];
    const float* wp   = (const float*)d_in[17];
    const float* bp   = (const float*)d_in[18];
    const float* bnp  = (const float*)d_in[19];
    const float* ab   = (const float*)d_in[20];
    const int*   bidx = (const int*)d_in[21];
    float* out = (float*)d_out;

    u16* wsb  = (u16*)d_ws;
    u16* WbI  = wsb + WBI_OFF;
    u16* WpI  = wsb + WPI_OFF;
    u16* qI   = wsb + QI_OFF;
    u16* kI   = wsb + KI_OFF;
    u16* vI   = wsb + VI_OFF;
    u16* vlocI = wsb + VLOC_U16;
    u16* xI   = wsb + TAIL_OFF;   // aliased: xI -> aoI (disjoint lifetimes)
    u16* aoI  = wsb + TAIL_OFF;
    float* TB    = (float*)(wsb + TB_OFF);
    float* biasE = (float*)(wsb + BIASE_OFF);

    k_pre<<<dim3(3229), 256, 0, stream>>>(x, wq, wk, wv, wp, ab, th1w, th1b,
                                          bq, bnq, bk, bnk, bv, bnv, bp, bnp, bvl, bnvl,
                                          bidx, xI, WbI, WpI, TB, biasE);
    k_qkv<<<dim3(2, 12, B_), 256, 0, stream>>>(WbI, xI, TB, qI, kI, vI);
    k_dwconv<<<dim3(16, B_), 256, 0, stream>>>(vI, wvl, TB, vlocI);
    k_attn_av<<<dim3(13, B_), 512, 0, stream>>>(qI, kI, vI, th1w, th2w, th2b,
                                                biasE, vlocI, aoI);
    k_proj<<<dim3(2, 3, B_), 256, 0, stream>>>(WpI, aoI, TB, out);
}

// Round 13
// 239.438 us; speedup vs baseline: 1.1142x; 1.0021x over previous
//
#include <hip/hip_runtime.h>

#define B_     64
#define DIM_   384
#define RES_   14
#define N_     196
#define HEADS_ 8
#define KD_    32
#define D_     128
#define DH_    1024
#define QK_    256
#define CH_    1536
#define EPS_   1e-5f
#define SCALE_ 0.17677669529663687f   // 32^-0.5

typedef unsigned short u16;
typedef unsigned int u32;
typedef short v8s __attribute__((ext_vector_type(8)));
typedef float v4f __attribute__((ext_vector_type(4)));
typedef u16  v4u __attribute__((ext_vector_type(4)));
typedef u16  v8u __attribute__((ext_vector_type(8)));

static __device__ __forceinline__ u16 f2bf(float f) {
    unsigned int u = __builtin_bit_cast(unsigned int, f);
    u = (u + 0x7fffu + ((u >> 16) & 1u)) >> 16;
    return (u16)u;
}
static __device__ __forceinline__ float bf2f(u16 u) {
    unsigned int x = ((unsigned int)u) << 16;
    return __builtin_bit_cast(float, x);
}
static __device__ __forceinline__ u16 f2h(float f) {
    _Float16 h = (_Float16)f;
    return __builtin_bit_cast(u16, h);
}
static __device__ __forceinline__ float h2f(u16 u) {
    return (float)__builtin_bit_cast(_Float16, u);
}

// workspace layout (u16 element offsets)
// GEMM operand images: [kstep][kquad(4)][row(128)][8] = 4096 elems (8KB)/kstep
#define WBI_OFF  0u          // Wb  image: 12 mtiles x 12 ksteps      (589824)
#define WPI_OFF  589824u     // wp  image: 3 mtiles x 32 ksteps       (393216)
#define QI_OFF   983040u     // qT  [B][8][256][32]                   (4194304)
#define KI_OFF   5177344u    // kT  [B][8][256][32]                   (4194304)
#define VI_OFF   9371648u    // v   image: [B][8] x 7 ksteps          (14680064)
#define VLOC_U16 53411840u   // vlocI in aoI image layout             (16777216)
#define TAIL_OFF 79101952u   // union: xI (6291456) / aoI (16777216)
#define TB_OFF   98770944u   // BN tables fp32[5888]
#define BIASE_OFF 98785920u  // biasE16 [196][98][8][2] f16 (307328 u16)

// ---------------------------------------------------------------------------
// barrier-free direct-from-global 128x128 MFMA core.
// ---------------------------------------------------------------------------
template<int KSTEPS>
static __device__ __forceinline__ void gemm_direct(
    const u16* __restrict__ Ag, const u16* __restrict__ Bg,
    v4f acc[4][4], int tid)
{
    const int lane = tid & 63, w = tid >> 6;
    const int wm = (w & 1) * 64, wn = (w >> 1) * 64;
    const int quad = lane >> 4, l16 = lane & 15;
    const u16* pa = Ag + quad * 1024 + (wm + l16) * 8;
    const u16* pb = Bg + quad * 1024 + (wn + l16) * 8;
    v8s a[2][4], b[2][4];
    #pragma unroll
    for (int i = 0; i < 4; i++) {
        a[0][i] = *(const v8s*)(pa + i * 128);
        b[0][i] = *(const v8s*)(pb + i * 128);
    }
    #pragma unroll
    for (int ks = 0; ks < KSTEPS; ks++) {
        const int cur = ks & 1, nxt = cur ^ 1;
        if (ks + 1 < KSTEPS) {
            const u16* qa = pa + (size_t)(ks + 1) * 4096;
            const u16* qb = pb + (size_t)(ks + 1) * 4096;
            #pragma unroll
            for (int i = 0; i < 4; i++) {
                a[nxt][i] = *(const v8s*)(qa + i * 128);
                b[nxt][i] = *(const v8s*)(qb + i * 128);
            }
        }
        #pragma unroll
        for (int i = 0; i < 4; i++)
            #pragma unroll
            for (int j = 0; j < 4; j++)
                acc[i][j] = __builtin_amdgcn_mfma_f32_16x16x32_bf16(a[cur][i], b[cur][j], acc[i][j], 0, 0, 0);
    }
}

// 3-deep variant for long-K latency-exposed GEMMs (k_proj: K=32 steps).
template<int KSTEPS>
static __device__ __forceinline__ void gemm_direct3(
    const u16* __restrict__ Ag, const u16* __restrict__ Bg,
    v4f acc[4][4], int tid)
{
    const int lane = tid & 63, w = tid >> 6;
    const int wm = (w & 1) * 64, wn = (w >> 1) * 64;
    const int quad = lane >> 4, l16 = lane & 15;
    const u16* pa = Ag + quad * 1024 + (wm + l16) * 8;
    const u16* pb = Bg + quad * 1024 + (wn + l16) * 8;
    v8s a[3][4], b[3][4];
    #pragma unroll
    for (int s = 0; s < 2; s++) {
        #pragma unroll
        for (int i = 0; i < 4; i++) {
            a[s][i] = *(const v8s*)(pa + (size_t)s * 4096 + i * 128);
            b[s][i] = *(const v8s*)(pb + (size_t)s * 4096 + i * 128);
        }
    }
    #pragma unroll
    for (int ks = 0; ks < KSTEPS; ks++) {
        const int cur = ks % 3, nxt = (ks + 2) % 3;
        if (ks + 2 < KSTEPS) {
            const u16* qa = pa + (size_t)(ks + 2) * 4096;
            const u16* qb = pb + (size_t)(ks + 2) * 4096;
            #pragma unroll
            for (int i = 0; i < 4; i++) {
                a[nxt][i] = *(const v8s*)(qa + i * 128);
                b[nxt][i] = *(const v8s*)(qb + i * 128);
            }
        }
        #pragma unroll
        for (int i = 0; i < 4; i++)
            #pragma unroll
            for (int j = 0; j < 4; j++)
                acc[i][j] = __builtin_amdgcn_mfma_f32_16x16x32_bf16(a[cur][i], b[cur][j], acc[i][j], 0, 0, 0);
    }
}

// ---------------------------------------------------------------------------
// k_pre: ALL preprocessing in one launch (round-11 vectorized version).
// biasE now packed f16 [n][m-pair][o][2] so attn B1 reads 2x16B per (thr,q).
// Grid: [0,1536) castX | [1536,1824) WbI | [1824,2016) WpI
//       [2016,2028) BN | [2028,3229) biasE16
// ---------------------------------------------------------------------------
__global__ __launch_bounds__(256) void k_pre(
    const float* __restrict__ x,
    const float* __restrict__ wq, const float* __restrict__ wk,
    const float* __restrict__ wv, const float* __restrict__ wp,
    const float* __restrict__ ab,
    const float* __restrict__ th1w, const float* __restrict__ th1b,
    const float* __restrict__ bq, const float* __restrict__ bnq,
    const float* __restrict__ bk, const float* __restrict__ bnk,
    const float* __restrict__ bv, const float* __restrict__ bnv,
    const float* __restrict__ bp, const float* __restrict__ bnp,
    const float* __restrict__ bvl, const float* __restrict__ bnvl,
    const int* __restrict__ bidx,
    u16* __restrict__ xI, u16* __restrict__ WbI, u16* __restrict__ WpI,
    float* __restrict__ TB, u16* __restrict__ biasE16)
{
    __shared__ float T[64][65];
    const int tid = threadIdx.x;
    const int t = blockIdx.x;
    if (t < 1536) {               // ---- castX (vectorized 16B image stores) ----
        const int n0 = (t & 3) * 64;
        const int k0 = ((t >> 2) % 6) * 64;
        const int b  = t / 24;
        const int c = tid & 63, r4 = tid >> 6;
        #pragma unroll
        for (int i = 0; i < 16; i++) {
            int kr = i * 4 + r4;
            int gn = n0 + c;
            T[kr][c] = (gn < N_) ? x[((size_t)b * DIM_ + k0 + kr) * N_ + gn] : 0.f;
        }
        __syncthreads();
        #pragma unroll
        for (int it = 0; it < 2; it++) {
            int m2 = it * 256 + tid;          // (token, k-octet) item
            int oct = m2 & 7, nn = m2 >> 3;
            int k = k0 + oct * 8, n = n0 + nn;
            v8u u;
            #pragma unroll
            for (int e = 0; e < 8; e++) u[e] = f2bf(T[oct * 8 + e][nn]);
            *(v8u*)&xI[(size_t)b * 98304 + (n >> 7) * 49152 + (k >> 5) * 4096
                       + ((k >> 3) & 3) * 1024 + (n & 127) * 8] = u;
        }
        return;
    }
    if (t < 1824) {               // ---- WbI: 8 elems/thread, float4 reads ----
        int base = ((t - 1536) * 256 + tid) * 8;       // < 589824
        int mt = base / 49152, rem = base % 49152;
        int ks = rem >> 12, r2 = rem & 4095;
        int q = r2 >> 10, row = (r2 >> 3) & 127;
        int c = mt * 128 + row, k = ks * 32 + q * 8;
        const float* src = (c < 256) ? &wq[c * 384 + k]
                         : (c < 512) ? &wk[(c - 256) * 384 + k]
                                     : &wv[(size_t)(c - 512) * 384 + k];
        float4 v0 = *(const float4*)src;
        float4 v1 = *(const float4*)(src + 4);
        v8u u;
        u[0] = f2bf(v0.x); u[1] = f2bf(v0.y); u[2] = f2bf(v0.z); u[3] = f2bf(v0.w);
        u[4] = f2bf(v1.x); u[5] = f2bf(v1.y); u[6] = f2bf(v1.z); u[7] = f2bf(v1.w);
        *(v8u*)&WbI[base] = u;
        return;
    }
    if (t < 2016) {               // ---- WpI: 8 elems/thread ----
        int base = ((t - 1824) * 256 + tid) * 8;       // < 393216
        int mt = base >> 17, rem = base & 131071;
        int ks = rem >> 12, r2 = rem & 4095;
        int q = r2 >> 10, row = (r2 >> 3) & 127;
        int p = mt * 128 + row, k = ks * 32 + q * 8;
        const float* src = &wp[(size_t)p * 1024 + k];
        float4 v0 = *(const float4*)src;
        float4 v1 = *(const float4*)(src + 4);
        v8u u;
        u[0] = f2bf(v0.x); u[1] = f2bf(v0.y); u[2] = f2bf(v0.z); u[3] = f2bf(v0.w);
        u[4] = f2bf(v1.x); u[5] = f2bf(v1.y); u[6] = f2bf(v1.z); u[7] = f2bf(v1.w);
        *(v8u*)&WpI[base] = u;
        return;
    }
    if (t < 2028) {               // ---- BN tables ----
        int j = (t - 2016) * 256 + tid;
        if (j >= 2944) return;
        if (j < 256) {
            int c = j;
            float s = bnq[c] * rsqrtf(bnq[768 + c] + EPS_);
            float tt = (bq[c] - bnq[512 + c]) * s + bnq[256 + c];
            TB[c] = s * SCALE_; TB[256 + c] = tt * SCALE_;
        } else if (j < 512) {
            int c = j - 256;
            float s = bnk[c] * rsqrtf(bnk[768 + c] + EPS_);
            float tt = (bk[c] - bnk[512 + c]) * s + bnk[256 + c];
            TB[512 + c] = s; TB[768 + c] = tt;
        } else if (j < 1536) {
            int c = j - 512;
            float s = bnv[c] * rsqrtf(bnv[3072 + c] + EPS_);
            float tt = (bv[c] - bnv[2048 + c]) * s + bnv[1024 + c];
            TB[1024 + c] = s; TB[2048 + c] = tt;
        } else if (j < 1920) {
            int c = j - 1536;
            float s = bnp[c] * rsqrtf(bnp[1152 + c] + EPS_);
            float tt = (bp[c] - bnp[768 + c]) * s + bnp[384 + c];
            TB[3072 + c] = s; TB[3456 + c] = tt;
        } else {
            int c = j - 1920;
            float s = bnvl[c] * rsqrtf(bnvl[3072 + c] + EPS_);
            float tt = (bvl[c] - bnvl[2048 + c]) * s + bnvl[1024 + c];
            TB[3840 + c] = s; TB[4864 + c] = tt;
        }
        return;
    }
    {                             // ---- biasE16 [n][mp2(98)][o(8)][half(2)] f16 ----
        int j = (t - 2028) * 256 + tid;
        if (j >= 307328) return;
        int half = j & 1;
        int o    = (j >> 1) & 7;
        int rest = j >> 4;          // n*98 + mp2
        int mp2  = rest % 98;
        int n    = rest / 98;
        int m    = mp2 * 2 + half;  // < 196 always
        int idx = bidx[n * N_ + m];
        float a = th1b[o];
        #pragma unroll
        for (int h = 0; h < 8; h++) a += th1w[o * 8 + h] * ab[h * N_ + idx];
        biasE16[j] = f2h(a - 5.f);
    }
}

// ---------------------------------------------------------------------------
// K1: QKV GEMM (direct core). v-epilogue: per-wave LDS transpose so the
// vI image is written as 16B coalesced chunks.
// XCD swizzle: 1536 blocks = 8 XCDs x (8 b x 24 tiles).
// ---------------------------------------------------------------------------
__global__ __launch_bounds__(256) void k_qkv(
    const u16* __restrict__ WbI, const u16* __restrict__ xI,
    const float* __restrict__ TB,
    u16* __restrict__ qI, u16* __restrict__ kI, u16* __restrict__ vI)
{
    __shared__ u16 S[4][64][20];   // per-wave [tok64][ch16 pad20] = 10240 B
    const int tid = threadIdx.x;
    const int L = blockIdx.x + 2 * (blockIdx.y + 12 * blockIdx.z);
    const int idx = L >> 3;                 // 0..191
    const int b  = (L & 7) * 8 + idx / 24;  // contiguous b-chunk per XCD
    const int r  = idx % 24;
    const int mt = r >> 1, nt = r & 1;
    v4f acc[4][4] = {};
    gemm_direct<12>(WbI + (size_t)mt * 49152,
                    xI + ((size_t)b * 2 + nt) * 49152, acc, tid);

    const int lane = tid & 63, w = tid >> 6;
    const int wm = (w & 1) * 64, wn = (w >> 1) * 64;
    const int quad = lane >> 4, l16 = lane & 15;

    if (mt < 4) {                 // ---- q / k epilogue (unchanged) ----
        #pragma unroll
        for (int i = 0; i < 4; i++) {
            #pragma unroll
            for (int j = 0; j < 4; j++) {
                int gc = mt * 128 + wm + i * 16 + quad * 4;
                int n  = nt * 128 + wn + j * 16 + l16;
                v4f v = acc[i][j];
                if (gc < 256) {            // q
                    v4f s = *(const v4f*)&TB[gc];
                    v4f t = *(const v4f*)&TB[256 + gc];
                    v4u u;
                    #pragma unroll
                    for (int r2 = 0; r2 < 4; r2++) u[r2] = f2bf(v[r2] * s[r2] + t[r2]);
                    *(v4u*)&qI[((size_t)(b * 8 + (gc >> 5)) * 256 + n) * 32 + (gc & 31)] = u;
                } else {                   // k
                    int c = gc - 256;
                    v4f s = *(const v4f*)&TB[512 + c];
                    v4f t = *(const v4f*)&TB[768 + c];
                    v4u u;
                    #pragma unroll
                    for (int r2 = 0; r2 < 4; r2++) u[r2] = f2bf(v[r2] * s[r2] + t[r2]);
                    *(v4u*)&kI[((size_t)(b * 8 + (c >> 5)) * 256 + n) * 32 + (c & 31)] = u;
                }
            }
        }
    } else {                      // ---- v epilogue: LDS transpose ----
        const int o = mt - 4;
        u16* vbase = vI + (size_t)(b * 8 + o) * 28672;
        const int ntBase = nt * 128;
        #pragma unroll
        for (int i = 0; i < 4; i++) {
            const int e0 = wm + i * 16;                  // 16-channel group base
            const int cg = o * 128 + e0 + quad * 4;      // global v channel
            v4f s = *(const v4f*)&TB[1024 + cg];
            v4f t = *(const v4f*)&TB[2048 + cg];
            // stage: lane (quad,l16) -> S[w][tok][quad*4..+3], zeros for n>=196
            #pragma unroll
            for (int j = 0; j < 4; j++) {
                int n = ntBase + wn + j * 16 + l16;
                v4u u = {0, 0, 0, 0};
                if (n < N_) {
                    v4f v = acc[i][j];
                    #pragma unroll
                    for (int r2 = 0; r2 < 4; r2++) u[r2] = f2bf(v[r2] * s[r2] + t[r2]);
                }
                *(v4u*)&S[w][j * 16 + l16][quad * 4] = u;
            }
            asm volatile("s_waitcnt lgkmcnt(0)" ::: "memory");
            // read out (ch, 8-tok) chunks -> 16B coalesced image stores
            #pragma unroll
            for (int half = 0; half < 2; half++) {
                int c = half * 64 + lane;        // chunk 0..127
                int ch = c >> 3, t0 = (c & 7) * 8;
                int n0 = ntBase + wn + t0;
                if (n0 < 224) {
                    v8u val;
                    #pragma unroll
                    for (int k = 0; k < 8; k++) val[k] = S[w][t0 + k][ch];
                    *(v8u*)&vbase[(size_t)(n0 >> 5) * 4096 + ((n0 >> 3) & 3) * 1024
                                  + (size_t)(e0 + ch) * 8] = val;
                }
            }
            asm volatile("s_waitcnt lgkmcnt(0)" ::: "memory");   // WAR vs next i
        }
    }
}

// ---------------------------------------------------------------------------
// K2: depthwise 3x3 conv. Block = 64 channels of one (b,o).
// Output path via [token][ch+pad] LDS transpose (round-12).
// ---------------------------------------------------------------------------
__global__ __launch_bounds__(256) void k_dwconv(
    const u16* __restrict__ vI, const float* __restrict__ wvl,
    const float* __restrict__ TB, u16* __restrict__ vlocI)
{
    __shared__ __attribute__((aligned(16))) u16 V[64 * 230];   // 29440 B
    const int tid = threadIdx.x;
    const int sub = blockIdx.x;             // 0..15: o = sub>>1, half = sub&1
    const int b   = blockIdx.y;
    const int o   = sub >> 1;
    const int e0  = (sub & 1) * 64;
    const u16* img = vI + (size_t)(b * 8 + o) * 28672;

    {
        const int quad = tid >> 6, l = tid & 63;
        #pragma unroll
        for (int i = 0; i < 7; i++) {
            v8s u = *(const v8s*)&img[i * 4096 + quad * 1024 + (e0 + l) * 8];
            const u32* ui = (const u32*)&u;
            int m0 = i * 32 + quad * 8;
            u32* dst = (u32*)&V[l * 230 + m0];
            #pragma unroll
            for (int c = 0; c < 4; c++) dst[c] = ui[c];
        }
    }
    __syncthreads();

    const int e = tid & 63, j = tid >> 6;
    const int cg = sub * 64 + e;
    const int y0 = j * 4;
    const int ny = (j == 3) ? 2 : 4;
    float wgt[9];
    #pragma unroll
    for (int k = 0; k < 9; k++) wgt[k] = wvl[cg * 9 + k];
    const float sc = TB[3840 + cg], sh = TB[4864 + cg];
    u32 po[4][7];

    for (int yi = 0; yi < ny; yi++) {
        int y = y0 + yi;
        float a[3][16];
        #pragma unroll
        for (int dy = 0; dy < 3; dy++) {
            int yy = y + dy - 1;
            a[dy][0] = 0.f; a[dy][15] = 0.f;
            if (yy < 0 || yy > 13) {
                #pragma unroll
                for (int x = 1; x < 15; x++) a[dy][x] = 0.f;
            } else {
                const u16* rp = &V[e * 230 + yy * 14];
                #pragma unroll
                for (int c4 = 0; c4 < 7; c4++) {
                    u32 u = *(const u32*)&rp[c4 * 2];
                    a[dy][1 + 2 * c4] = bf2f((u16)(u & 0xffffu));
                    a[dy][2 + 2 * c4] = bf2f((u16)(u >> 16));
                }
            }
        }
        #pragma unroll
        for (int xp = 0; xp < 7; xp++) {
            u32 pk = 0;
            #pragma unroll
            for (int half = 0; half < 2; half++) {
                int x = 2 * xp + half;
                float s = 0.f;
                #pragma unroll
                for (int dy = 0; dy < 3; dy++)
                    #pragma unroll
                    for (int kx = 0; kx < 3; kx++)
                        s += wgt[dy * 3 + kx] * a[dy][x + kx];
                u16 bv = f2bf(s * sc + sh);
                pk |= ((u32)bv) << (16 * half);
            }
            po[yi][xp] = pk;
        }
    }
    __syncthreads();

    // phase 2: write results to V2[n][72-pad][ch] (transposed for vector gather)
    for (int yi = 0; yi < ny; yi++) {
        int y = y0 + yi;
        #pragma unroll
        for (int xp = 0; xp < 7; xp++) {
            u32 pk = po[yi][xp];
            int n = y * 14 + 2 * xp;
            V[n * 72 + e]       = (u16)(pk & 0xffffu);
            V[(n + 1) * 72 + e] = (u16)(pk >> 16);
        }
    }
    __syncthreads();

    // phase 3: one b128 gather + one 16B store per (g, n) item
    for (int it = 0; it < 7; it++) {
        int idx = it * 256 + tid;
        if (idx < 1568) {
            int g = idx / 196, n = idx - g * 196;
            v8u val = *(const v8u*)&V[n * 72 + g * 8];
            u16* dst = vlocI + ((size_t)(b * 2 + (n >> 7)) * 32 + sub * 2 + (g >> 2)) * 4096
                     + (g & 3) * 1024 + (n & 127) * 8;
            *(v8u*)dst = val;
        }
    }
}

// ---------------------------------------------------------------------------
// K3: FUSED attention + AV + vloc + relu -> aoI (round-5 config: QBLK=16,
// Sl stride 200, Zf zero-fragment, V prefetch, setprio).
// B1 now reads packed-f16 biasE16: two 16B loads per (thread, q) instead of
// eight 8B float2 loads -- halves the largest global stream in the kernel.
// XCD swizzle: 832 blocks = 8 XCDs x (8 b x 13 qt).
// ---------------------------------------------------------------------------
#define SLS 200   // Sl stride (u16 elems); %4==0 for b64/b128 alignment
__global__ __launch_bounds__(512, 6) void k_attn_av(
    const u16* __restrict__ qI, const u16* __restrict__ kI,
    const u16* __restrict__ vI,
    const float* __restrict__ th1w,
    const float* __restrict__ th2w, const float* __restrict__ th2b,
    const u16* __restrict__ biasE16,
    const u16* __restrict__ vlocI, u16* __restrict__ aoI)
{
    __shared__ u16 Sl[8 * 16 * SLS];   // [h][q16][m<200] = 51200 B
    __shared__ float red[128][4];
    __shared__ float invS[128];        // [h*16+q]
    __shared__ __attribute__((aligned(16))) u16 Zf[8];   // zero fragment
    const int tid = threadIdx.x;
    const int w = tid >> 6, lane = tid & 63;
    const int quad = lane >> 4, l16 = lane & 15;
    const int L = blockIdx.x + 13 * blockIdx.y;
    const int idx = L >> 3;                 // 0..103
    const int b  = (L & 7) * 8 + idx / 13;  // contiguous b-chunk per XCD
    const int qt = idx % 13;                // 0..12
    const int n0 = qt * 16;
    if (tid < 8) Zf[tid] = 0;

    // phase A: wave w -> head w. Operand-swapped MFMA: D[m_local][q16].
    {
        const int h = w;
        const u16* qb = qI + (size_t)(b * 8 + h) * 8192;
        const u16* kb = kI + (size_t)(b * 8 + h) * 8192;
        v8s qf = *(const v8s*)&qb[(n0 + l16) * 32 + quad * 8];   // B operand (cols)
        #pragma unroll
        for (int mt = 0; mt < 13; mt++) {
            v8s kf = *(const v8s*)&kb[(mt * 16 + l16) * 32 + quad * 8]; // A operand (rows)
            v4f acc = {};
            acc = __builtin_amdgcn_mfma_f32_16x16x32_bf16(kf, qf, acc, 0, 0, 0);
            if (mt < 12 || quad < 2) {
                v4u pk;
                #pragma unroll
                for (int r = 0; r < 4; r++) pk[r] = f2h(acc[r]);
                *(v4u*)&Sl[(h * 16 + l16) * SLS + mt * 16 + quad * 4] = pk;
            }
        }
    }
    __syncthreads();

    // phase B1: thread owns (m-pair, q-quad); biasE16 packed [n][mp2][o][2]
    const int mp  = (tid & 127) * 2;   // 0,2,...,254
    const int qh  = tid >> 7;          // 0..3 -> q = qh*4 + qq
    const bool pvalid = (mp < N_);
    for (int qq = 0; qq < 4; qq++) {
        int q = qh * 4 + qq;
        int n = n0 + q;
        if (pvalid && n < N_) {
            const u16* bE = biasE16 + ((size_t)n * 98 + (tid & 127)) * 16;
            v8u bb0 = *(const v8u*)bE;        // o=0..3 x {lo,hi}
            v8u bb1 = *(const v8u*)(bE + 8);  // o=4..7 x {lo,hi}
            float S0[8], S1[8];
            #pragma unroll
            for (int h = 0; h < 8; h++) {
                u32 u = *(const u32*)&Sl[(h * 16 + q) * SLS + mp];
                S0[h] = h2f((u16)(u & 0xffffu));
                S1[h] = h2f((u16)(u >> 16));
            }
            u32 ew[8];
            #pragma unroll
            for (int o = 0; o < 8; o++) {
                float a0 = h2f((o < 4) ? bb0[(o & 3) * 2 + 0] : bb1[(o & 3) * 2 + 0]);
                float a1 = h2f((o < 4) ? bb0[(o & 3) * 2 + 1] : bb1[(o & 3) * 2 + 1]);
                #pragma unroll
                for (int h = 0; h < 8; h++) {
                    a0 += th1w[o * 8 + h] * S0[h];
                    a1 += th1w[o * 8 + h] * S1[h];
                }
                ew[o] = (u32)f2h(__expf(a0)) | ((u32)f2h(__expf(a1)) << 16);
            }
            #pragma unroll
            for (int o = 0; o < 8; o++)
                *(u32*)&Sl[(o * 16 + q) * SLS + mp] = ew[o];
        }
    }
    __syncthreads();

    // phase B2: 128 rows x 4 quarters; vectorized u32 LDS reads (m < 196)
    {
        int r = tid >> 2, quarter = tid & 3;
        int mstart = quarter * 48;
        int cnt = (quarter == 3) ? 26 : 24;
        const u16* rowp = &Sl[r * SLS + mstart];
        float s = 0.f;
        for (int i = 0; i < cnt; i++) {
            u32 u = *(const u32*)&rowp[i * 2];
            s += h2f((u16)(u & 0xffffu)) + h2f((u16)(u >> 16));
        }
        red[r][quarter] = s;
    }
    __syncthreads();
    if (tid < 128)
        invS[tid] = 1.f / (red[tid][0] + red[tid][1] + red[tid][2] + red[tid][3]);
    __syncthreads();

    // phase B3: scale + TH2 in place (bf16); m-pair u32 traffic; zero m<200
    for (int qq = 0; qq < 4; qq++) {
        int q = qh * 4 + qq;
        bool valid = pvalid && (n0 + q < N_);
        u32 pw[8];
        if (valid) {
            float s0[8], s1[8];
            #pragma unroll
            for (int h = 0; h < 8; h++) {
                u32 u = *(const u32*)&Sl[(h * 16 + q) * SLS + mp];
                float is = invS[h * 16 + q];
                s0[h] = h2f((u16)(u & 0xffffu)) * is;
                s1[h] = h2f((u16)(u >> 16)) * is;
            }
            #pragma unroll
            for (int o = 0; o < 8; o++) {
                float v0 = th2b[o], v1 = th2b[o];
                #pragma unroll
                for (int h = 0; h < 8; h++) {
                    v0 += th2w[o * 8 + h] * s0[h];
                    v1 += th2w[o * 8 + h] * s1[h];
                }
                pw[o] = (u32)f2bf(v0) | ((u32)f2bf(v1) << 16);
            }
        } else {
            #pragma unroll
            for (int o = 0; o < 8; o++) pw[o] = 0;
        }
        if (mp < SLS) {
            #pragma unroll
            for (int o = 0; o < 8; o++)
                *(u32*)&Sl[(o * 16 + q) * SLS + mp] = pw[o];
        }
    }

    // pre-issue phase C's first V fragments (pure global, no LDS dependency)
    const int o = w;
    const u16* vb = vI + (size_t)(b * 8 + o) * 28672;
    v8s a0pre[4];
    {
        const u16* ab00 = vb + quad * 1024 + l16 * 8;   // eh=0 base
        #pragma unroll
        for (int e = 0; e < 4; e++) a0pre[e] = *(const v8s*)(ab00 + e * 128);
    }
    __syncthreads();

    // phase C: AV. Wave w handles o = w; all 16 output columns live.
    {
        const int half_ = n0 >> 7;
        const int row0 = n0 & 127;
        const int n = n0 + l16;
        const bool act = (n < N_);
        const u16* prow = &Sl[(o * 16 + l16) * SLS];
        __builtin_amdgcn_s_setprio(1);
        #pragma unroll
        for (int eh = 0; eh < 2; eh++) {       // 2 e-halves of 64
            v4f acc[4] = {};
            v8s a[2][4];
            const u16* ab0 = vb + quad * 1024 + (eh * 64 + l16) * 8;
            if (eh == 0) {
                #pragma unroll
                for (int e = 0; e < 4; e++) a[0][e] = a0pre[e];
            } else {
                #pragma unroll
                for (int e = 0; e < 4; e++) a[0][e] = *(const v8s*)(ab0 + e * 128);
            }
            #pragma unroll
            for (int ks = 0; ks < 7; ks++) {
                const int cur = ks & 1, nxt = cur ^ 1;
                if (ks < 6) {
                    const u16* an = ab0 + (size_t)(ks + 1) * 4096;
                    #pragma unroll
                    for (int e = 0; e < 4; e++) a[nxt][e] = *(const v8s*)(an + e * 128);
                }
                const u16* psrc = (ks == 6 && quad != 0) ? &Zf[0]
                                                         : &prow[ks * 32 + quad * 8];
                v8s bfr = *(const v8s*)psrc;
                #pragma unroll
                for (int e = 0; e < 4; e++)
                    acc[e] = __builtin_amdgcn_mfma_f32_16x16x32_bf16(a[cur][e], bfr, acc[e], 0, 0, 0);
            }
            if (act) {
                #pragma unroll
                for (int e = 0; e < 4; e++) {
                    const int c0 = o * 128 + (eh * 4 + e) * 16 + quad * 4;
                    const size_t ioff = ((size_t)(b * 2 + half_) * 32 + (c0 >> 5)) * 4096
                                      + ((c0 >> 3) & 3) * 1024 + (size_t)(row0 + l16) * 8 + (c0 & 7);
                    v4u lv = *(const v4u*)&vlocI[ioff];
                    v4u u;
                    #pragma unroll
                    for (int r = 0; r < 4; r++)
                        u[r] = f2bf(fmaxf(acc[e][r] + bf2f(lv[r]), 0.f));
                    *(v4u*)&aoI[ioff] = u;
                }
            }
        }
        __builtin_amdgcn_s_setprio(0);
    }
}

// ---------------------------------------------------------------------------
// K6: projection GEMM (3-deep direct core, K=1024) + BN -> out fp32
// XCD swizzle: 384 blocks = 8 XCDs x (8 b x 6 tiles).
// ---------------------------------------------------------------------------
__global__ __launch_bounds__(256) void k_proj(
    const u16* __restrict__ WpI, const u16* __restrict__ aoI,
    const float* __restrict__ TB, float* __restrict__ out)
{
    const int tid = threadIdx.x;
    const int L = blockIdx.x + 2 * (blockIdx.y + 3 * blockIdx.z);
    const int idx = L >> 3;                 // 0..47
    const int b  = (L & 7) * 8 + idx / 6;   // contiguous b-chunk per XCD
    const int r  = idx % 6;
    const int mt = r >> 1, nt = r & 1;
    v4f acc[4][4] = {};
    gemm_direct3<32>(WpI + (size_t)mt * 131072,
                     aoI + ((size_t)b * 2 + nt) * 131072, acc, tid);

    const int lane = tid & 63, w = tid >> 6;
    const int wm = (w & 1) * 64, wn = (w >> 1) * 64;
    const int quad = lane >> 4, l16 = lane & 15;
    #pragma unroll
    for (int i = 0; i < 4; i++) {
        #pragma unroll
        for (int j = 0; j < 4; j++) {
            int p0 = mt * 128 + wm + i * 16 + quad * 4;
            int n  = nt * 128 + wn + j * 16 + l16;
            if (n < N_) {
                v4f s = *(const v4f*)&TB[3072 + p0];
                v4f t = *(const v4f*)&TB[3456 + p0];
                #pragma unroll
                for (int r2 = 0; r2 < 4; r2++)
                    out[((size_t)b * DIM_ + p0 + r2) * N_ + n] = acc[i][j][r2] * s[r2] + t[r2];
            }
        }
    }
}

// ---------------------------------------------------------------------------
extern "C" void kernel_launch(void* const* d_in, const int* in_sizes, int n_in,
                              void* d_out, int out_size, void* d_ws, size_t ws_size,
                              hipStream_t stream)
{
    const float* x    = (const float*)d_in[0];
    const float* wq   = (const float*)d_in[1];
    const float* bq   = (const float*)d_in[2];
    const float* bnq  = (const float*)d_in[3];
    const float* wk   = (const float*)d_in[4];
    const float* bk   = (const float*)d_in[5];
    const float* bnk  = (const float*)d_in[6];
    const float* wv   = (const float*)d_in[7];
    const float* bv   = (const float*)d_in[8];
    const float* bnv  = (const float*)d_in[9];
    const float* wvl  = (const float*)d_in[10];
    const float* bvl  = (const float*)d_in[11];
    const float* bnvl = (const float*)d_in[12];
    const float* th1w = (const float*)d_in[13];
    const float* th1b = (const float*)d_in[14];
    const float* th2w = (const float*)d_in[15];
    const float* th2b = (const float*)d_in[16];
    const float* wp   = (const float*)d_in[17];
    const float* bp   = (const float*)d_in[18];
    const float* bnp  = (const float*)d_in[19];
    const float* ab   = (const float*)d_in[20];
    const int*   bidx = (const int*)d_in[21];
    float* out = (float*)d_out;

    u16* wsb  = (u16*)d_ws;
    u16* WbI  = wsb + WBI_OFF;
    u16* WpI  = wsb + WPI_OFF;
    u16* qI   = wsb + QI_OFF;
    u16* kI   = wsb + KI_OFF;
    u16* vI   = wsb + VI_OFF;
    u16* vlocI = wsb + VLOC_U16;
    u16* xI   = wsb + TAIL_OFF;   // aliased: xI -> aoI (disjoint lifetimes)
    u16* aoI  = wsb + TAIL_OFF;
    float* TB    = (float*)(wsb + TB_OFF);
    u16* biasE16 = wsb + BIASE_OFF;

    k_pre<<<dim3(3229), 256, 0, stream>>>(x, wq, wk, wv, wp, ab, th1w, th1b,
                                          bq, bnq, bk, bnk, bv, bnv, bp, bnp, bvl, bnvl,
                                          bidx, xI, WbI, WpI, TB, biasE16);
    k_qkv<<<dim3(2, 12, B_), 256, 0, stream>>>(WbI, xI, TB, qI, kI, vI);
    k_dwconv<<<dim3(16, B_), 256, 0, stream>>>(vI, wvl, TB, vlocI);
    k_attn_av<<<dim3(13, B_), 512, 0, stream>>>(qI, kI, vI, th1w, th2w, th2b,
                                                biasE16, vlocI, aoI);
    k_proj<<<dim3(2, 3, B_), 256, 0, stream>>>(WpI, aoI, TB, out);
}

// Round 14
// 237.091 us; speedup vs baseline: 1.1252x; 1.0099x over previous
//
#include <hip/hip_runtime.h>

#define B_     64
#define DIM_   384
#define RES_   14
#define N_     196
#define HEADS_ 8
#define KD_    32
#define D_     128
#define DH_    1024
#define QK_    256
#define CH_    1536
#define EPS_   1e-5f
#define SCALE_ 0.17677669529663687f   // 32^-0.5

typedef unsigned short u16;
typedef unsigned int u32;
typedef short v8s __attribute__((ext_vector_type(8)));
typedef float v4f __attribute__((ext_vector_type(4)));
typedef u16  v4u __attribute__((ext_vector_type(4)));
typedef u16  v8u __attribute__((ext_vector_type(8)));

static __device__ __forceinline__ u16 f2bf(float f) {
    unsigned int u = __builtin_bit_cast(unsigned int, f);
    u = (u + 0x7fffu + ((u >> 16) & 1u)) >> 16;
    return (u16)u;
}
static __device__ __forceinline__ float bf2f(u16 u) {
    unsigned int x = ((unsigned int)u) << 16;
    return __builtin_bit_cast(float, x);
}
static __device__ __forceinline__ u16 f2h(float f) {
    _Float16 h = (_Float16)f;
    return __builtin_bit_cast(u16, h);
}
static __device__ __forceinline__ float h2f(u16 u) {
    return (float)__builtin_bit_cast(_Float16, u);
}

// workspace layout (u16 element offsets)
// GEMM operand images: [kstep][kquad(4)][row(128)][8] = 4096 elems (8KB)/kstep
#define WBI_OFF  0u          // Wb  image: 12 mtiles x 12 ksteps      (589824)
#define WPI_OFF  589824u     // wp  image: 3 mtiles x 32 ksteps       (393216)
#define QI_OFF   983040u     // qT  [B][8][256][32]                   (4194304)
#define KI_OFF   5177344u    // kT  [B][8][256][32]                   (4194304)
#define VI_OFF   9371648u    // v   image: [B][8] x 7 ksteps          (14680064)
#define VLOC_U16 53411840u   // vlocI in aoI image layout             (16777216)
#define TAIL_OFF 79101952u   // union: xI (6291456) / aoI (16777216)
#define TB_OFF   98770944u   // BN tables fp32[5888]
#define BIASE_OFF 98785920u  // biasE [196][8][196] fp32 (614656 u16)

// ---------------------------------------------------------------------------
// barrier-free direct-from-global 128x128 MFMA core.
// ---------------------------------------------------------------------------
template<int KSTEPS>
static __device__ __forceinline__ void gemm_direct(
    const u16* __restrict__ Ag, const u16* __restrict__ Bg,
    v4f acc[4][4], int tid)
{
    const int lane = tid & 63, w = tid >> 6;
    const int wm = (w & 1) * 64, wn = (w >> 1) * 64;
    const int quad = lane >> 4, l16 = lane & 15;
    const u16* pa = Ag + quad * 1024 + (wm + l16) * 8;
    const u16* pb = Bg + quad * 1024 + (wn + l16) * 8;
    v8s a[2][4], b[2][4];
    #pragma unroll
    for (int i = 0; i < 4; i++) {
        a[0][i] = *(const v8s*)(pa + i * 128);
        b[0][i] = *(const v8s*)(pb + i * 128);
    }
    #pragma unroll
    for (int ks = 0; ks < KSTEPS; ks++) {
        const int cur = ks & 1, nxt = cur ^ 1;
        if (ks + 1 < KSTEPS) {
            const u16* qa = pa + (size_t)(ks + 1) * 4096;
            const u16* qb = pb + (size_t)(ks + 1) * 4096;
            #pragma unroll
            for (int i = 0; i < 4; i++) {
                a[nxt][i] = *(const v8s*)(qa + i * 128);
                b[nxt][i] = *(const v8s*)(qb + i * 128);
            }
        }
        #pragma unroll
        for (int i = 0; i < 4; i++)
            #pragma unroll
            for (int j = 0; j < 4; j++)
                acc[i][j] = __builtin_amdgcn_mfma_f32_16x16x32_bf16(a[cur][i], b[cur][j], acc[i][j], 0, 0, 0);
    }
}

// 3-deep 64x128 variant for k_proj: M-split to 64-row A-tiles doubles the
// resident-block count (768 = 3/CU vs 1.5/CU) without increasing the Wp
// stream per unit work (R9's N-split mistake was doubling operand refetch).
template<int KSTEPS>
static __device__ __forceinline__ void gemm_direct3_m64(
    const u16* __restrict__ Ag, const u16* __restrict__ Bg,
    v4f acc[2][4], int tid)
{
    const int lane = tid & 63, w = tid >> 6;
    const int wm = (w & 1) * 32, wn = (w >> 1) * 64;
    const int quad = lane >> 4, l16 = lane & 15;
    const u16* pa = Ag + quad * 1024 + (wm + l16) * 8;
    const u16* pb = Bg + quad * 1024 + (wn + l16) * 8;
    v8s a[3][2], b[3][4];
    #pragma unroll
    for (int s = 0; s < 2; s++) {
        #pragma unroll
        for (int i = 0; i < 2; i++)
            a[s][i] = *(const v8s*)(pa + (size_t)s * 4096 + i * 128);
        #pragma unroll
        for (int j = 0; j < 4; j++)
            b[s][j] = *(const v8s*)(pb + (size_t)s * 4096 + j * 128);
    }
    #pragma unroll
    for (int ks = 0; ks < KSTEPS; ks++) {
        const int cur = ks % 3, nxt = (ks + 2) % 3;
        if (ks + 2 < KSTEPS) {
            const u16* qa = pa + (size_t)(ks + 2) * 4096;
            const u16* qb = pb + (size_t)(ks + 2) * 4096;
            #pragma unroll
            for (int i = 0; i < 2; i++)
                a[nxt][i] = *(const v8s*)(qa + i * 128);
            #pragma unroll
            for (int j = 0; j < 4; j++)
                b[nxt][j] = *(const v8s*)(qb + j * 128);
        }
        #pragma unroll
        for (int i = 0; i < 2; i++)
            #pragma unroll
            for (int j = 0; j < 4; j++)
                acc[i][j] = __builtin_amdgcn_mfma_f32_16x16x32_bf16(a[cur][i], b[cur][j], acc[i][j], 0, 0, 0);
    }
}

// ---------------------------------------------------------------------------
// k_pre: ALL preprocessing in one launch (round-12 version, fp32 biasE).
// Grid: [0,1536) castX | [1536,1824) WbI | [1824,2016) WpI
//       [2016,2028) BN | [2028,3229) biasE
// ---------------------------------------------------------------------------
__global__ __launch_bounds__(256) void k_pre(
    const float* __restrict__ x,
    const float* __restrict__ wq, const float* __restrict__ wk,
    const float* __restrict__ wv, const float* __restrict__ wp,
    const float* __restrict__ ab,
    const float* __restrict__ th1w, const float* __restrict__ th1b,
    const float* __restrict__ bq, const float* __restrict__ bnq,
    const float* __restrict__ bk, const float* __restrict__ bnk,
    const float* __restrict__ bv, const float* __restrict__ bnv,
    const float* __restrict__ bp, const float* __restrict__ bnp,
    const float* __restrict__ bvl, const float* __restrict__ bnvl,
    const int* __restrict__ bidx,
    u16* __restrict__ xI, u16* __restrict__ WbI, u16* __restrict__ WpI,
    float* __restrict__ TB, float* __restrict__ biasE)
{
    __shared__ float T[64][65];
    const int tid = threadIdx.x;
    const int t = blockIdx.x;
    if (t < 1536) {               // ---- castX (vectorized 16B image stores) ----
        const int n0 = (t & 3) * 64;
        const int k0 = ((t >> 2) % 6) * 64;
        const int b  = t / 24;
        const int c = tid & 63, r4 = tid >> 6;
        #pragma unroll
        for (int i = 0; i < 16; i++) {
            int kr = i * 4 + r4;
            int gn = n0 + c;
            T[kr][c] = (gn < N_) ? x[((size_t)b * DIM_ + k0 + kr) * N_ + gn] : 0.f;
        }
        __syncthreads();
        #pragma unroll
        for (int it = 0; it < 2; it++) {
            int m2 = it * 256 + tid;          // (token, k-octet) item
            int oct = m2 & 7, nn = m2 >> 3;
            int k = k0 + oct * 8, n = n0 + nn;
            v8u u;
            #pragma unroll
            for (int e = 0; e < 8; e++) u[e] = f2bf(T[oct * 8 + e][nn]);
            *(v8u*)&xI[(size_t)b * 98304 + (n >> 7) * 49152 + (k >> 5) * 4096
                       + ((k >> 3) & 3) * 1024 + (n & 127) * 8] = u;
        }
        return;
    }
    if (t < 1824) {               // ---- WbI: 8 elems/thread, float4 reads ----
        int base = ((t - 1536) * 256 + tid) * 8;       // < 589824
        int mt = base / 49152, rem = base % 49152;
        int ks = rem >> 12, r2 = rem & 4095;
        int q = r2 >> 10, row = (r2 >> 3) & 127;
        int c = mt * 128 + row, k = ks * 32 + q * 8;
        const float* src = (c < 256) ? &wq[c * 384 + k]
                         : (c < 512) ? &wk[(c - 256) * 384 + k]
                                     : &wv[(size_t)(c - 512) * 384 + k];
        float4 v0 = *(const float4*)src;
        float4 v1 = *(const float4*)(src + 4);
        v8u u;
        u[0] = f2bf(v0.x); u[1] = f2bf(v0.y); u[2] = f2bf(v0.z); u[3] = f2bf(v0.w);
        u[4] = f2bf(v1.x); u[5] = f2bf(v1.y); u[6] = f2bf(v1.z); u[7] = f2bf(v1.w);
        *(v8u*)&WbI[base] = u;
        return;
    }
    if (t < 2016) {               // ---- WpI: 8 elems/thread ----
        int base = ((t - 1824) * 256 + tid) * 8;       // < 393216
        int mt = base >> 17, rem = base & 131071;
        int ks = rem >> 12, r2 = rem & 4095;
        int q = r2 >> 10, row = (r2 >> 3) & 127;
        int p = mt * 128 + row, k = ks * 32 + q * 8;
        const float* src = &wp[(size_t)p * 1024 + k];
        float4 v0 = *(const float4*)src;
        float4 v1 = *(const float4*)(src + 4);
        v8u u;
        u[0] = f2bf(v0.x); u[1] = f2bf(v0.y); u[2] = f2bf(v0.z); u[3] = f2bf(v0.w);
        u[4] = f2bf(v1.x); u[5] = f2bf(v1.y); u[6] = f2bf(v1.z); u[7] = f2bf(v1.w);
        *(v8u*)&WpI[base] = u;
        return;
    }
    if (t < 2028) {               // ---- BN tables ----
        int j = (t - 2016) * 256 + tid;
        if (j >= 2944) return;
        if (j < 256) {
            int c = j;
            float s = bnq[c] * rsqrtf(bnq[768 + c] + EPS_);
            float tt = (bq[c] - bnq[512 + c]) * s + bnq[256 + c];
            TB[c] = s * SCALE_; TB[256 + c] = tt * SCALE_;
        } else if (j < 512) {
            int c = j - 256;
            float s = bnk[c] * rsqrtf(bnk[768 + c] + EPS_);
            float tt = (bk[c] - bnk[512 + c]) * s + bnk[256 + c];
            TB[512 + c] = s; TB[768 + c] = tt;
        } else if (j < 1536) {
            int c = j - 512;
            float s = bnv[c] * rsqrtf(bnv[3072 + c] + EPS_);
            float tt = (bv[c] - bnv[2048 + c]) * s + bnv[1024 + c];
            TB[1024 + c] = s; TB[2048 + c] = tt;
        } else if (j < 1920) {
            int c = j - 1536;
            float s = bnp[c] * rsqrtf(bnp[1152 + c] + EPS_);
            float tt = (bp[c] - bnp[768 + c]) * s + bnp[384 + c];
            TB[3072 + c] = s; TB[3456 + c] = tt;
        } else {
            int c = j - 1920;
            float s = bnvl[c] * rsqrtf(bnvl[3072 + c] + EPS_);
            float tt = (bvl[c] - bnvl[2048 + c]) * s + bnvl[1024 + c];
            TB[3840 + c] = s; TB[4864 + c] = tt;
        }
        return;
    }
    {                             // ---- biasE (fp32; the f16 packing regressed attn) ----
        int j = (t - 2028) * 256 + tid;
        if (j >= 307328) return;
        int m = j % N_;
        int t2 = j / N_;
        int o = t2 & 7;
        int n = t2 >> 3;
        int idx = bidx[n * N_ + m];
        float a = th1b[o];
        #pragma unroll
        for (int h = 0; h < 8; h++) a += th1w[o * 8 + h] * ab[h * N_ + idx];
        biasE[j] = a - 5.f;
    }
}

// ---------------------------------------------------------------------------
// K1: QKV GEMM (direct core). v-epilogue: per-wave LDS transpose so the
// vI image is written as 16B coalesced chunks.
// XCD swizzle: 1536 blocks = 8 XCDs x (8 b x 24 tiles).
// ---------------------------------------------------------------------------
__global__ __launch_bounds__(256) void k_qkv(
    const u16* __restrict__ WbI, const u16* __restrict__ xI,
    const float* __restrict__ TB,
    u16* __restrict__ qI, u16* __restrict__ kI, u16* __restrict__ vI)
{
    __shared__ u16 S[4][64][20];   // per-wave [tok64][ch16 pad20] = 10240 B
    const int tid = threadIdx.x;
    const int L = blockIdx.x + 2 * (blockIdx.y + 12 * blockIdx.z);
    const int idx = L >> 3;                 // 0..191
    const int b  = (L & 7) * 8 + idx / 24;  // contiguous b-chunk per XCD
    const int r  = idx % 24;
    const int mt = r >> 1, nt = r & 1;
    v4f acc[4][4] = {};
    gemm_direct<12>(WbI + (size_t)mt * 49152,
                    xI + ((size_t)b * 2 + nt) * 49152, acc, tid);

    const int lane = tid & 63, w = tid >> 6;
    const int wm = (w & 1) * 64, wn = (w >> 1) * 64;
    const int quad = lane >> 4, l16 = lane & 15;

    if (mt < 4) {                 // ---- q / k epilogue (unchanged) ----
        #pragma unroll
        for (int i = 0; i < 4; i++) {
            #pragma unroll
            for (int j = 0; j < 4; j++) {
                int gc = mt * 128 + wm + i * 16 + quad * 4;
                int n  = nt * 128 + wn + j * 16 + l16;
                v4f v = acc[i][j];
                if (gc < 256) {            // q
                    v4f s = *(const v4f*)&TB[gc];
                    v4f t = *(const v4f*)&TB[256 + gc];
                    v4u u;
                    #pragma unroll
                    for (int r2 = 0; r2 < 4; r2++) u[r2] = f2bf(v[r2] * s[r2] + t[r2]);
                    *(v4u*)&qI[((size_t)(b * 8 + (gc >> 5)) * 256 + n) * 32 + (gc & 31)] = u;
                } else {                   // k
                    int c = gc - 256;
                    v4f s = *(const v4f*)&TB[512 + c];
                    v4f t = *(const v4f*)&TB[768 + c];
                    v4u u;
                    #pragma unroll
                    for (int r2 = 0; r2 < 4; r2++) u[r2] = f2bf(v[r2] * s[r2] + t[r2]);
                    *(v4u*)&kI[((size_t)(b * 8 + (c >> 5)) * 256 + n) * 32 + (c & 31)] = u;
                }
            }
        }
    } else {                      // ---- v epilogue: LDS transpose ----
        const int o = mt - 4;
        u16* vbase = vI + (size_t)(b * 8 + o) * 28672;
        const int ntBase = nt * 128;
        #pragma unroll
        for (int i = 0; i < 4; i++) {
            const int e0 = wm + i * 16;                  // 16-channel group base
            const int cg = o * 128 + e0 + quad * 4;      // global v channel
            v4f s = *(const v4f*)&TB[1024 + cg];
            v4f t = *(const v4f*)&TB[2048 + cg];
            // stage: lane (quad,l16) -> S[w][tok][quad*4..+3], zeros for n>=196
            #pragma unroll
            for (int j = 0; j < 4; j++) {
                int n = ntBase + wn + j * 16 + l16;
                v4u u = {0, 0, 0, 0};
                if (n < N_) {
                    v4f v = acc[i][j];
                    #pragma unroll
                    for (int r2 = 0; r2 < 4; r2++) u[r2] = f2bf(v[r2] * s[r2] + t[r2]);
                }
                *(v4u*)&S[w][j * 16 + l16][quad * 4] = u;
            }
            asm volatile("s_waitcnt lgkmcnt(0)" ::: "memory");
            // read out (ch, 8-tok) chunks -> 16B coalesced image stores
            #pragma unroll
            for (int half = 0; half < 2; half++) {
                int c = half * 64 + lane;        // chunk 0..127
                int ch = c >> 3, t0 = (c & 7) * 8;
                int n0 = ntBase + wn + t0;
                if (n0 < 224) {
                    v8u val;
                    #pragma unroll
                    for (int k = 0; k < 8; k++) val[k] = S[w][t0 + k][ch];
                    *(v8u*)&vbase[(size_t)(n0 >> 5) * 4096 + ((n0 >> 3) & 3) * 1024
                                  + (size_t)(e0 + ch) * 8] = val;
                }
            }
            asm volatile("s_waitcnt lgkmcnt(0)" ::: "memory");   // WAR vs next i
        }
    }
}

// ---------------------------------------------------------------------------
// K2: depthwise 3x3 conv. Block = 64 channels of one (b,o).
// Output path via [token][ch+pad] LDS transpose (round-12).
// ---------------------------------------------------------------------------
__global__ __launch_bounds__(256) void k_dwconv(
    const u16* __restrict__ vI, const float* __restrict__ wvl,
    const float* __restrict__ TB, u16* __restrict__ vlocI)
{
    __shared__ __attribute__((aligned(16))) u16 V[64 * 230];   // 29440 B
    const int tid = threadIdx.x;
    const int sub = blockIdx.x;             // 0..15: o = sub>>1, half = sub&1
    const int b   = blockIdx.y;
    const int o   = sub >> 1;
    const int e0  = (sub & 1) * 64;
    const u16* img = vI + (size_t)(b * 8 + o) * 28672;

    {
        const int quad = tid >> 6, l = tid & 63;
        #pragma unroll
        for (int i = 0; i < 7; i++) {
            v8s u = *(const v8s*)&img[i * 4096 + quad * 1024 + (e0 + l) * 8];
            const u32* ui = (const u32*)&u;
            int m0 = i * 32 + quad * 8;
            u32* dst = (u32*)&V[l * 230 + m0];
            #pragma unroll
            for (int c = 0; c < 4; c++) dst[c] = ui[c];
        }
    }
    __syncthreads();

    const int e = tid & 63, j = tid >> 6;
    const int cg = sub * 64 + e;
    const int y0 = j * 4;
    const int ny = (j == 3) ? 2 : 4;
    float wgt[9];
    #pragma unroll
    for (int k = 0; k < 9; k++) wgt[k] = wvl[cg * 9 + k];
    const float sc = TB[3840 + cg], sh = TB[4864 + cg];
    u32 po[4][7];

    for (int yi = 0; yi < ny; yi++) {
        int y = y0 + yi;
        float a[3][16];
        #pragma unroll
        for (int dy = 0; dy < 3; dy++) {
            int yy = y + dy - 1;
            a[dy][0] = 0.f; a[dy][15] = 0.f;
            if (yy < 0 || yy > 13) {
                #pragma unroll
                for (int x = 1; x < 15; x++) a[dy][x] = 0.f;
            } else {
                const u16* rp = &V[e * 230 + yy * 14];
                #pragma unroll
                for (int c4 = 0; c4 < 7; c4++) {
                    u32 u = *(const u32*)&rp[c4 * 2];
                    a[dy][1 + 2 * c4] = bf2f((u16)(u & 0xffffu));
                    a[dy][2 + 2 * c4] = bf2f((u16)(u >> 16));
                }
            }
        }
        #pragma unroll
        for (int xp = 0; xp < 7; xp++) {
            u32 pk = 0;
            #pragma unroll
            for (int half = 0; half < 2; half++) {
                int x = 2 * xp + half;
                float s = 0.f;
                #pragma unroll
                for (int dy = 0; dy < 3; dy++)
                    #pragma unroll
                    for (int kx = 0; kx < 3; kx++)
                        s += wgt[dy * 3 + kx] * a[dy][x + kx];
                u16 bv = f2bf(s * sc + sh);
                pk |= ((u32)bv) << (16 * half);
            }
            po[yi][xp] = pk;
        }
    }
    __syncthreads();

    // phase 2: write results to V2[n][72-pad][ch] (transposed for vector gather)
    for (int yi = 0; yi < ny; yi++) {
        int y = y0 + yi;
        #pragma unroll
        for (int xp = 0; xp < 7; xp++) {
            u32 pk = po[yi][xp];
            int n = y * 14 + 2 * xp;
            V[n * 72 + e]       = (u16)(pk & 0xffffu);
            V[(n + 1) * 72 + e] = (u16)(pk >> 16);
        }
    }
    __syncthreads();

    // phase 3: one b128 gather + one 16B store per (g, n) item
    for (int it = 0; it < 7; it++) {
        int idx = it * 256 + tid;
        if (idx < 1568) {
            int g = idx / 196, n = idx - g * 196;
            v8u val = *(const v8u*)&V[n * 72 + g * 8];
            u16* dst = vlocI + ((size_t)(b * 2 + (n >> 7)) * 32 + sub * 2 + (g >> 2)) * 4096
                     + (g & 3) * 1024 + (n & 127) * 8;
            *(v8u*)dst = val;
        }
    }
}

// ---------------------------------------------------------------------------
// K3: FUSED attention + AV + vloc + relu -> aoI (round-12 config: QBLK=16,
// Sl stride 200, Zf zero-fragment, V prefetch, setprio, fp32 biasE).
// XCD swizzle: 832 blocks = 8 XCDs x (8 b x 13 qt).
// ---------------------------------------------------------------------------
#define SLS 200   // Sl stride (u16 elems); %4==0 for b64/b128 alignment
__global__ __launch_bounds__(512, 6) void k_attn_av(
    const u16* __restrict__ qI, const u16* __restrict__ kI,
    const u16* __restrict__ vI,
    const float* __restrict__ th1w,
    const float* __restrict__ th2w, const float* __restrict__ th2b,
    const float* __restrict__ biasE,
    const u16* __restrict__ vlocI, u16* __restrict__ aoI)
{
    __shared__ u16 Sl[8 * 16 * SLS];   // [h][q16][m<200] = 51200 B
    __shared__ float red[128][4];
    __shared__ float invS[128];        // [h*16+q]
    __shared__ __attribute__((aligned(16))) u16 Zf[8];   // zero fragment
    const int tid = threadIdx.x;
    const int w = tid >> 6, lane = tid & 63;
    const int quad = lane >> 4, l16 = lane & 15;
    const int L = blockIdx.x + 13 * blockIdx.y;
    const int idx = L >> 3;                 // 0..103
    const int b  = (L & 7) * 8 + idx / 13;  // contiguous b-chunk per XCD
    const int qt = idx % 13;                // 0..12
    const int n0 = qt * 16;
    if (tid < 8) Zf[tid] = 0;

    // phase A: wave w -> head w. Operand-swapped MFMA: D[m_local][q16].
    {
        const int h = w;
        const u16* qb = qI + (size_t)(b * 8 + h) * 8192;
        const u16* kb = kI + (size_t)(b * 8 + h) * 8192;
        v8s qf = *(const v8s*)&qb[(n0 + l16) * 32 + quad * 8];   // B operand (cols)
        #pragma unroll
        for (int mt = 0; mt < 13; mt++) {
            v8s kf = *(const v8s*)&kb[(mt * 16 + l16) * 32 + quad * 8]; // A operand (rows)
            v4f acc = {};
            acc = __builtin_amdgcn_mfma_f32_16x16x32_bf16(kf, qf, acc, 0, 0, 0);
            if (mt < 12 || quad < 2) {
                v4u pk;
                #pragma unroll
                for (int r = 0; r < 4; r++) pk[r] = f2h(acc[r]);
                *(v4u*)&Sl[(h * 16 + l16) * SLS + mt * 16 + quad * 4] = pk;
            }
        }
    }
    __syncthreads();

    // phase B1: thread owns (m-pair, q-quad); all LDS traffic u32, biasE float2
    const int mp  = (tid & 127) * 2;   // 0,2,...,254
    const int qh  = tid >> 7;          // 0..3 -> q = qh*4 + qq
    const bool pvalid = (mp < N_);
    for (int qq = 0; qq < 4; qq++) {
        int q = qh * 4 + qq;
        int n = n0 + q;
        if (pvalid && n < N_) {
            const float* bE = biasE + (size_t)n * 1568 + mp;
            float S0[8], S1[8];
            #pragma unroll
            for (int h = 0; h < 8; h++) {
                u32 u = *(const u32*)&Sl[(h * 16 + q) * SLS + mp];
                S0[h] = h2f((u16)(u & 0xffffu));
                S1[h] = h2f((u16)(u >> 16));
            }
            u32 ew[8];
            #pragma unroll
            for (int o = 0; o < 8; o++) {
                float2 bb = *(const float2*)&bE[o * 196];
                float a0 = bb.x, a1 = bb.y;
                #pragma unroll
                for (int h = 0; h < 8; h++) {
                    a0 += th1w[o * 8 + h] * S0[h];
                    a1 += th1w[o * 8 + h] * S1[h];
                }
                ew[o] = (u32)f2h(__expf(a0)) | ((u32)f2h(__expf(a1)) << 16);
            }
            #pragma unroll
            for (int o = 0; o < 8; o++)
                *(u32*)&Sl[(o * 16 + q) * SLS + mp] = ew[o];
        }
    }
    __syncthreads();

    // phase B2: 128 rows x 4 quarters; vectorized u32 LDS reads (m < 196)
    {
        int r = tid >> 2, quarter = tid & 3;
        int mstart = quarter * 48;
        int cnt = (quarter == 3) ? 26 : 24;
        const u16* rowp = &Sl[r * SLS + mstart];
        float s = 0.f;
        for (int i = 0; i < cnt; i++) {
            u32 u = *(const u32*)&rowp[i * 2];
            s += h2f((u16)(u & 0xffffu)) + h2f((u16)(u >> 16));
        }
        red[r][quarter] = s;
    }
    __syncthreads();
    if (tid < 128)
        invS[tid] = 1.f / (red[tid][0] + red[tid][1] + red[tid][2] + red[tid][3]);
    __syncthreads();

    // phase B3: scale + TH2 in place (bf16); m-pair u32 traffic; zero m<200
    for (int qq = 0; qq < 4; qq++) {
        int q = qh * 4 + qq;
        bool valid = pvalid && (n0 + q < N_);
        u32 pw[8];
        if (valid) {
            float s0[8], s1[8];
            #pragma unroll
            for (int h = 0; h < 8; h++) {
                u32 u = *(const u32*)&Sl[(h * 16 + q) * SLS + mp];
                float is = invS[h * 16 + q];
                s0[h] = h2f((u16)(u & 0xffffu)) * is;
                s1[h] = h2f((u16)(u >> 16)) * is;
            }
            #pragma unroll
            for (int o = 0; o < 8; o++) {
                float v0 = th2b[o], v1 = th2b[o];
                #pragma unroll
                for (int h = 0; h < 8; h++) {
                    v0 += th2w[o * 8 + h] * s0[h];
                    v1 += th2w[o * 8 + h] * s1[h];
                }
                pw[o] = (u32)f2bf(v0) | ((u32)f2bf(v1) << 16);
            }
        } else {
            #pragma unroll
            for (int o = 0; o < 8; o++) pw[o] = 0;
        }
        if (mp < SLS) {
            #pragma unroll
            for (int o = 0; o < 8; o++)
                *(u32*)&Sl[(o * 16 + q) * SLS + mp] = pw[o];
        }
    }

    // pre-issue phase C's first V fragments (pure global, no LDS dependency)
    const int o = w;
    const u16* vb = vI + (size_t)(b * 8 + o) * 28672;
    v8s a0pre[4];
    {
        const u16* ab00 = vb + quad * 1024 + l16 * 8;   // eh=0 base
        #pragma unroll
        for (int e = 0; e < 4; e++) a0pre[e] = *(const v8s*)(ab00 + e * 128);
    }
    __syncthreads();

    // phase C: AV. Wave w handles o = w; all 16 output columns live.
    {
        const int half_ = n0 >> 7;
        const int row0 = n0 & 127;
        const int n = n0 + l16;
        const bool act = (n < N_);
        const u16* prow = &Sl[(o * 16 + l16) * SLS];
        __builtin_amdgcn_s_setprio(1);
        #pragma unroll
        for (int eh = 0; eh < 2; eh++) {       // 2 e-halves of 64
            v4f acc[4] = {};
            v8s a[2][4];
            const u16* ab0 = vb + quad * 1024 + (eh * 64 + l16) * 8;
            if (eh == 0) {
                #pragma unroll
                for (int e = 0; e < 4; e++) a[0][e] = a0pre[e];
            } else {
                #pragma unroll
                for (int e = 0; e < 4; e++) a[0][e] = *(const v8s*)(ab0 + e * 128);
            }
            #pragma unroll
            for (int ks = 0; ks < 7; ks++) {
                const int cur = ks & 1, nxt = cur ^ 1;
                if (ks < 6) {
                    const u16* an = ab0 + (size_t)(ks + 1) * 4096;
                    #pragma unroll
                    for (int e = 0; e < 4; e++) a[nxt][e] = *(const v8s*)(an + e * 128);
                }
                const u16* psrc = (ks == 6 && quad != 0) ? &Zf[0]
                                                         : &prow[ks * 32 + quad * 8];
                v8s bfr = *(const v8s*)psrc;
                #pragma unroll
                for (int e = 0; e < 4; e++)
                    acc[e] = __builtin_amdgcn_mfma_f32_16x16x32_bf16(a[cur][e], bfr, acc[e], 0, 0, 0);
            }
            if (act) {
                #pragma unroll
                for (int e = 0; e < 4; e++) {
                    const int c0 = o * 128 + (eh * 4 + e) * 16 + quad * 4;
                    const size_t ioff = ((size_t)(b * 2 + half_) * 32 + (c0 >> 5)) * 4096
                                      + ((c0 >> 3) & 3) * 1024 + (size_t)(row0 + l16) * 8 + (c0 & 7);
                    v4u lv = *(const v4u*)&vlocI[ioff];
                    v4u u;
                    #pragma unroll
                    for (int r = 0; r < 4; r++)
                        u[r] = f2bf(fmaxf(acc[e][r] + bf2f(lv[r]), 0.f));
                    *(v4u*)&aoI[ioff] = u;
                }
            }
        }
        __builtin_amdgcn_s_setprio(0);
    }
}

// ---------------------------------------------------------------------------
// K6: projection GEMM (3-deep, 64x128 M-split tiles, K=1024) + BN -> fp32.
// 768 blocks = 3/CU (vs 384 = 1.5/CU): per-block Wp bytes halve, aoI reads
// double but stay L2-resident under the b-per-XCD chunking.
// XCD swizzle: 768 blocks = 8 XCDs x (8 b x 12 tiles).
// ---------------------------------------------------------------------------
__global__ __launch_bounds__(256) void k_proj(
    const u16* __restrict__ WpI, const u16* __restrict__ aoI,
    const float* __restrict__ TB, float* __restrict__ out)
{
    const int tid = threadIdx.x;
    const int L = blockIdx.x + 2 * (blockIdx.y + 6 * blockIdx.z);
    const int idx = L >> 3;                 // 0..95
    const int b  = (L & 7) * 8 + idx / 12;  // contiguous b-chunk per XCD
    const int r  = idx % 12;
    const int m64 = r >> 1, nt = r & 1;     // m64 0..5 (64-row tiles), nt 0..1
    const int mt = m64 >> 1, mh = m64 & 1;
    v4f acc[2][4] = {};
    gemm_direct3_m64<32>(WpI + (size_t)mt * 131072 + mh * 512,
                         aoI + ((size_t)b * 2 + nt) * 131072, acc, tid);

    const int lane = tid & 63, w = tid >> 6;
    const int wm = (w & 1) * 32, wn = (w >> 1) * 64;
    const int quad = lane >> 4, l16 = lane & 15;
    #pragma unroll
    for (int i = 0; i < 2; i++) {
        #pragma unroll
        for (int j = 0; j < 4; j++) {
            int p0 = m64 * 64 + wm + i * 16 + quad * 4;
            int n  = nt * 128 + wn + j * 16 + l16;
            if (n < N_) {
                v4f s = *(const v4f*)&TB[3072 + p0];
                v4f t = *(const v4f*)&TB[3456 + p0];
                #pragma unroll
                for (int r2 = 0; r2 < 4; r2++)
                    out[((size_t)b * DIM_ + p0 + r2) * N_ + n] = acc[i][j][r2] * s[r2] + t[r2];
            }
        }
    }
}

// ---------------------------------------------------------------------------
extern "C" void kernel_launch(void* const* d_in, const int* in_sizes, int n_in,
                              void* d_out, int out_size, void* d_ws, size_t ws_size,
                              hipStream_t stream)
{
    const float* x    = (const float*)d_in[0];
    const float* wq   = (const float*)d_in[1];
    const float* bq   = (const float*)d_in[2];
    const float* bnq  = (const float*)d_in[3];
    const float* wk   = (const float*)d_in[4];
    const float* bk   = (const float*)d_in[5];
    const float* bnk  = (const float*)d_in[6];
    const float* wv   = (const float*)d_in[7];
    const float* bv   = (const float*)d_in[8];
    const float* bnv  = (const float*)d_in[9];
    const float* wvl  = (const float*)d_in[10];
    const float* bvl  = (const float*)d_in[11];
    const float* bnvl = (const float*)d_in[12];
    const float* th1w = (const float*)d_in[13];
    const float* th1b = (const float*)d_in[14];
    const float* th2w = (const float*)d_in[15];
    const float* th2b = (const float*)d_in[16];
    const float* wp   = (const float*)d_in[17];
    const float* bp   = (const float*)d_in[18];
    const float* bnp  = (const float*)d_in[19];
    const float* ab   = (const float*)d_in[20];
    const int*   bidx = (const int*)d_in[21];
    float* out = (float*)d_out;

    u16* wsb  = (u16*)d_ws;
    u16* WbI  = wsb + WBI_OFF;
    u16* WpI  = wsb + WPI_OFF;
    u16* qI   = wsb + QI_OFF;
    u16* kI   = wsb + KI_OFF;
    u16* vI   = wsb + VI_OFF;
    u16* vlocI = wsb + VLOC_U16;
    u16* xI   = wsb + TAIL_OFF;   // aliased: xI -> aoI (disjoint lifetimes)
    u16* aoI  = wsb + TAIL_OFF;
    float* TB    = (float*)(wsb + TB_OFF);
    float* biasE = (float*)(wsb + BIASE_OFF);

    k_pre<<<dim3(3229), 256, 0, stream>>>(x, wq, wk, wv, wp, ab, th1w, th1b,
                                          bq, bnq, bk, bnk, bv, bnv, bp, bnp, bvl, bnvl,
                                          bidx, xI, WbI, WpI, TB, biasE);
    k_qkv<<<dim3(2, 12, B_), 256, 0, stream>>>(WbI, xI, TB, qI, kI, vI);
    k_dwconv<<<dim3(16, B_), 256, 0, stream>>>(vI, wvl, TB, vlocI);
    k_attn_av<<<dim3(13, B_), 512, 0, stream>>>(qI, kI, vI, th1w, th2w, th2b,
                                                biasE, vlocI, aoI);
    k_proj<<<dim3(2, 6, B_), 256, 0, stream>>>(WpI, aoI, TB, out);
}